// Round 4
// baseline (1712.905 us; speedup 1.0000x reference)
//
#include <hip/hip_runtime.h>

// ---------------------------------------------------------------------------
// MatchModule forward. H=4 D=128 B=16 K=256 M=8 L=80 DET_C=1152, dk=32.
// All intermediates f32 in d_ws. External inputs read via runtime dtype flag
// (0 = bf16, 1 = f32) detected on-device. Output store also flag-branched.
// (Round 4: byte-identical resubmission after 2x UnresponsiveContainer infra
// failures on the same pod — no kernel verdict was produced.)
//
// ws layout (floats): [flag int @0 | pad | rowsum @4096 | X @16384 |
//                      VO @16384+SZ | Kc @16384+2SZ | Vc @+10240*128]
// SZ = 32768*128.  Total = 44,105,728 bytes (42.1 MiB).
// ---------------------------------------------------------------------------

#define DD 128
#define WMAT 16384

__device__ __forceinline__ float bf2f(unsigned short u) {
    union { unsigned int i; float f; } v; v.i = ((unsigned int)u) << 16; return v.f;
}
__device__ __forceinline__ unsigned short f2bf(float f) {
    union { float f; unsigned int i; } v; v.f = f;
    unsigned int x = v.i;
    return (unsigned short)((x + 0x7FFFu + ((x >> 16) & 1u)) >> 16);
}
// external (input) load: dtype chosen at runtime
__device__ __forceinline__ float ldx(const void* p, size_t i, int isf32) {
    return isf32 ? ((const float*)p)[i] : bf2f(((const unsigned short*)p)[i]);
}

// ---------------------------------------------------------------------------
// dtype detector: interpret first 256 ushorts of `center` as bf16. True bf16
// N(0,1) data -> ~256 sane values. f32 data -> even ushorts are random
// mantissa bits -> only ~60% sane. Threshold 224.
// ---------------------------------------------------------------------------
__global__ __launch_bounds__(256) void detect_kernel(
    const unsigned short* __restrict__ c, int* __restrict__ flag) {
    __shared__ int cnt;
    if (threadIdx.x == 0) cnt = 0;
    __syncthreads();
    float v = bf2f(c[threadIdx.x]);
    int sane = (v == v) && (fabsf(v) <= 1e4f) && (v == 0.f || fabsf(v) >= 1e-10f);
    atomicAdd(&cnt, sane);
    __syncthreads();
    if (threadIdx.x == 0) flag[0] = (cnt >= 224) ? 0 : 1;  // 0=bf16, 1=f32
}

__global__ void sentinel_kernel(unsigned short* out, int n, int val) {
    int i = blockIdx.x * 256 + threadIdx.x;
    if (i < n) out[i] = (unsigned short)val;
}

// ---------------------------------------------------------------------------
// rowsum[b,i] = sum_j 1/(dist(b,i,j)+0.01)  (dist symmetric -> also col sum)
// ---------------------------------------------------------------------------
__global__ __launch_bounds__(256) void rowsum_kernel(
    const void* __restrict__ center, float* __restrict__ rs,
    const int* __restrict__ flagp) {
    const int isf32 = *flagp;
    const int b = blockIdx.x, i = threadIdx.x;
    __shared__ float c[768];
    for (int idx = i; idx < 768; idx += 256) c[idx] = ldx(center, (size_t)b * 768 + idx, isf32);
    __syncthreads();
    const float cx = c[i * 3], cy = c[i * 3 + 1], cz = c[i * 3 + 2];
    float s = 0.f;
    for (int j = 0; j < 256; ++j) {
        float dx = cx - c[j * 3], dy = cy - c[j * 3 + 1], dz = cz - c[j * 3 + 2];
        s += 1.f / (sqrtf(dx * dx + dy * dy + dz * dz) + 0.01f);
    }
    rs[b * 256 + i] = s;
}

// ---------------------------------------------------------------------------
// out(nrows,128) = A(nrows,Kdim) @ W(Kdim,128) + bias  [+ BN + PReLU if epi]
// A: workspace f32 (aExt=0) or external flag-dtype (aExt=1). W/bias/bn/alpha
// always external. 256 thr = 128 cols x 2 row-groups, 8 rows/thread.
// ---------------------------------------------------------------------------
__global__ __launch_bounds__(256) void gemm128_kernel(
    const void* __restrict__ A, int aExt,
    const void* __restrict__ W, int wOff,
    const void* __restrict__ bias, int bOff,
    float* __restrict__ out, int nrows, int Kdim, int epi,
    const void* __restrict__ bn, int bnOff,
    const void* __restrict__ alpha, int aOff, int alpha_pc,
    const int* __restrict__ flagp) {
    const int isf32 = *flagp;
    const int aF = aExt ? isf32 : 1;
    const int d = threadIdx.x & 127, rg = threadIdx.x >> 7;
    const int r0 = blockIdx.x * 16 + rg * 8;
    if (r0 >= nrows) return;
    float acc[8] = {0.f, 0.f, 0.f, 0.f, 0.f, 0.f, 0.f, 0.f};
    const float* Af = (const float*)A;
    const unsigned short* Au = (const unsigned short*)A;
    for (int k = 0; k < Kdim; k += 4) {
        const float w0 = ldx(W, (size_t)wOff + (size_t)(k + 0) * DD + d, isf32);
        const float w1 = ldx(W, (size_t)wOff + (size_t)(k + 1) * DD + d, isf32);
        const float w2 = ldx(W, (size_t)wOff + (size_t)(k + 2) * DD + d, isf32);
        const float w3 = ldx(W, (size_t)wOff + (size_t)(k + 3) * DD + d, isf32);
#pragma unroll
        for (int r = 0; r < 8; ++r) {
            const size_t base = (size_t)(r0 + r) * Kdim + k;
            float a0, a1, a2, a3;
            if (aF) {
                a0 = Af[base]; a1 = Af[base + 1]; a2 = Af[base + 2]; a3 = Af[base + 3];
            } else {
                a0 = bf2f(Au[base]); a1 = bf2f(Au[base + 1]);
                a2 = bf2f(Au[base + 2]); a3 = bf2f(Au[base + 3]);
            }
            acc[r] = fmaf(a0, w0, fmaf(a1, w1, fmaf(a2, w2, fmaf(a3, w3, acc[r]))));
        }
    }
    const float bs = ldx(bias, (size_t)bOff + d, isf32);
#pragma unroll
    for (int r = 0; r < 8; ++r) {
        float v = acc[r] + bs;
        if (epi) {
            const float g  = ldx(bn, (size_t)bnOff + d, isf32);
            const float bb = ldx(bn, (size_t)bnOff + DD + d, isf32);
            const float mm = ldx(bn, (size_t)bnOff + 2 * DD + d, isf32);
            const float vv = ldx(bn, (size_t)bnOff + 3 * DD + d, isf32);
            v = g * (v - mm) * rsqrtf(vv + 1e-5f) + bb;
            const float a = alpha_pc ? ldx(alpha, (size_t)aOff + d, isf32)
                                     : ldx(alpha, (size_t)aOff, isf32);
            v = (v >= 0.f) ? v : a * v;
        }
        out[(size_t)(r0 + r) * DD + d] = v;
    }
}

// ---------------------------------------------------------------------------
// Attention, block = (seq s, head h), 256 threads = 256 query rows.
// Q projection fused (weight slice staged in LDS). selfmode: K projection
// also fused (keys = same X rows), V read from Vg (row s*256+j), O written
// IN PLACE over Vg (disjoint col slices across heads; __syncthreads before
// store covers intra-block). cross: K staged from Kc, V from Vg (row s*nk+j).
// Self bias: h0 = (1/(d+.01))/rowsum[key], h1 = -d, h2/3 = 0.
// ---------------------------------------------------------------------------
__global__ __launch_bounds__(256) void attn_kernel(
    const float* __restrict__ X, const float* __restrict__ Vg,
    const float* __restrict__ Kc,
    const void* __restrict__ Wqkv, int wqOff, int wkOff,
    const void* __restrict__ bqkv, int bqOff, int bkOff,
    float* __restrict__ O,
    const void* __restrict__ center, const float* __restrict__ rs,
    const int* __restrict__ flagp, int nk, int selfmode, int bDiv) {
    __shared__ float sK[256 * 32];   // 32 KB
    __shared__ float sW[128 * 32];   // 16 KB (Wq slice, then Wk slice)
    __shared__ float sC[768];
    __shared__ float sR[256];
    const int isf32 = *flagp;
    const int s = blockIdx.x, h = blockIdx.y, q = threadIdx.x;
    const int hc = h * 32;

    // ---- fused Q projection ----
    for (int idx = q; idx < 4096; idx += 256) {
        int k = idx >> 5, i = idx & 31;
        sW[idx] = ldx(Wqkv, (size_t)wqOff + (size_t)k * DD + hc + i, isf32);
    }
    __syncthreads();
    float qr[32];
#pragma unroll
    for (int i = 0; i < 32; ++i) qr[i] = ldx(bqkv, (size_t)bqOff + hc + i, isf32);
    const float* xq = X + (size_t)(s * 256 + q) * DD;
    for (int k = 0; k < DD; ++k) {
        const float x = xq[k];
        const float* w = &sW[k * 32];
#pragma unroll
        for (int i = 0; i < 32; ++i) qr[i] = fmaf(x, w[i], qr[i]);
    }
    __syncthreads();  // done with Wq slice

    if (selfmode) {
        for (int idx = q; idx < 4096; idx += 256) {
            int k = idx >> 5, i = idx & 31;
            sW[idx] = ldx(Wqkv, (size_t)wkOff + (size_t)k * DD + hc + i, isf32);
        }
        const int bb = s / bDiv;
        for (int idx = q; idx < 768; idx += 256)
            sC[idx] = ldx(center, (size_t)bb * 768 + idx, isf32);
        sR[q] = rs[bb * 256 + q];
        __syncthreads();
        float kr[32];
#pragma unroll
        for (int i = 0; i < 32; ++i) kr[i] = ldx(bqkv, (size_t)bkOff + hc + i, isf32);
        for (int k = 0; k < DD; ++k) {
            const float x = xq[k];
            const float* w = &sW[k * 32];
#pragma unroll
            for (int i = 0; i < 32; ++i) kr[i] = fmaf(x, w[i], kr[i]);
        }
#pragma unroll
        for (int i = 0; i < 32; ++i) sK[q * 32 + i] = kr[i];
        __syncthreads();
    } else {
        for (int idx = q; idx < nk * 32; idx += 256) {
            int j = idx >> 5, i = idx & 31;
            sK[idx] = Kc[((size_t)(s * nk + j)) * DD + hc + i];
        }
        __syncthreads();
    }

    float cx = 0.f, cy = 0.f, cz = 0.f;
    if (selfmode) { cx = sC[q * 3]; cy = sC[q * 3 + 1]; cz = sC[q * 3 + 2]; }
    const float scale = 0.17677669529663687f;  // 1/sqrt(32)

    // pass 1: online max + sum
    float m = -1e30f, l = 0.f;
    for (int j = 0; j < nk; ++j) {
        const float* kp = &sK[j * 32];
        float sc = 0.f;
#pragma unroll
        for (int i = 0; i < 32; ++i) sc = fmaf(qr[i], kp[i], sc);
        sc *= scale;
        if (selfmode) {
            float dx = cx - sC[j * 3], dy = cy - sC[j * 3 + 1], dz = cz - sC[j * 3 + 2];
            float dist = sqrtf(dx * dx + dy * dy + dz * dz);
            if (h == 0) sc += (1.f / (dist + 0.01f)) / sR[j];
            else if (h == 1) sc -= dist;
        }
        const float mn = fmaxf(m, sc);
        l = l * __expf(m - mn) + __expf(sc - mn);
        m = mn;
    }

    // pass 2: recompute scores, accumulate P·V
    float acc[32];
#pragma unroll
    for (int i = 0; i < 32; ++i) acc[i] = 0.f;
    for (int j = 0; j < nk; ++j) {
        const float* kp = &sK[j * 32];
        float sc = 0.f;
#pragma unroll
        for (int i = 0; i < 32; ++i) sc = fmaf(qr[i], kp[i], sc);
        sc *= scale;
        if (selfmode) {
            float dx = cx - sC[j * 3], dy = cy - sC[j * 3 + 1], dz = cz - sC[j * 3 + 2];
            float dist = sqrtf(dx * dx + dy * dy + dz * dz);
            if (h == 0) sc += (1.f / (dist + 0.01f)) / sR[j];
            else if (h == 1) sc -= dist;
        }
        const float p = __expf(sc - m);
        const float* vp = Vg + ((size_t)(s * nk + j)) * DD + hc;
#pragma unroll
        for (int i = 0; i < 32; ++i) acc[i] = fmaf(p, vp[i], acc[i]);
    }
    __syncthreads();  // all V reads done before in-place O store
    const float inv = 1.f / l;
    float* op = O + ((size_t)(s * 256 + q)) * DD + hc;
#pragma unroll
    for (int i = 0; i < 32; ++i) op[i] = acc[i] * inv;
}

// ---------------------------------------------------------------------------
// Y[row] = LayerNorm(X[row] + O[row] @ Wo + bo); Y may alias X or O (row-local)
// ---------------------------------------------------------------------------
__global__ __launch_bounds__(128) void proj_ln_kernel(
    const float* __restrict__ X, const float* __restrict__ O,
    const void* __restrict__ Wo, int woOff, const void* __restrict__ bo, int boOff,
    const void* __restrict__ ln, int lnOff, float* __restrict__ Y,
    const int* __restrict__ flagp) {
    const int isf32 = *flagp;
    const int row = blockIdx.x, d = threadIdx.x;
    __shared__ float sO[128];
    __shared__ float red1[2], red2[2];
    sO[d] = O[(size_t)row * DD + d];
    __syncthreads();
    float acc = 0.f;
#pragma unroll 4
    for (int k = 0; k < DD; ++k)
        acc = fmaf(sO[k], ldx(Wo, (size_t)woOff + (size_t)k * DD + d, isf32), acc);
    const float v = X[(size_t)row * DD + d] + acc + ldx(bo, (size_t)boOff + d, isf32);
    float s1 = v, s2 = v * v;
#pragma unroll
    for (int o = 1; o < 64; o <<= 1) { s1 += __shfl_xor(s1, o); s2 += __shfl_xor(s2, o); }
    if ((d & 63) == 0) { red1[d >> 6] = s1; red2[d >> 6] = s2; }
    __syncthreads();
    const float S1 = red1[0] + red1[1], S2 = red2[0] + red2[1];
    const float mu = S1 * (1.f / 128.f);
    const float var = S2 * (1.f / 128.f) - mu * mu;
    Y[(size_t)row * DD + d] =
        ldx(ln, (size_t)lnOff + d, isf32) * (v - mu) * rsqrtf(var + 1e-5f) +
        ldx(ln, (size_t)lnOff + DD + d, isf32);
}

// f1_0[(b*M+m)*256+n, d] = x1[b*256+n, d]
__global__ __launch_bounds__(256) void bcast_kernel(
    const float* __restrict__ src, float* __restrict__ dst) {
    const int i = blockIdx.x * 256 + threadIdx.x;
    const int rowd = i >> 7, d = i & 127;
    const int sq = rowd >> 8, n = rowd & 255, b = sq >> 3;
    dst[i] = src[((size_t)(b * 256 + n)) * DD + d];
}

// out[row] = Y[row,:] . W3 + b3
__global__ __launch_bounds__(64) void final_dot_kernel(
    const float* __restrict__ Y, const void* __restrict__ W3,
    const void* __restrict__ b3, void* __restrict__ out,
    const int* __restrict__ flagp) {
    const int isf32 = *flagp;
    const int row = blockIdx.x, lid = threadIdx.x;
    const float* yp = Y + (size_t)row * DD;
    float v = yp[lid] * ldx(W3, lid, isf32) + yp[lid + 64] * ldx(W3, (size_t)lid + 64, isf32);
#pragma unroll
    for (int o = 1; o < 64; o <<= 1) v += __shfl_xor(v, o);
    if (lid == 0) {
        const float r = v + ldx(b3, 0, isf32);
        if (isf32) ((float*)out)[row] = r;
        else ((unsigned short*)out)[row] = f2bf(r);
    }
}

// ---------------------------------------------------------------------------

extern "C" void kernel_launch(void* const* d_in, const int* in_sizes, int n_in,
                              void* d_out, int out_size, void* d_ws, size_t ws_size,
                              hipStream_t stream) {
    // diagnostic sentinels: 2000 -> input layout mismatch, 1000 -> ws too small
    bool ok = (n_in >= 29) && in_sizes[0] == 12288 && in_sizes[1] == 4718592 &&
              in_sizes[2] == 1310720 && in_sizes[7] == 147456 &&
              in_sizes[13] == 98304 && in_sizes[25] == 1024 && in_sizes[27] == 128;
    if (!ok) {
        sentinel_kernel<<<(out_size + 255) / 256, 256, 0, stream>>>(
            (unsigned short*)d_out, out_size, 0x44FA);  // bf16(2000)
        return;
    }
    const size_t SZ = (size_t)32768 * 128;
    const size_t NEED = (16384ull + 2ull * SZ + 2ull * 10240 * 128) * 4ull;  // 44,105,728
    if (ws_size < NEED) {
        sentinel_kernel<<<(out_size + 255) / 256, 256, 0, stream>>>(
            (unsigned short*)d_out, out_size, 0x447A);  // bf16(1000)
        return;
    }

    const void* center = d_in[0];
    const void* detr   = d_in[1];
    const void* lang   = d_in[2];
    const void* fc1_W  = d_in[7];
    const void* fc1_b  = d_in[8];
    const void* bn0    = d_in[9];
    const void* prelu0 = d_in[10];
    const void* fc2_W  = d_in[11];
    const void* fc2_b  = d_in[12];
    const void* s_qkv  = d_in[13];
    const void* s_qkvb = d_in[14];
    const void* s_Wo   = d_in[15];
    const void* s_bo   = d_in[16];
    const void* s_ln   = d_in[17];
    const void* c_qkv  = d_in[18];
    const void* c_qkvb = d_in[19];
    const void* c_Wo   = d_in[20];
    const void* c_bo   = d_in[21];
    const void* c_ln   = d_in[22];
    const void* m_W    = d_in[23];
    const void* m_b    = d_in[24];
    const void* m_bn   = d_in[25];
    const void* m_al   = d_in[26];
    const void* m_W3   = d_in[27];
    const void* m_b3   = d_in[28];

    float* wsf  = (float*)d_ws;
    int*   flag = (int*)d_ws;
    float* rs   = wsf + 4096;
    float* X    = wsf + 16384;
    float* VO   = X + SZ;
    float* Kc   = VO + SZ;
    float* Vc   = Kc + (size_t)10240 * 128;

    detect_kernel<<<1, 256, 0, stream>>>((const unsigned short*)center, flag);
    rowsum_kernel<<<16, 256, 0, stream>>>(center, rs, flag);

    // fc1 (+BN+PReLU per-channel) -> VO[0:4096); fc2 -> X[0:4096) = x0
    gemm128_kernel<<<256, 256, 0, stream>>>(detr, 1, fc1_W, 0, fc1_b, 0, VO, 4096, 1152, 1,
                                            bn0, 0, prelu0, 0, 1, flag);
    gemm128_kernel<<<256, 256, 0, stream>>>(VO, 0, fc2_W, 0, fc2_b, 0, X, 4096, 128, 0,
                                            nullptr, 0, nullptr, 0, 0, flag);

    // self block 0 (16 seqs): V = X@Wv -> VO; attn (fused Q,K) O in-place VO;
    // post-LN (residual X) -> VO (= x1)
    gemm128_kernel<<<256, 256, 0, stream>>>(X, 0, s_qkv, 2 * WMAT, s_qkvb, 256, VO, 4096, 128, 0,
                                            nullptr, 0, nullptr, 0, 0, flag);
    attn_kernel<<<dim3(16, 4), 256, 0, stream>>>(X, VO, nullptr, s_qkv, 0, WMAT, s_qkvb, 0, 128,
                                                 VO, center, rs, flag, 256, 1, 1);
    proj_ln_kernel<<<4096, 128, 0, stream>>>(X, VO, s_Wo, 0, s_bo, 0, s_ln, 0, VO, flag);

    // broadcast x1 (VO, 4096 rows) -> X (32768 rows) = f1_0
    bcast_kernel<<<16384, 256, 0, stream>>>(VO, X);

    // cross block 0: K,V from lang -> Kc,Vc; attn (fused Q) -> VO; LN -> X
    gemm128_kernel<<<640, 256, 0, stream>>>(lang, 1, c_qkv, WMAT, c_qkvb, 128, Kc, 10240, 128, 0,
                                            nullptr, 0, nullptr, 0, 0, flag);
    gemm128_kernel<<<640, 256, 0, stream>>>(lang, 1, c_qkv, 2 * WMAT, c_qkvb, 256, Vc, 10240, 128, 0,
                                            nullptr, 0, nullptr, 0, 0, flag);
    attn_kernel<<<dim3(128, 4), 256, 0, stream>>>(X, Vc, Kc, c_qkv, 0, 0, c_qkvb, 0, 0,
                                                  VO, nullptr, nullptr, flag, 80, 0, 1);
    proj_ln_kernel<<<32768, 128, 0, stream>>>(X, VO, c_Wo, 0, c_bo, 0, c_ln, 0, X, flag);

    // self block 1 (128 seqs, bias with b = s/8)
    gemm128_kernel<<<2048, 256, 0, stream>>>(X, 0, s_qkv, 5 * WMAT, s_qkvb, 640, VO, 32768, 128, 0,
                                             nullptr, 0, nullptr, 0, 0, flag);
    attn_kernel<<<dim3(128, 4), 256, 0, stream>>>(X, VO, nullptr, s_qkv, 3 * WMAT, 4 * WMAT,
                                                  s_qkvb, 384, 512, VO, center, rs, flag, 256, 1, 8);
    proj_ln_kernel<<<32768, 128, 0, stream>>>(X, VO, s_Wo, WMAT, s_bo, 128, s_ln, 256, X, flag);

    // cross block 1
    gemm128_kernel<<<640, 256, 0, stream>>>(lang, 1, c_qkv, 4 * WMAT, c_qkvb, 512, Kc, 10240, 128, 0,
                                            nullptr, 0, nullptr, 0, 0, flag);
    gemm128_kernel<<<640, 256, 0, stream>>>(lang, 1, c_qkv, 5 * WMAT, c_qkvb, 640, Vc, 10240, 128, 0,
                                            nullptr, 0, nullptr, 0, 0, flag);
    attn_kernel<<<dim3(128, 4), 256, 0, stream>>>(X, Vc, Kc, c_qkv, 3 * WMAT, 0, c_qkvb, 384, 0,
                                                  VO, nullptr, nullptr, flag, 80, 0, 1);
    proj_ln_kernel<<<32768, 128, 0, stream>>>(X, VO, c_Wo, WMAT, c_bo, 128, c_ln, 256, X, flag);

    // match head
    gemm128_kernel<<<2048, 256, 0, stream>>>(X, 0, m_W, 0, m_b, 0, VO, 32768, 128, 1,
                                             m_bn, 0, m_al, 0, 0, flag);
    gemm128_kernel<<<2048, 256, 0, stream>>>(VO, 0, m_W, WMAT, m_b, 128, X, 32768, 128, 1,
                                             m_bn, 512, m_al, 1, 0, flag);
    final_dot_kernel<<<32768, 64, 0, stream>>>(X, m_W3, m_b3, d_out, flag);
}

// Round 6
// 1324.355 us; speedup vs baseline: 1.2934x; 1.2934x over previous
//
#include <hip/hip_runtime.h>

// ---------------------------------------------------------------------------
// MatchModule forward. H=4 D=128 B=16 K=256 M=8 L=80 DET_C=1152, dk=32.
// All intermediates f32 in d_ws. External inputs read via runtime dtype flag
// (0 = bf16, 1 = f32) detected on-device. Output store also flag-branched.
//
// R5: attention rewritten — single-pass chunked flash softmax (j-chunks of 8,
// 4-way partial-sum dots), swizzled K tile (16B XOR), W-stage aliased into sK
// (LDS 53->36 KB), __launch_bounds__(256,2); GEMM/LN dtype branch hoisted to
// templated bodies; proj_ln does 8 rows/block (Wo L2 traffic /8).
// (R6: byte-identical resubmission — R5 got UnresponsiveContainer, no verdict.)
//
// ws layout (floats): [flag int @0 | pad | rowsum @4096 | X @16384 |
//                      VO @16384+SZ | Kc @16384+2SZ | Vc @+10240*128]
// SZ = 32768*128.  Total = 44,105,728 bytes (42.1 MiB).
// ---------------------------------------------------------------------------

#define DD 128
#define WMAT 16384

__device__ __forceinline__ float bf2f(unsigned short u) {
    union { unsigned int i; float f; } v; v.i = ((unsigned int)u) << 16; return v.f;
}
__device__ __forceinline__ unsigned short f2bf(float f) {
    union { float f; unsigned int i; } v; v.f = f;
    unsigned int x = v.i;
    return (unsigned short)((x + 0x7FFFu + ((x >> 16) & 1u)) >> 16);
}
__device__ __forceinline__ float ldx(const void* p, size_t i, int isf32) {
    return isf32 ? ((const float*)p)[i] : bf2f(((const unsigned short*)p)[i]);
}

// ---------------------------------------------------------------------------
__global__ __launch_bounds__(256) void detect_kernel(
    const unsigned short* __restrict__ c, int* __restrict__ flag) {
    __shared__ int cnt;
    if (threadIdx.x == 0) cnt = 0;
    __syncthreads();
    float v = bf2f(c[threadIdx.x]);
    int sane = (v == v) && (fabsf(v) <= 1e4f) && (v == 0.f || fabsf(v) >= 1e-10f);
    atomicAdd(&cnt, sane);
    __syncthreads();
    if (threadIdx.x == 0) flag[0] = (cnt >= 224) ? 0 : 1;  // 0=bf16, 1=f32
}

__global__ void sentinel_kernel(unsigned short* out, int n, int val) {
    int i = blockIdx.x * 256 + threadIdx.x;
    if (i < n) out[i] = (unsigned short)val;
}

// ---------------------------------------------------------------------------
// rowsum[b,i] = sum_j 1/(dist(b,i,j)+0.01)  (dist symmetric -> also col sum)
// ---------------------------------------------------------------------------
__global__ __launch_bounds__(256) void rowsum_kernel(
    const void* __restrict__ center, float* __restrict__ rs,
    const int* __restrict__ flagp) {
    const int isf32 = *flagp;
    const int b = blockIdx.x, i = threadIdx.x;
    __shared__ float c[768];
    for (int idx = i; idx < 768; idx += 256) c[idx] = ldx(center, (size_t)b * 768 + idx, isf32);
    __syncthreads();
    const float cx = c[i * 3], cy = c[i * 3 + 1], cz = c[i * 3 + 2];
    float s = 0.f;
    for (int j = 0; j < 256; ++j) {
        float dx = cx - c[j * 3], dy = cy - c[j * 3 + 1], dz = cz - c[j * 3 + 2];
        s += 1.f / (sqrtf(dx * dx + dy * dy + dz * dz) + 0.01f);
    }
    rs[b * 256 + i] = s;
}

// ---------------------------------------------------------------------------
// GEMM body, dtype-specialized at compile time; runtime flag picks variant.
// 256 thr = 128 cols x 2 row-groups, 8 rows/thread.
// ---------------------------------------------------------------------------
template <bool AF32, bool WF32>
__device__ __forceinline__ void gemm_body(
    const void* __restrict__ A, const void* __restrict__ W, int wOff,
    const void* __restrict__ bias, int bOff, float* __restrict__ out,
    int nrows, int Kdim, int epi, const void* __restrict__ bn, int bnOff,
    const void* __restrict__ alpha, int aOff, int alpha_pc, int isf32) {
    const int d = threadIdx.x & 127, rg = threadIdx.x >> 7;
    const int r0 = blockIdx.x * 16 + rg * 8;
    if (r0 >= nrows) return;
    float acc[8] = {0.f, 0.f, 0.f, 0.f, 0.f, 0.f, 0.f, 0.f};
    const float* Af = (const float*)A;
    const unsigned short* Au = (const unsigned short*)A;
    const float* Wf = (const float*)W + wOff;
    const unsigned short* Wu = (const unsigned short*)W + wOff;
    for (int k = 0; k < Kdim; k += 4) {
        float w0, w1, w2, w3;
        if (WF32) {
            w0 = Wf[(size_t)(k + 0) * DD + d]; w1 = Wf[(size_t)(k + 1) * DD + d];
            w2 = Wf[(size_t)(k + 2) * DD + d]; w3 = Wf[(size_t)(k + 3) * DD + d];
        } else {
            w0 = bf2f(Wu[(size_t)(k + 0) * DD + d]); w1 = bf2f(Wu[(size_t)(k + 1) * DD + d]);
            w2 = bf2f(Wu[(size_t)(k + 2) * DD + d]); w3 = bf2f(Wu[(size_t)(k + 3) * DD + d]);
        }
#pragma unroll
        for (int r = 0; r < 8; ++r) {
            const size_t base = (size_t)(r0 + r) * Kdim + k;
            float a0, a1, a2, a3;
            if (AF32) {
                const float4 t = *reinterpret_cast<const float4*>(Af + base);
                a0 = t.x; a1 = t.y; a2 = t.z; a3 = t.w;
            } else {
                const ushort4 t = *reinterpret_cast<const ushort4*>(Au + base);
                a0 = bf2f(t.x); a1 = bf2f(t.y); a2 = bf2f(t.z); a3 = bf2f(t.w);
            }
            acc[r] = fmaf(a0, w0, fmaf(a1, w1, fmaf(a2, w2, fmaf(a3, w3, acc[r]))));
        }
    }
    const float bs = ldx(bias, (size_t)bOff + d, isf32);
    float g = 1.f, bb = 0.f, mm = 0.f, rinv = 1.f, al = 0.f;
    if (epi) {
        g  = ldx(bn, (size_t)bnOff + d, isf32);
        bb = ldx(bn, (size_t)bnOff + DD + d, isf32);
        mm = ldx(bn, (size_t)bnOff + 2 * DD + d, isf32);
        rinv = rsqrtf(ldx(bn, (size_t)bnOff + 3 * DD + d, isf32) + 1e-5f);
        al = alpha_pc ? ldx(alpha, (size_t)aOff + d, isf32) : ldx(alpha, (size_t)aOff, isf32);
    }
#pragma unroll
    for (int r = 0; r < 8; ++r) {
        float v = acc[r] + bs;
        if (epi) {
            v = g * (v - mm) * rinv + bb;
            v = (v >= 0.f) ? v : al * v;
        }
        out[(size_t)(r0 + r) * DD + d] = v;
    }
}

__global__ __launch_bounds__(256) void gemm128_kernel(
    const void* __restrict__ A, int aExt,
    const void* __restrict__ W, int wOff,
    const void* __restrict__ bias, int bOff,
    float* __restrict__ out, int nrows, int Kdim, int epi,
    const void* __restrict__ bn, int bnOff,
    const void* __restrict__ alpha, int aOff, int alpha_pc,
    const int* __restrict__ flagp) {
    const int isf32 = *flagp;
    if (isf32) gemm_body<true, true>(A, W, wOff, bias, bOff, out, nrows, Kdim, epi, bn, bnOff, alpha, aOff, alpha_pc, 1);
    else if (aExt) gemm_body<false, false>(A, W, wOff, bias, bOff, out, nrows, Kdim, epi, bn, bnOff, alpha, aOff, alpha_pc, 0);
    else gemm_body<true, false>(A, W, wOff, bias, bOff, out, nrows, Kdim, epi, bn, bnOff, alpha, aOff, alpha_pc, 0);
}

// ---------------------------------------------------------------------------
// Fused projection helper: r[0:32] += sum_k x[k] * sW[k*32 + i]
// ---------------------------------------------------------------------------
#define PROJ_STEP(XS, KK)                                                     \
    {                                                                         \
        const float xs = (XS);                                                \
        const float4* w = (const float4*)(sW + (k4 * 4 + (KK)) * 32);         \
        _Pragma("unroll") for (int c = 0; c < 8; ++c) {                       \
            const float4 wv = w[c];                                           \
            r[4 * c]     = fmaf(xs, wv.x, r[4 * c]);                          \
            r[4 * c + 1] = fmaf(xs, wv.y, r[4 * c + 1]);                      \
            r[4 * c + 2] = fmaf(xs, wv.z, r[4 * c + 2]);                      \
            r[4 * c + 3] = fmaf(xs, wv.w, r[4 * c + 3]);                      \
        }                                                                     \
    }

__device__ __forceinline__ void proj_accum(float* r, const float* xq, const float* sW) {
    const float4* x4 = (const float4*)xq;
    for (int k4 = 0; k4 < 32; ++k4) {
        const float4 xv = x4[k4];
        PROJ_STEP(xv.x, 0)
        PROJ_STEP(xv.y, 1)
        PROJ_STEP(xv.z, 2)
        PROJ_STEP(xv.w, 3)
    }
}

// ---------------------------------------------------------------------------
// Attention, block = (seq s, head h), 256 threads = 256 query rows.
// Single-pass online softmax in j-chunks of 8. Q (and for SELF also K)
// projection fused, W slice staged into the first 16 KB of sK. K tile kept
// swizzled (16B XOR by row&7) to break store bank conflicts; reads are
// wave-broadcast. SELF: V from Vg, O written IN PLACE over Vg (block-private
// (rows of s) x (cols of h) region; barrier before store).
// Self bias: h0 = (1/(d+.01))/rowsum[key], h1 = -d, h2/3 = 0.
// ---------------------------------------------------------------------------
template <int SELF>
__global__ __launch_bounds__(256, 2) void attn_kernel(
    const float* __restrict__ X, const float* __restrict__ Vg,
    const float* __restrict__ Kc,
    const void* __restrict__ Wqkv, int wqOff, int wkOff,
    const void* __restrict__ bqkv, int bqOff, int bkOff,
    float* __restrict__ O,
    const void* __restrict__ center, const float* __restrict__ rs,
    const int* __restrict__ flagp, int nk, int bDiv) {
    __shared__ float sK[8192];              // 32 KB; first 4 K floats = W stage
    __shared__ float sC[SELF ? 768 : 1];
    __shared__ float sR[SELF ? 256 : 1];
    const int isf32 = *flagp;
    const int s = blockIdx.x, h = blockIdx.y, q = threadIdx.x;
    const int hc = h * 32;

    // ---- stage Wq into sK[0:4096] (+ center/rowsum for SELF) ----
    for (int idx = q; idx < 4096; idx += 256) {
        const int k = idx >> 5, i = idx & 31;
        sK[idx] = ldx(Wqkv, (size_t)wqOff + (size_t)k * DD + hc + i, isf32);
    }
    if (SELF) {
        const int bb = s / bDiv;
        for (int idx = q; idx < 768; idx += 256)
            sC[idx] = ldx(center, (size_t)bb * 768 + idx, isf32);
        sR[q] = 1.0f / rs[bb * 256 + q];    // store reciprocal
    }
    __syncthreads();

    // ---- fused Q projection ----
    float qr[32];
#pragma unroll
    for (int i = 0; i < 32; ++i) qr[i] = ldx(bqkv, (size_t)bqOff + hc + i, isf32);
    const float* xq = X + (size_t)(s * 256 + q) * DD;
    proj_accum(qr, xq, sK);
    __syncthreads();                        // done reading Wq

    if (SELF) {
        // stage Wk, project K, store swizzled K tile
        for (int idx = q; idx < 4096; idx += 256) {
            const int k = idx >> 5, i = idx & 31;
            sK[idx] = ldx(Wqkv, (size_t)wkOff + (size_t)k * DD + hc + i, isf32);
        }
        __syncthreads();
        float kr[32];
#pragma unroll
        for (int i = 0; i < 32; ++i) kr[i] = ldx(bqkv, (size_t)bkOff + hc + i, isf32);
        proj_accum(kr, xq, sK);
        __syncthreads();                    // all reads of Wk done
#pragma unroll
        for (int c = 0; c < 8; ++c) {
            float4 v; v.x = kr[4 * c]; v.y = kr[4 * c + 1]; v.z = kr[4 * c + 2]; v.w = kr[4 * c + 3];
            *(float4*)((char*)sK + q * 128 + ((c * 16) ^ ((q & 7) << 4))) = v;
        }
        __syncthreads();
    } else {
        // stage K tile from global Kc (swizzled)
        for (int idx = q; idx < nk * 32; idx += 256) {
            const int j = idx >> 5, i = idx & 31, c = i >> 2, w = i & 3;
            const int byte = j * 128 + ((c * 16) ^ ((j & 7) << 4)) + w * 4;
            *(float*)((char*)sK + byte) = Kc[((size_t)(s * nk + j)) * DD + hc + i];
        }
        __syncthreads();
    }

    float cx = 0.f, cy = 0.f, cz = 0.f;
    if (SELF) { cx = sC[q * 3]; cy = sC[q * 3 + 1]; cz = sC[q * 3 + 2]; }
    const float scale = 0.17677669529663687f;  // 1/sqrt(32)

    // ---- single-pass flash, chunks of 8 keys ----
    float m = -3.0e38f, l = 0.f;
    float acc[32];
#pragma unroll
    for (int i = 0; i < 32; ++i) acc[i] = 0.f;

    for (int j0 = 0; j0 < nk; j0 += 8) {
        float sc[8];
#pragma unroll
        for (int u = 0; u < 8; ++u) {
            const int j = j0 + u;
            const char* kb = (const char*)sK + j * 128;
            const int sw = (j & 7) << 4;
            float d0 = 0.f, d1 = 0.f, d2 = 0.f, d3 = 0.f;
#pragma unroll
            for (int c = 0; c < 8; ++c) {
                const float4 kv = *(const float4*)(kb + ((c * 16) ^ sw));
                d0 = fmaf(qr[4 * c], kv.x, d0);
                d1 = fmaf(qr[4 * c + 1], kv.y, d1);
                d2 = fmaf(qr[4 * c + 2], kv.z, d2);
                d3 = fmaf(qr[4 * c + 3], kv.w, d3);
            }
            float v = ((d0 + d1) + (d2 + d3)) * scale;
            if (SELF) {
                const float dx = cx - sC[j * 3], dy = cy - sC[j * 3 + 1], dz = cz - sC[j * 3 + 2];
                const float dist = sqrtf(dx * dx + dy * dy + dz * dz);
                if (h == 0) v += __fdividef(1.f, dist + 0.01f) * sR[j];
                else if (h == 1) v -= dist;
            }
            sc[u] = v;
        }
        const float cmax = fmaxf(fmaxf(fmaxf(sc[0], sc[1]), fmaxf(sc[2], sc[3])),
                                 fmaxf(fmaxf(sc[4], sc[5]), fmaxf(sc[6], sc[7])));
        if (cmax > m) {
            const float f = __expf(m - cmax);
            l *= f;
#pragma unroll
            for (int i = 0; i < 32; ++i) acc[i] *= f;
            m = cmax;
        }
#pragma unroll
        for (int u = 0; u < 8; ++u) {
            const float p = __expf(sc[u] - m);
            l += p;
            const float4* vp = (const float4*)(Vg + ((size_t)(s * nk + j0 + u)) * DD + hc);
#pragma unroll
            for (int c = 0; c < 8; ++c) {
                const float4 vv = vp[c];
                acc[4 * c]     = fmaf(p, vv.x, acc[4 * c]);
                acc[4 * c + 1] = fmaf(p, vv.y, acc[4 * c + 1]);
                acc[4 * c + 2] = fmaf(p, vv.z, acc[4 * c + 2]);
                acc[4 * c + 3] = fmaf(p, vv.w, acc[4 * c + 3]);
            }
        }
    }
    __syncthreads();   // all V reads complete before in-place O store
    const float inv = 1.f / l;
    float4* op = (float4*)(O + ((size_t)(s * 256 + q)) * DD + hc);
#pragma unroll
    for (int c = 0; c < 8; ++c) {
        float4 t;
        t.x = acc[4 * c] * inv; t.y = acc[4 * c + 1] * inv;
        t.z = acc[4 * c + 2] * inv; t.w = acc[4 * c + 3] * inv;
        op[c] = t;
    }
}

// ---------------------------------------------------------------------------
// Y[row] = LayerNorm(X[row] + O[row] @ Wo + bo); 8 rows per block (Wo reuse).
// Y may alias X or O (row-local).
// ---------------------------------------------------------------------------
template <bool WF32>
__device__ __forceinline__ void ln_body(
    const float* __restrict__ X, const float* __restrict__ O,
    const void* __restrict__ Wo, int woOff, const void* __restrict__ bo, int boOff,
    const void* __restrict__ ln, int lnOff, float* __restrict__ Y, int isf32,
    float* sO, float* red1, float* red2) {
    const int d = threadIdx.x;
    const int row0 = blockIdx.x * 8;
#pragma unroll
    for (int r = 0; r < 8; ++r) sO[r * DD + d] = O[(size_t)(row0 + r) * DD + d];
    const float gam = ldx(ln, (size_t)lnOff + d, isf32);
    const float bet = ldx(ln, (size_t)lnOff + DD + d, isf32);
    const float bov = ldx(bo, (size_t)boOff + d, isf32);
    const float* Wf = (const float*)Wo + woOff;
    const unsigned short* Wu = (const unsigned short*)Wo + woOff;
    __syncthreads();
    for (int r = 0; r < 8; ++r) {
        float acc = 0.f;
#pragma unroll 4
        for (int k = 0; k < DD; ++k) {
            const float w = WF32 ? Wf[(size_t)k * DD + d] : bf2f(Wu[(size_t)k * DD + d]);
            acc = fmaf(sO[r * DD + k], w, acc);
        }
        const float v = X[(size_t)(row0 + r) * DD + d] + acc + bov;
        float s1 = v, s2 = v * v;
#pragma unroll
        for (int o = 1; o < 64; o <<= 1) { s1 += __shfl_xor(s1, o); s2 += __shfl_xor(s2, o); }
        if ((d & 63) == 0) { red1[d >> 6] = s1; red2[d >> 6] = s2; }
        __syncthreads();
        const float S1 = red1[0] + red1[1], S2 = red2[0] + red2[1];
        const float mu = S1 * (1.f / 128.f);
        const float var = S2 * (1.f / 128.f) - mu * mu;
        Y[(size_t)(row0 + r) * DD + d] = gam * (v - mu) * rsqrtf(var + 1e-5f) + bet;
        __syncthreads();
    }
}

__global__ __launch_bounds__(128) void proj_ln_kernel(
    const float* __restrict__ X, const float* __restrict__ O,
    const void* __restrict__ Wo, int woOff, const void* __restrict__ bo, int boOff,
    const void* __restrict__ ln, int lnOff, float* __restrict__ Y,
    const int* __restrict__ flagp) {
    __shared__ float sO[8 * DD];
    __shared__ float red1[2], red2[2];
    const int isf32 = *flagp;
    if (isf32) ln_body<true>(X, O, Wo, woOff, bo, boOff, ln, lnOff, Y, 1, sO, red1, red2);
    else       ln_body<false>(X, O, Wo, woOff, bo, boOff, ln, lnOff, Y, 0, sO, red1, red2);
}

// f1_0[(b*M+m)*256+n, d] = x1[b*256+n, d]
__global__ __launch_bounds__(256) void bcast_kernel(
    const float* __restrict__ src, float* __restrict__ dst) {
    const int i = blockIdx.x * 256 + threadIdx.x;
    const int rowd = i >> 7, d = i & 127;
    const int sq = rowd >> 8, n = rowd & 255, b = sq >> 3;
    dst[i] = src[((size_t)(b * 256 + n)) * DD + d];
}

// out[row] = Y[row,:] . W3 + b3
__global__ __launch_bounds__(64) void final_dot_kernel(
    const float* __restrict__ Y, const void* __restrict__ W3,
    const void* __restrict__ b3, void* __restrict__ out,
    const int* __restrict__ flagp) {
    const int isf32 = *flagp;
    const int row = blockIdx.x, lid = threadIdx.x;
    const float* yp = Y + (size_t)row * DD;
    float v = yp[lid] * ldx(W3, lid, isf32) + yp[lid + 64] * ldx(W3, (size_t)lid + 64, isf32);
#pragma unroll
    for (int o = 1; o < 64; o <<= 1) v += __shfl_xor(v, o);
    if (lid == 0) {
        const float r = v + ldx(b3, 0, isf32);
        if (isf32) ((float*)out)[row] = r;
        else ((unsigned short*)out)[row] = f2bf(r);
    }
}

// ---------------------------------------------------------------------------

extern "C" void kernel_launch(void* const* d_in, const int* in_sizes, int n_in,
                              void* d_out, int out_size, void* d_ws, size_t ws_size,
                              hipStream_t stream) {
    bool ok = (n_in >= 29) && in_sizes[0] == 12288 && in_sizes[1] == 4718592 &&
              in_sizes[2] == 1310720 && in_sizes[7] == 147456 &&
              in_sizes[13] == 98304 && in_sizes[25] == 1024 && in_sizes[27] == 128;
    if (!ok) {
        sentinel_kernel<<<(out_size + 255) / 256, 256, 0, stream>>>(
            (unsigned short*)d_out, out_size, 0x44FA);  // bf16(2000)
        return;
    }
    const size_t SZ = (size_t)32768 * 128;
    const size_t NEED = (16384ull + 2ull * SZ + 2ull * 10240 * 128) * 4ull;
    if (ws_size < NEED) {
        sentinel_kernel<<<(out_size + 255) / 256, 256, 0, stream>>>(
            (unsigned short*)d_out, out_size, 0x447A);  // bf16(1000)
        return;
    }

    const void* center = d_in[0];
    const void* detr   = d_in[1];
    const void* lang   = d_in[2];
    const void* fc1_W  = d_in[7];
    const void* fc1_b  = d_in[8];
    const void* bn0    = d_in[9];
    const void* prelu0 = d_in[10];
    const void* fc2_W  = d_in[11];
    const void* fc2_b  = d_in[12];
    const void* s_qkv  = d_in[13];
    const void* s_qkvb = d_in[14];
    const void* s_Wo   = d_in[15];
    const void* s_bo   = d_in[16];
    const void* s_ln   = d_in[17];
    const void* c_qkv  = d_in[18];
    const void* c_qkvb = d_in[19];
    const void* c_Wo   = d_in[20];
    const void* c_bo   = d_in[21];
    const void* c_ln   = d_in[22];
    const void* m_W    = d_in[23];
    const void* m_b    = d_in[24];
    const void* m_bn   = d_in[25];
    const void* m_al   = d_in[26];
    const void* m_W3   = d_in[27];
    const void* m_b3   = d_in[28];

    float* wsf  = (float*)d_ws;
    int*   flag = (int*)d_ws;
    float* rs   = wsf + 4096;
    float* X    = wsf + 16384;
    float* VO   = X + SZ;
    float* Kc   = VO + SZ;
    float* Vc   = Kc + (size_t)10240 * 128;

    detect_kernel<<<1, 256, 0, stream>>>((const unsigned short*)center, flag);
    rowsum_kernel<<<16, 256, 0, stream>>>(center, rs, flag);

    // fc1 (+BN+PReLU per-channel) -> VO[0:4096); fc2 -> X[0:4096) = x0
    gemm128_kernel<<<256, 256, 0, stream>>>(detr, 1, fc1_W, 0, fc1_b, 0, VO, 4096, 1152, 1,
                                            bn0, 0, prelu0, 0, 1, flag);
    gemm128_kernel<<<256, 256, 0, stream>>>(VO, 0, fc2_W, 0, fc2_b, 0, X, 4096, 128, 0,
                                            nullptr, 0, nullptr, 0, 0, flag);

    // self block 0 (16 seqs): V -> VO; attn (fused Q,K) O in-place VO; LN -> VO
    gemm128_kernel<<<256, 256, 0, stream>>>(X, 0, s_qkv, 2 * WMAT, s_qkvb, 256, VO, 4096, 128, 0,
                                            nullptr, 0, nullptr, 0, 0, flag);
    attn_kernel<1><<<dim3(16, 4), 256, 0, stream>>>(X, VO, nullptr, s_qkv, 0, WMAT, s_qkvb, 0, 128,
                                                    VO, center, rs, flag, 256, 1);
    proj_ln_kernel<<<512, 128, 0, stream>>>(X, VO, s_Wo, 0, s_bo, 0, s_ln, 0, VO, flag);

    // broadcast x1 (VO, 4096 rows) -> X (32768 rows) = f1_0
    bcast_kernel<<<16384, 256, 0, stream>>>(VO, X);

    // cross block 0: K,V from lang -> Kc,Vc; attn (fused Q) -> VO; LN -> X
    gemm128_kernel<<<640, 256, 0, stream>>>(lang, 1, c_qkv, WMAT, c_qkvb, 128, Kc, 10240, 128, 0,
                                            nullptr, 0, nullptr, 0, 0, flag);
    gemm128_kernel<<<640, 256, 0, stream>>>(lang, 1, c_qkv, 2 * WMAT, c_qkvb, 256, Vc, 10240, 128, 0,
                                            nullptr, 0, nullptr, 0, 0, flag);
    attn_kernel<0><<<dim3(128, 4), 256, 0, stream>>>(X, Vc, Kc, c_qkv, 0, 0, c_qkvb, 0, 0,
                                                     VO, nullptr, nullptr, flag, 80, 1);
    proj_ln_kernel<<<4096, 128, 0, stream>>>(X, VO, c_Wo, 0, c_bo, 0, c_ln, 0, X, flag);

    // self block 1 (128 seqs, bias with b = s/8)
    gemm128_kernel<<<2048, 256, 0, stream>>>(X, 0, s_qkv, 5 * WMAT, s_qkvb, 640, VO, 32768, 128, 0,
                                             nullptr, 0, nullptr, 0, 0, flag);
    attn_kernel<1><<<dim3(128, 4), 256, 0, stream>>>(X, VO, nullptr, s_qkv, 3 * WMAT, 4 * WMAT,
                                                     s_qkvb, 384, 512, VO, center, rs, flag, 256, 8);
    proj_ln_kernel<<<4096, 128, 0, stream>>>(X, VO, s_Wo, WMAT, s_bo, 128, s_ln, 256, X, flag);

    // cross block 1
    gemm128_kernel<<<640, 256, 0, stream>>>(lang, 1, c_qkv, 4 * WMAT, c_qkvb, 512, Kc, 10240, 128, 0,
                                            nullptr, 0, nullptr, 0, 0, flag);
    gemm128_kernel<<<640, 256, 0, stream>>>(lang, 1, c_qkv, 5 * WMAT, c_qkvb, 640, Vc, 10240, 128, 0,
                                            nullptr, 0, nullptr, 0, 0, flag);
    attn_kernel<0><<<dim3(128, 4), 256, 0, stream>>>(X, Vc, Kc, c_qkv, 3 * WMAT, 0, c_qkvb, 384, 0,
                                                     VO, nullptr, nullptr, flag, 80, 1);
    proj_ln_kernel<<<4096, 128, 0, stream>>>(X, VO, c_Wo, WMAT, c_bo, 128, c_ln, 256, X, flag);

    // match head
    gemm128_kernel<<<2048, 256, 0, stream>>>(X, 0, m_W, 0, m_b, 0, VO, 32768, 128, 1,
                                             m_bn, 0, m_al, 0, 0, flag);
    gemm128_kernel<<<2048, 256, 0, stream>>>(VO, 0, m_W, WMAT, m_b, 128, X, 32768, 128, 1,
                                             m_bn, 512, m_al, 1, 0, flag);
    final_dot_kernel<<<32768, 64, 0, stream>>>(X, m_W3, m_b3, d_out, flag);
}

// Round 7
// 1230.908 us; speedup vs baseline: 1.3916x; 1.0759x over previous
//
#include <hip/hip_runtime.h>

// ---------------------------------------------------------------------------
// MatchModule forward. H=4 D=128 B=16 K=256 M=8 L=80 DET_C=1152, dk=32.
// All intermediates f32 in d_ws. External inputs read via runtime dtype flag
// (0 = bf16, 1 = f32) detected on-device. Output store also flag-branched.
//
// R7: attention split-pair restructure — 512 threads/block, each query row
// owned by a lane PAIR (e = tid&1 selects a 16-float half of the 32-dim head).
// Halves per-thread critical path, doubles waves/CU (8->16 on big grids).
// Score = own 16-dot + __shfl_xor(.,1). All else (swizzled K tile, fused Q/K
// projection, single-pass flash) as R6.
//
// ws layout (floats): [flag int @0 | pad | rowsum @4096 | X @16384 |
//                      VO @16384+SZ | Kc @16384+2SZ | Vc @+10240*128]
// SZ = 32768*128.  Total = 44,105,728 bytes (42.1 MiB).
// ---------------------------------------------------------------------------

#define DD 128
#define WMAT 16384

__device__ __forceinline__ float bf2f(unsigned short u) {
    union { unsigned int i; float f; } v; v.i = ((unsigned int)u) << 16; return v.f;
}
__device__ __forceinline__ unsigned short f2bf(float f) {
    union { float f; unsigned int i; } v; v.f = f;
    unsigned int x = v.i;
    return (unsigned short)((x + 0x7FFFu + ((x >> 16) & 1u)) >> 16);
}
__device__ __forceinline__ float ldx(const void* p, size_t i, int isf32) {
    return isf32 ? ((const float*)p)[i] : bf2f(((const unsigned short*)p)[i]);
}

// ---------------------------------------------------------------------------
__global__ __launch_bounds__(256) void detect_kernel(
    const unsigned short* __restrict__ c, int* __restrict__ flag) {
    __shared__ int cnt;
    if (threadIdx.x == 0) cnt = 0;
    __syncthreads();
    float v = bf2f(c[threadIdx.x]);
    int sane = (v == v) && (fabsf(v) <= 1e4f) && (v == 0.f || fabsf(v) >= 1e-10f);
    atomicAdd(&cnt, sane);
    __syncthreads();
    if (threadIdx.x == 0) flag[0] = (cnt >= 224) ? 0 : 1;  // 0=bf16, 1=f32
}

__global__ void sentinel_kernel(unsigned short* out, int n, int val) {
    int i = blockIdx.x * 256 + threadIdx.x;
    if (i < n) out[i] = (unsigned short)val;
}

// ---------------------------------------------------------------------------
// rowsum[b,i] = sum_j 1/(dist(b,i,j)+0.01)  (dist symmetric -> also col sum)
// ---------------------------------------------------------------------------
__global__ __launch_bounds__(256) void rowsum_kernel(
    const void* __restrict__ center, float* __restrict__ rs,
    const int* __restrict__ flagp) {
    const int isf32 = *flagp;
    const int b = blockIdx.x, i = threadIdx.x;
    __shared__ float c[768];
    for (int idx = i; idx < 768; idx += 256) c[idx] = ldx(center, (size_t)b * 768 + idx, isf32);
    __syncthreads();
    const float cx = c[i * 3], cy = c[i * 3 + 1], cz = c[i * 3 + 2];
    float s = 0.f;
    for (int j = 0; j < 256; ++j) {
        float dx = cx - c[j * 3], dy = cy - c[j * 3 + 1], dz = cz - c[j * 3 + 2];
        s += 1.f / (sqrtf(dx * dx + dy * dy + dz * dz) + 0.01f);
    }
    rs[b * 256 + i] = s;
}

// ---------------------------------------------------------------------------
// GEMM body, dtype-specialized at compile time; runtime flag picks variant.
// 256 thr = 128 cols x 2 row-groups, 8 rows/thread.
// ---------------------------------------------------------------------------
template <bool AF32, bool WF32>
__device__ __forceinline__ void gemm_body(
    const void* __restrict__ A, const void* __restrict__ W, int wOff,
    const void* __restrict__ bias, int bOff, float* __restrict__ out,
    int nrows, int Kdim, int epi, const void* __restrict__ bn, int bnOff,
    const void* __restrict__ alpha, int aOff, int alpha_pc, int isf32) {
    const int d = threadIdx.x & 127, rg = threadIdx.x >> 7;
    const int r0 = blockIdx.x * 16 + rg * 8;
    if (r0 >= nrows) return;
    float acc[8] = {0.f, 0.f, 0.f, 0.f, 0.f, 0.f, 0.f, 0.f};
    const float* Af = (const float*)A;
    const unsigned short* Au = (const unsigned short*)A;
    const float* Wf = (const float*)W + wOff;
    const unsigned short* Wu = (const unsigned short*)W + wOff;
    for (int k = 0; k < Kdim; k += 4) {
        float w0, w1, w2, w3;
        if (WF32) {
            w0 = Wf[(size_t)(k + 0) * DD + d]; w1 = Wf[(size_t)(k + 1) * DD + d];
            w2 = Wf[(size_t)(k + 2) * DD + d]; w3 = Wf[(size_t)(k + 3) * DD + d];
        } else {
            w0 = bf2f(Wu[(size_t)(k + 0) * DD + d]); w1 = bf2f(Wu[(size_t)(k + 1) * DD + d]);
            w2 = bf2f(Wu[(size_t)(k + 2) * DD + d]); w3 = bf2f(Wu[(size_t)(k + 3) * DD + d]);
        }
#pragma unroll
        for (int r = 0; r < 8; ++r) {
            const size_t base = (size_t)(r0 + r) * Kdim + k;
            float a0, a1, a2, a3;
            if (AF32) {
                const float4 t = *reinterpret_cast<const float4*>(Af + base);
                a0 = t.x; a1 = t.y; a2 = t.z; a3 = t.w;
            } else {
                const ushort4 t = *reinterpret_cast<const ushort4*>(Au + base);
                a0 = bf2f(t.x); a1 = bf2f(t.y); a2 = bf2f(t.z); a3 = bf2f(t.w);
            }
            acc[r] = fmaf(a0, w0, fmaf(a1, w1, fmaf(a2, w2, fmaf(a3, w3, acc[r]))));
        }
    }
    const float bs = ldx(bias, (size_t)bOff + d, isf32);
    float g = 1.f, bb = 0.f, mm = 0.f, rinv = 1.f, al = 0.f;
    if (epi) {
        g  = ldx(bn, (size_t)bnOff + d, isf32);
        bb = ldx(bn, (size_t)bnOff + DD + d, isf32);
        mm = ldx(bn, (size_t)bnOff + 2 * DD + d, isf32);
        rinv = rsqrtf(ldx(bn, (size_t)bnOff + 3 * DD + d, isf32) + 1e-5f);
        al = alpha_pc ? ldx(alpha, (size_t)aOff + d, isf32) : ldx(alpha, (size_t)aOff, isf32);
    }
#pragma unroll
    for (int r = 0; r < 8; ++r) {
        float v = acc[r] + bs;
        if (epi) {
            v = g * (v - mm) * rinv + bb;
            v = (v >= 0.f) ? v : al * v;
        }
        out[(size_t)(r0 + r) * DD + d] = v;
    }
}

__global__ __launch_bounds__(256) void gemm128_kernel(
    const void* __restrict__ A, int aExt,
    const void* __restrict__ W, int wOff,
    const void* __restrict__ bias, int bOff,
    float* __restrict__ out, int nrows, int Kdim, int epi,
    const void* __restrict__ bn, int bnOff,
    const void* __restrict__ alpha, int aOff, int alpha_pc,
    const int* __restrict__ flagp) {
    const int isf32 = *flagp;
    if (isf32) gemm_body<true, true>(A, W, wOff, bias, bOff, out, nrows, Kdim, epi, bn, bnOff, alpha, aOff, alpha_pc, 1);
    else if (aExt) gemm_body<false, false>(A, W, wOff, bias, bOff, out, nrows, Kdim, epi, bn, bnOff, alpha, aOff, alpha_pc, 0);
    else gemm_body<true, false>(A, W, wOff, bias, bOff, out, nrows, Kdim, epi, bn, bnOff, alpha, aOff, alpha_pc, 0);
}

// ---------------------------------------------------------------------------
// Half-projection: r[0:16] += sum_k x[k] * sW[k*32 + e*16 + i]
// ---------------------------------------------------------------------------
#define PSTEP16(XS, KK)                                                       \
    {                                                                         \
        const float xs = (XS);                                                \
        const float4* w = (const float4*)(wb + (k4 * 4 + (KK)) * 32);         \
        _Pragma("unroll") for (int c = 0; c < 4; ++c) {                       \
            const float4 wv = w[c];                                           \
            r[4 * c]     = fmaf(xs, wv.x, r[4 * c]);                          \
            r[4 * c + 1] = fmaf(xs, wv.y, r[4 * c + 1]);                      \
            r[4 * c + 2] = fmaf(xs, wv.z, r[4 * c + 2]);                      \
            r[4 * c + 3] = fmaf(xs, wv.w, r[4 * c + 3]);                      \
        }                                                                     \
    }

__device__ __forceinline__ void proj16(float* r, const float* xq, const float* sW, int e) {
    const float4* x4 = (const float4*)xq;
    const float* wb = sW + e * 16;
    for (int k4 = 0; k4 < 32; ++k4) {
        const float4 xv = x4[k4];
        PSTEP16(xv.x, 0)
        PSTEP16(xv.y, 1)
        PSTEP16(xv.z, 2)
        PSTEP16(xv.w, 3)
    }
}

// ---------------------------------------------------------------------------
// Attention, block = (seq s, head h), 512 threads: lane pair per query row.
// q = tid>>1 (query row), e = tid&1 (16-float half of the 32-dim head).
// Score: own 16-dot + __shfl_xor(.,1) (single commutative add -> both lanes
// bit-identical m/l). PV: each lane accumulates its half. Q (and SELF K)
// projection fused; W slice staged into sK[0:4096]; K tile swizzled 16B-XOR.
// SELF: V from Vg, O written IN PLACE over Vg (block-private region; barrier
// before store). Self bias: h0 = (1/(d+.01))/rowsum[key], h1 = -d, h2/3 = 0.
// ---------------------------------------------------------------------------
template <int SELF>
__global__ __launch_bounds__(512, 4) void attn_kernel(
    const float* __restrict__ X, const float* __restrict__ Vg,
    const float* __restrict__ Kc,
    const void* __restrict__ Wqkv, int wqOff, int wkOff,
    const void* __restrict__ bqkv, int bqOff, int bkOff,
    float* __restrict__ O,
    const void* __restrict__ center, const float* __restrict__ rs,
    const int* __restrict__ flagp, int nk, int bDiv) {
    __shared__ float sK[8192];              // 32 KB; first 4 K floats = W stage
    __shared__ float sC[SELF ? 768 : 1];
    __shared__ float sR[SELF ? 256 : 1];
    const int isf32 = *flagp;
    const int s = blockIdx.x, h = blockIdx.y, tid = threadIdx.x;
    const int q = tid >> 1, e = tid & 1;
    const int hc = h * 32;
    const int ho = hc + e * 16;

    // ---- stage Wq into sK[0:4096] (+ center/rowsum for SELF) ----
    for (int idx = tid; idx < 4096; idx += 512) {
        const int k = idx >> 5, i = idx & 31;
        sK[idx] = ldx(Wqkv, (size_t)wqOff + (size_t)k * DD + hc + i, isf32);
    }
    if (SELF) {
        const int bb = s / bDiv;
        for (int idx = tid; idx < 768; idx += 512)
            sC[idx] = ldx(center, (size_t)bb * 768 + idx, isf32);
        if (tid < 256) sR[tid] = 1.0f / rs[bb * 256 + tid];
    }
    __syncthreads();

    // ---- fused Q half-projection ----
    float qr[16];
#pragma unroll
    for (int i = 0; i < 16; ++i) qr[i] = ldx(bqkv, (size_t)bqOff + ho + i, isf32);
    const float* xq = X + (size_t)(s * 256 + q) * DD;
    proj16(qr, xq, sK, e);
    __syncthreads();                        // done reading Wq

    if (SELF) {
        // stage Wk, half-project key row q, store swizzled K tile
        for (int idx = tid; idx < 4096; idx += 512) {
            const int k = idx >> 5, i = idx & 31;
            sK[idx] = ldx(Wqkv, (size_t)wkOff + (size_t)k * DD + hc + i, isf32);
        }
        __syncthreads();
        float kr[16];
#pragma unroll
        for (int i = 0; i < 16; ++i) kr[i] = ldx(bqkv, (size_t)bkOff + ho + i, isf32);
        proj16(kr, xq, sK, e);
        __syncthreads();                    // all reads of Wk done
#pragma unroll
        for (int cc = 0; cc < 4; ++cc) {
            const int c = e * 4 + cc;
            float4 v;
            v.x = kr[4 * cc]; v.y = kr[4 * cc + 1]; v.z = kr[4 * cc + 2]; v.w = kr[4 * cc + 3];
            *(float4*)((char*)sK + q * 128 + ((c * 16) ^ ((q & 7) << 4))) = v;
        }
        __syncthreads();
    } else {
        // stage K tile from global Kc (swizzled)
        for (int idx = tid; idx < nk * 32; idx += 512) {
            const int j = idx >> 5, i = idx & 31, c = i >> 2, w = i & 3;
            const int byte = j * 128 + ((c * 16) ^ ((j & 7) << 4)) + w * 4;
            *(float*)((char*)sK + byte) = Kc[((size_t)(s * nk + j)) * DD + hc + i];
        }
        __syncthreads();
    }

    float cx = 0.f, cy = 0.f, cz = 0.f;
    if (SELF) { cx = sC[q * 3]; cy = sC[q * 3 + 1]; cz = sC[q * 3 + 2]; }
    const float scale = 0.17677669529663687f;  // 1/sqrt(32)

    // ---- single-pass flash, chunks of 8 keys ----
    float m = -3.0e38f, l = 0.f;
    float acc[16];
#pragma unroll
    for (int i = 0; i < 16; ++i) acc[i] = 0.f;

    for (int j0 = 0; j0 < nk; j0 += 8) {
        float sc[8];
#pragma unroll
        for (int u = 0; u < 8; ++u) {
            const int j = j0 + u;
            const char* kb = (const char*)sK + j * 128;
            const int sw = (j & 7) << 4;
            float d0 = 0.f, d1 = 0.f, d2 = 0.f, d3 = 0.f;
#pragma unroll
            for (int cc = 0; cc < 4; ++cc) {
                const int c = e * 4 + cc;
                const float4 kv = *(const float4*)(kb + ((c * 16) ^ sw));
                d0 = fmaf(qr[4 * cc], kv.x, d0);
                d1 = fmaf(qr[4 * cc + 1], kv.y, d1);
                d2 = fmaf(qr[4 * cc + 2], kv.z, d2);
                d3 = fmaf(qr[4 * cc + 3], kv.w, d3);
            }
            const float half = (d0 + d1) + (d2 + d3);
            float v = (half + __shfl_xor(half, 1)) * scale;
            if (SELF) {
                const float dx = cx - sC[j * 3], dy = cy - sC[j * 3 + 1], dz = cz - sC[j * 3 + 2];
                const float dist = sqrtf(dx * dx + dy * dy + dz * dz);
                if (h == 0) v += __fdividef(1.f, dist + 0.01f) * sR[j];
                else if (h == 1) v -= dist;
            }
            sc[u] = v;
        }
        const float cmax = fmaxf(fmaxf(fmaxf(sc[0], sc[1]), fmaxf(sc[2], sc[3])),
                                 fmaxf(fmaxf(sc[4], sc[5]), fmaxf(sc[6], sc[7])));
        if (cmax > m) {
            const float f = __expf(m - cmax);
            l *= f;
#pragma unroll
            for (int i = 0; i < 16; ++i) acc[i] *= f;
            m = cmax;
        }
#pragma unroll
        for (int u = 0; u < 8; ++u) {
            const float p = __expf(sc[u] - m);
            l += p;
            const float4* vp = (const float4*)(Vg + ((size_t)(s * nk + j0 + u)) * DD + ho);
#pragma unroll
            for (int cc = 0; cc < 4; ++cc) {
                const float4 vv = vp[cc];
                acc[4 * cc]     = fmaf(p, vv.x, acc[4 * cc]);
                acc[4 * cc + 1] = fmaf(p, vv.y, acc[4 * cc + 1]);
                acc[4 * cc + 2] = fmaf(p, vv.z, acc[4 * cc + 2]);
                acc[4 * cc + 3] = fmaf(p, vv.w, acc[4 * cc + 3]);
            }
        }
    }
    __syncthreads();   // all V reads complete before in-place O store
    const float inv = 1.f / l;
    float4* op = (float4*)(O + ((size_t)(s * 256 + q)) * DD + ho);
#pragma unroll
    for (int cc = 0; cc < 4; ++cc) {
        float4 t;
        t.x = acc[4 * cc] * inv; t.y = acc[4 * cc + 1] * inv;
        t.z = acc[4 * cc + 2] * inv; t.w = acc[4 * cc + 3] * inv;
        op[cc] = t;
    }
}

// ---------------------------------------------------------------------------
// Y[row] = LayerNorm(X[row] + O[row] @ Wo + bo); 8 rows per block (Wo reuse).
// Y may alias X or O (row-local).
// ---------------------------------------------------------------------------
template <bool WF32>
__device__ __forceinline__ void ln_body(
    const float* __restrict__ X, const float* __restrict__ O,
    const void* __restrict__ Wo, int woOff, const void* __restrict__ bo, int boOff,
    const void* __restrict__ ln, int lnOff, float* __restrict__ Y, int isf32,
    float* sO, float* red1, float* red2) {
    const int d = threadIdx.x;
    const int row0 = blockIdx.x * 8;
#pragma unroll
    for (int r = 0; r < 8; ++r) sO[r * DD + d] = O[(size_t)(row0 + r) * DD + d];
    const float gam = ldx(ln, (size_t)lnOff + d, isf32);
    const float bet = ldx(ln, (size_t)lnOff + DD + d, isf32);
    const float bov = ldx(bo, (size_t)boOff + d, isf32);
    const float* Wf = (const float*)Wo + woOff;
    const unsigned short* Wu = (const unsigned short*)Wo + woOff;
    __syncthreads();
    for (int r = 0; r < 8; ++r) {
        float acc = 0.f;
#pragma unroll 4
        for (int k = 0; k < DD; ++k) {
            const float w = WF32 ? Wf[(size_t)k * DD + d] : bf2f(Wu[(size_t)k * DD + d]);
            acc = fmaf(sO[r * DD + k], w, acc);
        }
        const float v = X[(size_t)(row0 + r) * DD + d] + acc + bov;
        float s1 = v, s2 = v * v;
#pragma unroll
        for (int o = 1; o < 64; o <<= 1) { s1 += __shfl_xor(s1, o); s2 += __shfl_xor(s2, o); }
        if ((d & 63) == 0) { red1[d >> 6] = s1; red2[d >> 6] = s2; }
        __syncthreads();
        const float S1 = red1[0] + red1[1], S2 = red2[0] + red2[1];
        const float mu = S1 * (1.f / 128.f);
        const float var = S2 * (1.f / 128.f) - mu * mu;
        Y[(size_t)(row0 + r) * DD + d] = gam * (v - mu) * rsqrtf(var + 1e-5f) + bet;
        __syncthreads();
    }
}

__global__ __launch_bounds__(128) void proj_ln_kernel(
    const float* __restrict__ X, const float* __restrict__ O,
    const void* __restrict__ Wo, int woOff, const void* __restrict__ bo, int boOff,
    const void* __restrict__ ln, int lnOff, float* __restrict__ Y,
    const int* __restrict__ flagp) {
    __shared__ float sO[8 * DD];
    __shared__ float red1[2], red2[2];
    const int isf32 = *flagp;
    if (isf32) ln_body<true>(X, O, Wo, woOff, bo, boOff, ln, lnOff, Y, 1, sO, red1, red2);
    else       ln_body<false>(X, O, Wo, woOff, bo, boOff, ln, lnOff, Y, 0, sO, red1, red2);
}

// f1_0[(b*M+m)*256+n, d] = x1[b*256+n, d]
__global__ __launch_bounds__(256) void bcast_kernel(
    const float* __restrict__ src, float* __restrict__ dst) {
    const int i = blockIdx.x * 256 + threadIdx.x;
    const int rowd = i >> 7, d = i & 127;
    const int sq = rowd >> 8, n = rowd & 255, b = sq >> 3;
    dst[i] = src[((size_t)(b * 256 + n)) * DD + d];
}

// out[row] = Y[row,:] . W3 + b3
__global__ __launch_bounds__(64) void final_dot_kernel(
    const float* __restrict__ Y, const void* __restrict__ W3,
    const void* __restrict__ b3, void* __restrict__ out,
    const int* __restrict__ flagp) {
    const int isf32 = *flagp;
    const int row = blockIdx.x, lid = threadIdx.x;
    const float* yp = Y + (size_t)row * DD;
    float v = yp[lid] * ldx(W3, lid, isf32) + yp[lid + 64] * ldx(W3, (size_t)lid + 64, isf32);
#pragma unroll
    for (int o = 1; o < 64; o <<= 1) v += __shfl_xor(v, o);
    if (lid == 0) {
        const float r = v + ldx(b3, 0, isf32);
        if (isf32) ((float*)out)[row] = r;
        else ((unsigned short*)out)[row] = f2bf(r);
    }
}

// ---------------------------------------------------------------------------

extern "C" void kernel_launch(void* const* d_in, const int* in_sizes, int n_in,
                              void* d_out, int out_size, void* d_ws, size_t ws_size,
                              hipStream_t stream) {
    bool ok = (n_in >= 29) && in_sizes[0] == 12288 && in_sizes[1] == 4718592 &&
              in_sizes[2] == 1310720 && in_sizes[7] == 147456 &&
              in_sizes[13] == 98304 && in_sizes[25] == 1024 && in_sizes[27] == 128;
    if (!ok) {
        sentinel_kernel<<<(out_size + 255) / 256, 256, 0, stream>>>(
            (unsigned short*)d_out, out_size, 0x44FA);  // bf16(2000)
        return;
    }
    const size_t SZ = (size_t)32768 * 128;
    const size_t NEED = (16384ull + 2ull * SZ + 2ull * 10240 * 128) * 4ull;
    if (ws_size < NEED) {
        sentinel_kernel<<<(out_size + 255) / 256, 256, 0, stream>>>(
            (unsigned short*)d_out, out_size, 0x447A);  // bf16(1000)
        return;
    }

    const void* center = d_in[0];
    const void* detr   = d_in[1];
    const void* lang   = d_in[2];
    const void* fc1_W  = d_in[7];
    const void* fc1_b  = d_in[8];
    const void* bn0    = d_in[9];
    const void* prelu0 = d_in[10];
    const void* fc2_W  = d_in[11];
    const void* fc2_b  = d_in[12];
    const void* s_qkv  = d_in[13];
    const void* s_qkvb = d_in[14];
    const void* s_Wo   = d_in[15];
    const void* s_bo   = d_in[16];
    const void* s_ln   = d_in[17];
    const void* c_qkv  = d_in[18];
    const void* c_qkvb = d_in[19];
    const void* c_Wo   = d_in[20];
    const void* c_bo   = d_in[21];
    const void* c_ln   = d_in[22];
    const void* m_W    = d_in[23];
    const void* m_b    = d_in[24];
    const void* m_bn   = d_in[25];
    const void* m_al   = d_in[26];
    const void* m_W3   = d_in[27];
    const void* m_b3   = d_in[28];

    float* wsf  = (float*)d_ws;
    int*   flag = (int*)d_ws;
    float* rs   = wsf + 4096;
    float* X    = wsf + 16384;
    float* VO   = X + SZ;
    float* Kc   = VO + SZ;
    float* Vc   = Kc + (size_t)10240 * 128;

    detect_kernel<<<1, 256, 0, stream>>>((const unsigned short*)center, flag);
    rowsum_kernel<<<16, 256, 0, stream>>>(center, rs, flag);

    // fc1 (+BN+PReLU per-channel) -> VO[0:4096); fc2 -> X[0:4096) = x0
    gemm128_kernel<<<256, 256, 0, stream>>>(detr, 1, fc1_W, 0, fc1_b, 0, VO, 4096, 1152, 1,
                                            bn0, 0, prelu0, 0, 1, flag);
    gemm128_kernel<<<256, 256, 0, stream>>>(VO, 0, fc2_W, 0, fc2_b, 0, X, 4096, 128, 0,
                                            nullptr, 0, nullptr, 0, 0, flag);

    // self block 0 (16 seqs): V -> VO; attn (fused Q,K) O in-place VO; LN -> VO
    gemm128_kernel<<<256, 256, 0, stream>>>(X, 0, s_qkv, 2 * WMAT, s_qkvb, 256, VO, 4096, 128, 0,
                                            nullptr, 0, nullptr, 0, 0, flag);
    attn_kernel<1><<<dim3(16, 4), 512, 0, stream>>>(X, VO, nullptr, s_qkv, 0, WMAT, s_qkvb, 0, 128,
                                                    VO, center, rs, flag, 256, 1);
    proj_ln_kernel<<<512, 128, 0, stream>>>(X, VO, s_Wo, 0, s_bo, 0, s_ln, 0, VO, flag);

    // broadcast x1 (VO, 4096 rows) -> X (32768 rows) = f1_0
    bcast_kernel<<<16384, 256, 0, stream>>>(VO, X);

    // cross block 0: K,V from lang -> Kc,Vc; attn (fused Q) -> VO; LN -> X
    gemm128_kernel<<<640, 256, 0, stream>>>(lang, 1, c_qkv, WMAT, c_qkvb, 128, Kc, 10240, 128, 0,
                                            nullptr, 0, nullptr, 0, 0, flag);
    gemm128_kernel<<<640, 256, 0, stream>>>(lang, 1, c_qkv, 2 * WMAT, c_qkvb, 256, Vc, 10240, 128, 0,
                                            nullptr, 0, nullptr, 0, 0, flag);
    attn_kernel<0><<<dim3(128, 4), 512, 0, stream>>>(X, Vc, Kc, c_qkv, 0, 0, c_qkvb, 0, 0,
                                                     VO, nullptr, nullptr, flag, 80, 1);
    proj_ln_kernel<<<4096, 128, 0, stream>>>(X, VO, c_Wo, 0, c_bo, 0, c_ln, 0, X, flag);

    // self block 1 (128 seqs, bias with b = s/8)
    gemm128_kernel<<<2048, 256, 0, stream>>>(X, 0, s_qkv, 5 * WMAT, s_qkvb, 640, VO, 32768, 128, 0,
                                             nullptr, 0, nullptr, 0, 0, flag);
    attn_kernel<1><<<dim3(128, 4), 512, 0, stream>>>(X, VO, nullptr, s_qkv, 3 * WMAT, 4 * WMAT,
                                                     s_qkvb, 384, 512, VO, center, rs, flag, 256, 8);
    proj_ln_kernel<<<4096, 128, 0, stream>>>(X, VO, s_Wo, WMAT, s_bo, 128, s_ln, 256, X, flag);

    // cross block 1
    gemm128_kernel<<<640, 256, 0, stream>>>(lang, 1, c_qkv, 4 * WMAT, c_qkvb, 512, Kc, 10240, 128, 0,
                                            nullptr, 0, nullptr, 0, 0, flag);
    gemm128_kernel<<<640, 256, 0, stream>>>(lang, 1, c_qkv, 5 * WMAT, c_qkvb, 640, Vc, 10240, 128, 0,
                                            nullptr, 0, nullptr, 0, 0, flag);
    attn_kernel<0><<<dim3(128, 4), 512, 0, stream>>>(X, Vc, Kc, c_qkv, 3 * WMAT, 0, c_qkvb, 384, 0,
                                                     VO, nullptr, nullptr, flag, 80, 1);
    proj_ln_kernel<<<4096, 128, 0, stream>>>(X, VO, c_Wo, WMAT, c_bo, 128, c_ln, 256, X, flag);

    // match head
    gemm128_kernel<<<2048, 256, 0, stream>>>(X, 0, m_W, 0, m_b, 0, VO, 32768, 128, 1,
                                             m_bn, 0, m_al, 0, 0, flag);
    gemm128_kernel<<<2048, 256, 0, stream>>>(VO, 0, m_W, WMAT, m_b, 128, X, 32768, 128, 1,
                                             m_bn, 512, m_al, 1, 0, flag);
    final_dot_kernel<<<32768, 64, 0, stream>>>(X, m_W3, m_b3, d_out, flag);
}

// Round 8
// 1020.695 us; speedup vs baseline: 1.6782x; 1.2060x over previous
//
#include <hip/hip_runtime.h>

// ---------------------------------------------------------------------------
// MatchModule forward. H=4 D=128 B=16 K=256 M=8 L=80 DET_C=1152, dk=32.
// R8: attention rewritten on MFMA (mfma_f32_16x16x32_bf16).
//  - swapped QK^T: S^T = mfma(A=K-frag, B=Q-frag); per-q reduce in-reg + 2 shfl
//  - P round-trips LDS as bf16 (per-wave tile) to become the PV A-operand
//  - V^T staged bf16 in LDS (stride 264: 2-way, free) - no more global V re-reads
//  - K/Q/P tiles stride 36 bf16 (conflict-free frag reads)
//  - f32 fused Q/K projections (proj16, R7-proven) feed the bf16 tiles
//  - no barrier inside k-loop (per-wave P/F regions, DS in-order per wave)
// ws layout unchanged (42.1 MiB): flag | rowsum | X | VO | Kc | Vc.
// ---------------------------------------------------------------------------

#define DD 128
#define WMAT 16384

typedef __attribute__((ext_vector_type(8))) short bf16x8;
typedef __attribute__((ext_vector_type(4))) float f32x4;

__device__ __forceinline__ float bf2f(unsigned short u) {
    union { unsigned int i; float f; } v; v.i = ((unsigned int)u) << 16; return v.f;
}
__device__ __forceinline__ unsigned short f2bf(float f) {
    union { float f; unsigned int i; } v; v.f = f;
    unsigned int x = v.i;
    return (unsigned short)((x + 0x7FFFu + ((x >> 16) & 1u)) >> 16);
}
__device__ __forceinline__ unsigned pack2bf(float a, float b) {
    return (unsigned)f2bf(a) | ((unsigned)f2bf(b) << 16);
}
__device__ __forceinline__ float ldx(const void* p, size_t i, int isf32) {
    return isf32 ? ((const float*)p)[i] : bf2f(((const unsigned short*)p)[i]);
}
__device__ __forceinline__ bf16x8 ld_frag8(const unsigned short* base) {  // 8B-aligned
    union { bf16x8 v; uint2 u[2]; } r;
    r.u[0] = *(const uint2*)(base);
    r.u[1] = *(const uint2*)(base + 4);
    return r.v;
}

// ---------------------------------------------------------------------------
__global__ __launch_bounds__(256) void detect_kernel(
    const unsigned short* __restrict__ c, int* __restrict__ flag) {
    __shared__ int cnt;
    if (threadIdx.x == 0) cnt = 0;
    __syncthreads();
    float v = bf2f(c[threadIdx.x]);
    int sane = (v == v) && (fabsf(v) <= 1e4f) && (v == 0.f || fabsf(v) >= 1e-10f);
    atomicAdd(&cnt, sane);
    __syncthreads();
    if (threadIdx.x == 0) flag[0] = (cnt >= 224) ? 0 : 1;  // 0=bf16, 1=f32
}

__global__ void sentinel_kernel(unsigned short* out, int n, int val) {
    int i = blockIdx.x * 256 + threadIdx.x;
    if (i < n) out[i] = (unsigned short)val;
}

// ---------------------------------------------------------------------------
__global__ __launch_bounds__(256) void rowsum_kernel(
    const void* __restrict__ center, float* __restrict__ rs,
    const int* __restrict__ flagp) {
    const int isf32 = *flagp;
    const int b = blockIdx.x, i = threadIdx.x;
    __shared__ float c[768];
    for (int idx = i; idx < 768; idx += 256) c[idx] = ldx(center, (size_t)b * 768 + idx, isf32);
    __syncthreads();
    const float cx = c[i * 3], cy = c[i * 3 + 1], cz = c[i * 3 + 2];
    float s = 0.f;
    for (int j = 0; j < 256; ++j) {
        float dx = cx - c[j * 3], dy = cy - c[j * 3 + 1], dz = cz - c[j * 3 + 2];
        s += 1.f / (sqrtf(dx * dx + dy * dy + dz * dz) + 0.01f);
    }
    rs[b * 256 + i] = s;
}

// ---------------------------------------------------------------------------
// GEMM (unchanged from R7)
// ---------------------------------------------------------------------------
template <bool AF32, bool WF32>
__device__ __forceinline__ void gemm_body(
    const void* __restrict__ A, const void* __restrict__ W, int wOff,
    const void* __restrict__ bias, int bOff, float* __restrict__ out,
    int nrows, int Kdim, int epi, const void* __restrict__ bn, int bnOff,
    const void* __restrict__ alpha, int aOff, int alpha_pc, int isf32) {
    const int d = threadIdx.x & 127, rg = threadIdx.x >> 7;
    const int r0 = blockIdx.x * 16 + rg * 8;
    if (r0 >= nrows) return;
    float acc[8] = {0.f, 0.f, 0.f, 0.f, 0.f, 0.f, 0.f, 0.f};
    const float* Af = (const float*)A;
    const unsigned short* Au = (const unsigned short*)A;
    const float* Wf = (const float*)W + wOff;
    const unsigned short* Wu = (const unsigned short*)W + wOff;
    for (int k = 0; k < Kdim; k += 4) {
        float w0, w1, w2, w3;
        if (WF32) {
            w0 = Wf[(size_t)(k + 0) * DD + d]; w1 = Wf[(size_t)(k + 1) * DD + d];
            w2 = Wf[(size_t)(k + 2) * DD + d]; w3 = Wf[(size_t)(k + 3) * DD + d];
        } else {
            w0 = bf2f(Wu[(size_t)(k + 0) * DD + d]); w1 = bf2f(Wu[(size_t)(k + 1) * DD + d]);
            w2 = bf2f(Wu[(size_t)(k + 2) * DD + d]); w3 = bf2f(Wu[(size_t)(k + 3) * DD + d]);
        }
#pragma unroll
        for (int r = 0; r < 8; ++r) {
            const size_t base = (size_t)(r0 + r) * Kdim + k;
            float a0, a1, a2, a3;
            if (AF32) {
                const float4 t = *reinterpret_cast<const float4*>(Af + base);
                a0 = t.x; a1 = t.y; a2 = t.z; a3 = t.w;
            } else {
                const ushort4 t = *reinterpret_cast<const ushort4*>(Au + base);
                a0 = bf2f(t.x); a1 = bf2f(t.y); a2 = bf2f(t.z); a3 = bf2f(t.w);
            }
            acc[r] = fmaf(a0, w0, fmaf(a1, w1, fmaf(a2, w2, fmaf(a3, w3, acc[r]))));
        }
    }
    const float bs = ldx(bias, (size_t)bOff + d, isf32);
    float g = 1.f, bb = 0.f, mm = 0.f, rinv = 1.f, al = 0.f;
    if (epi) {
        g  = ldx(bn, (size_t)bnOff + d, isf32);
        bb = ldx(bn, (size_t)bnOff + DD + d, isf32);
        mm = ldx(bn, (size_t)bnOff + 2 * DD + d, isf32);
        rinv = rsqrtf(ldx(bn, (size_t)bnOff + 3 * DD + d, isf32) + 1e-5f);
        al = alpha_pc ? ldx(alpha, (size_t)aOff + d, isf32) : ldx(alpha, (size_t)aOff, isf32);
    }
#pragma unroll
    for (int r = 0; r < 8; ++r) {
        float v = acc[r] + bs;
        if (epi) {
            v = g * (v - mm) * rinv + bb;
            v = (v >= 0.f) ? v : al * v;
        }
        out[(size_t)(r0 + r) * DD + d] = v;
    }
}

__global__ __launch_bounds__(256) void gemm128_kernel(
    const void* __restrict__ A, int aExt,
    const void* __restrict__ W, int wOff,
    const void* __restrict__ bias, int bOff,
    float* __restrict__ out, int nrows, int Kdim, int epi,
    const void* __restrict__ bn, int bnOff,
    const void* __restrict__ alpha, int aOff, int alpha_pc,
    const int* __restrict__ flagp) {
    const int isf32 = *flagp;
    if (isf32) gemm_body<true, true>(A, W, wOff, bias, bOff, out, nrows, Kdim, epi, bn, bnOff, alpha, aOff, alpha_pc, 1);
    else if (aExt) gemm_body<false, false>(A, W, wOff, bias, bOff, out, nrows, Kdim, epi, bn, bnOff, alpha, aOff, alpha_pc, 0);
    else gemm_body<true, false>(A, W, wOff, bias, bOff, out, nrows, Kdim, epi, bn, bnOff, alpha, aOff, alpha_pc, 0);
}

// ---------------------------------------------------------------------------
// Half-projection r[0:16] += sum_k x[k]*sW[k*32 + e*16 + i]  (R7-proven)
// ---------------------------------------------------------------------------
#define PSTEP16(XS, KK)                                                       \
    {                                                                         \
        const float xs = (XS);                                                \
        const float4* w = (const float4*)(wb + (k4 * 4 + (KK)) * 32);         \
        _Pragma("unroll") for (int c = 0; c < 4; ++c) {                       \
            const float4 wv = w[c];                                           \
            r[4 * c]     = fmaf(xs, wv.x, r[4 * c]);                          \
            r[4 * c + 1] = fmaf(xs, wv.y, r[4 * c + 1]);                      \
            r[4 * c + 2] = fmaf(xs, wv.z, r[4 * c + 2]);                      \
            r[4 * c + 3] = fmaf(xs, wv.w, r[4 * c + 3]);                      \
        }                                                                     \
    }

__device__ __forceinline__ void proj16(float* r, const float* xq, const float* sW, int e) {
    const float4* x4 = (const float4*)xq;
    const float* wb = sW + e * 16;
    for (int k4 = 0; k4 < 32; ++k4) {
        const float4 xv = x4[k4];
        PSTEP16(xv.x, 0)
        PSTEP16(xv.y, 1)
        PSTEP16(xv.z, 2)
        PSTEP16(xv.w, 3)
    }
}

// ---------------------------------------------------------------------------
// MFMA flash attention. Block = (seq s, head h), 512 threads = 8 waves.
// Wave w owns 32 q-rows (2 subtiles of 16). 16x16x32 bf16 MFMA.
//   scores:  S^T(16k x 16q) = mfma(A=K-frag, B=Q-frag)   [contraction = 32 d]
//   softmax: lane owns q=(l&15)+sub*16+w*32, 4 k-scores/reg; reduce shfl 16,32
//   PV:      O(16q x 16d)  = mfma(A=P-frag, B=V^T-frag)  [contraction = 32 k]
// P goes through per-wave LDS tile (bf16, stride 36) to fix the layout.
// LDS: [sW f32 16KB | alias sVT bf16 32x264] [sKb 256x36] [sQP 256x36]
//      [sF 256 f32] [sC/sR if SELF].  58.9 KB -> 2 blocks/CU.
// SELF: Q,K projected in-kernel (f32 proj16) from X; V from Vg; O in-place Vg.
// ---------------------------------------------------------------------------
template <int SELF>
__global__ __launch_bounds__(512, 2) void attn_kernel(
    const float* __restrict__ X, const float* __restrict__ Vg,
    const float* __restrict__ Kc,
    const void* __restrict__ Wqkv, int wqOff, int wkOff,
    const void* __restrict__ bqkv, int bqOff, int bkOff,
    float* __restrict__ O,
    const void* __restrict__ center, const float* __restrict__ rs,
    const int* __restrict__ flagp, int nk, int bDiv) {
    __shared__ __align__(16) char smem[54784 + (SELF ? 4096 : 0)];
    float* sW           = (float*)smem;                        // 16 KB (staging)
    unsigned short* sVT = (unsigned short*)smem;               // [32][264] bf16 (alias)
    unsigned short* sKb = (unsigned short*)(smem + 16896);     // [256][36] bf16
    unsigned short* sQP = (unsigned short*)(smem + 35328);     // [256][36] bf16 (Q then P)
    float* sF           = (float*)(smem + 53760);              // [256]
    float* sC           = (float*)(smem + 54784);              // [768] (SELF)
    float* sR           = sC + 768;                            // [256] (SELF)

    const int isf32 = *flagp;
    const int s = blockIdx.x, h = blockIdx.y, tid = threadIdx.x;
    const int l = tid & 63, w = tid >> 6;
    const int hc = h * 32;
    const int lg = l >> 4;        // k-group / q-row-group (0..3)
    const int ll = l & 15;        // q-col / k-row within tile
    const int qp = tid >> 1, e = tid & 1;          // projection roles

    // ---- phase 1: Wq stage + centers ----
    for (int idx = tid; idx < 4096; idx += 512) {
        const int k = idx >> 5, i = idx & 31;
        sW[idx] = ldx(Wqkv, (size_t)wqOff + (size_t)k * DD + hc + i, isf32);
    }
    if (SELF) {
        const int bb = s / bDiv;
        for (int idx = tid; idx < 768; idx += 512)
            sC[idx] = ldx(center, (size_t)bb * 768 + idx, isf32);
        if (tid < 256) sR[tid] = 1.0f / rs[(s / bDiv) * 256 + tid];
    }
    __syncthreads();

    // ---- phase 2: Q projection -> sQP bf16 ----
    const float* xq = X + (size_t)(s * 256 + qp) * DD;
    {
        float r[16];
#pragma unroll
        for (int i = 0; i < 16; ++i) r[i] = ldx(bqkv, (size_t)bqOff + hc + e * 16 + i, isf32);
        proj16(r, xq, sW, e);
        unsigned* dst = (unsigned*)((char*)sQP + qp * 72 + e * 32);
#pragma unroll
        for (int i = 0; i < 8; ++i) dst[i] = pack2bf(r[2 * i], r[2 * i + 1]);
    }
    __syncthreads();

    // ---- phase 3: K -> sKb bf16 ----
    if (SELF) {
        for (int idx = tid; idx < 4096; idx += 512) {
            const int k = idx >> 5, i = idx & 31;
            sW[idx] = ldx(Wqkv, (size_t)wkOff + (size_t)k * DD + hc + i, isf32);
        }
        __syncthreads();
        float r[16];
#pragma unroll
        for (int i = 0; i < 16; ++i) r[i] = ldx(bqkv, (size_t)bkOff + hc + e * 16 + i, isf32);
        proj16(r, xq, sW, e);
        unsigned* dst = (unsigned*)((char*)sKb + qp * 72 + e * 32);
#pragma unroll
        for (int i = 0; i < 8; ++i) dst[i] = pack2bf(r[2 * i], r[2 * i + 1]);
    } else {
        for (int idx = tid; idx < nk * 32; idx += 512) {
            const int j = idx >> 5, i = idx & 31;
            sKb[j * 36 + i] = f2bf(Kc[((size_t)(s * nk + j)) * DD + hc + i]);
        }
    }
    __syncthreads();

    // ---- phase 4: Q fragments (before any P write; per-wave rows) ----
    bf16x8 qfrag[2];
#pragma unroll
    for (int sub = 0; sub < 2; ++sub) {
        const int qrow = w * 32 + sub * 16 + ll;
        qfrag[sub] = ld_frag8(sQP + qrow * 36 + lg * 8);
    }

    // ---- phase 5: V^T -> sVT bf16 (overwrites sW alias) ----
    const int nkR = (nk + 31) & ~31;
    for (int idx = tid; idx < nkR * 32; idx += 512) {
        const int j = idx >> 5, i = idx & 31;
        const float v = (j < nk) ? Vg[((size_t)(s * nk + j)) * DD + hc + i] : 0.f;
        sVT[i * 264 + j] = f2bf(v);
    }
    __syncthreads();

    // ---- phase 6: flash k-loop (no barriers) ----
    const float scale = 0.17677669529663687f;  // 1/sqrt(32)
    float cqx[2], cqy[2], cqz[2];
    if (SELF) {
#pragma unroll
        for (int sub = 0; sub < 2; ++sub) {
            const int qg = w * 32 + sub * 16 + ll;
            cqx[sub] = sC[qg * 3]; cqy[sub] = sC[qg * 3 + 1]; cqz[sub] = sC[qg * 3 + 2];
        }
    }
    float m_[2] = {-3.0e38f, -3.0e38f}, l_[2] = {0.f, 0.f};
    const f32x4 zf = {0.f, 0.f, 0.f, 0.f};
    f32x4 oacc[2][2] = {{zf, zf}, {zf, zf}};
    unsigned short* sPw = sQP + w * 32 * 36;   // per-wave P tile [32][36]

    for (int kb = 0; kb < nk; kb += 32) {
        const int full = (nk - kb) >= 32;
        const unsigned short* kbase = sKb + (kb + ll) * 36 + lg * 8;
        const bf16x8 kf0 = ld_frag8(kbase);
        bf16x8 kf1;
        if (full) kf1 = ld_frag8(kbase + 16 * 36);

#pragma unroll
        for (int sub = 0; sub < 2; ++sub) {
            f32x4 s0 = __builtin_amdgcn_mfma_f32_16x16x32_bf16(kf0, qfrag[sub], zf, 0, 0, 0);
            f32x4 s1 = zf;
            if (full) s1 = __builtin_amdgcn_mfma_f32_16x16x32_bf16(kf1, qfrag[sub], zf, 0, 0, 0);

            float sc[8];
#pragma unroll
            for (int r = 0; r < 4; ++r) {
                const int k0 = kb + lg * 4 + r;
                float v0 = s0[r] * scale;
                float v1 = full ? s1[r] * scale : -3.0e38f;
                if (SELF && h < 2) {
                    {
                        const float dx = cqx[sub] - sC[k0 * 3], dy = cqy[sub] - sC[k0 * 3 + 1],
                                    dz = cqz[sub] - sC[k0 * 3 + 2];
                        const float dist = sqrtf(dx * dx + dy * dy + dz * dz);
                        if (h == 0) v0 += __fdividef(1.f, dist + 0.01f) * sR[k0];
                        else v0 -= dist;
                    }
                    if (full) {
                        const int k1 = k0 + 16;
                        const float dx = cqx[sub] - sC[k1 * 3], dy = cqy[sub] - sC[k1 * 3 + 1],
                                    dz = cqz[sub] - sC[k1 * 3 + 2];
                        const float dist = sqrtf(dx * dx + dy * dy + dz * dz);
                        if (h == 0) v1 += __fdividef(1.f, dist + 0.01f) * sR[k1];
                        else v1 -= dist;
                    }
                }
                sc[r] = v0; sc[4 + r] = v1;
            }
            float tmax = fmaxf(fmaxf(fmaxf(sc[0], sc[1]), fmaxf(sc[2], sc[3])),
                               fmaxf(fmaxf(sc[4], sc[5]), fmaxf(sc[6], sc[7])));
            tmax = fmaxf(tmax, __shfl_xor(tmax, 16));
            tmax = fmaxf(tmax, __shfl_xor(tmax, 32));
            const float mnew = fmaxf(m_[sub], tmax);
            const float f = __expf(m_[sub] - mnew);
            m_[sub] = mnew;
            float p[8], lsum = 0.f;
#pragma unroll
            for (int u = 0; u < 8; ++u) { p[u] = __expf(sc[u] - mnew); lsum += p[u]; }
            lsum += __shfl_xor(lsum, 16);
            lsum += __shfl_xor(lsum, 32);
            l_[sub] = l_[sub] * f + lsum;
            if (lg == 0) sF[w * 32 + sub * 16 + ll] = f;
            unsigned* prow = (unsigned*)((char*)sPw + (sub * 16 + ll) * 72 + lg * 8);
            prow[0] = pack2bf(p[0], p[1]);
            prow[1] = pack2bf(p[2], p[3]);
            unsigned* prow1 = (unsigned*)((char*)prow + 32);
            prow1[0] = pack2bf(p[4], p[5]);
            prow1[1] = pack2bf(p[6], p[7]);
        }

        // rescale + PV
        bf16x8 vf[2], pf[2];
#pragma unroll
        for (int dt = 0; dt < 2; ++dt)
            vf[dt] = *(const bf16x8*)(sVT + (dt * 16 + ll) * 264 + kb + lg * 8);
#pragma unroll
        for (int sub = 0; sub < 2; ++sub) {
            pf[sub] = ld_frag8(sPw + (sub * 16 + ll) * 36 + lg * 8);
            float fr[4];
#pragma unroll
            for (int r = 0; r < 4; ++r) fr[r] = sF[w * 32 + sub * 16 + lg * 4 + r];
#pragma unroll
            for (int dt = 0; dt < 2; ++dt) {
#pragma unroll
                for (int r = 0; r < 4; ++r) oacc[sub][dt][r] *= fr[r];
                oacc[sub][dt] = __builtin_amdgcn_mfma_f32_16x16x32_bf16(
                    pf[sub], vf[dt], oacc[sub][dt], 0, 0, 0);
            }
        }
    }

    // ---- phase 7: normalize + write O ----
    if (lg == 0) {
        sF[w * 32 + ll]      = 1.f / l_[0];
        sF[w * 32 + 16 + ll] = 1.f / l_[1];
    }
#pragma unroll
    for (int sub = 0; sub < 2; ++sub) {
#pragma unroll
        for (int r = 0; r < 4; ++r) {
            const float li = sF[w * 32 + sub * 16 + lg * 4 + r];
            const int qrow = w * 32 + sub * 16 + lg * 4 + r;
#pragma unroll
            for (int dt = 0; dt < 2; ++dt) {
                O[((size_t)(s * 256 + qrow)) * DD + hc + dt * 16 + ll] = oacc[sub][dt][r] * li;
            }
        }
    }
}

// ---------------------------------------------------------------------------
// proj_ln (unchanged from R7)
// ---------------------------------------------------------------------------
template <bool WF32>
__device__ __forceinline__ void ln_body(
    const float* __restrict__ X, const float* __restrict__ O,
    const void* __restrict__ Wo, int woOff, const void* __restrict__ bo, int boOff,
    const void* __restrict__ ln, int lnOff, float* __restrict__ Y, int isf32,
    float* sO, float* red1, float* red2) {
    const int d = threadIdx.x;
    const int row0 = blockIdx.x * 8;
#pragma unroll
    for (int r = 0; r < 8; ++r) sO[r * DD + d] = O[(size_t)(row0 + r) * DD + d];
    const float gam = ldx(ln, (size_t)lnOff + d, isf32);
    const float bet = ldx(ln, (size_t)lnOff + DD + d, isf32);
    const float bov = ldx(bo, (size_t)boOff + d, isf32);
    const float* Wf = (const float*)Wo + woOff;
    const unsigned short* Wu = (const unsigned short*)Wo + woOff;
    __syncthreads();
    for (int r = 0; r < 8; ++r) {
        float acc = 0.f;
#pragma unroll 4
        for (int k = 0; k < DD; ++k) {
            const float w = WF32 ? Wf[(size_t)k * DD + d] : bf2f(Wu[(size_t)k * DD + d]);
            acc = fmaf(sO[r * DD + k], w, acc);
        }
        const float v = X[(size_t)(row0 + r) * DD + d] + acc + bov;
        float s1 = v, s2 = v * v;
#pragma unroll
        for (int o = 1; o < 64; o <<= 1) { s1 += __shfl_xor(s1, o); s2 += __shfl_xor(s2, o); }
        if ((d & 63) == 0) { red1[d >> 6] = s1; red2[d >> 6] = s2; }
        __syncthreads();
        const float S1 = red1[0] + red1[1], S2 = red2[0] + red2[1];
        const float mu = S1 * (1.f / 128.f);
        const float var = S2 * (1.f / 128.f) - mu * mu;
        Y[(size_t)(row0 + r) * DD + d] = gam * (v - mu) * rsqrtf(var + 1e-5f) + bet;
        __syncthreads();
    }
}

__global__ __launch_bounds__(128) void proj_ln_kernel(
    const float* __restrict__ X, const float* __restrict__ O,
    const void* __restrict__ Wo, int woOff, const void* __restrict__ bo, int boOff,
    const void* __restrict__ ln, int lnOff, float* __restrict__ Y,
    const int* __restrict__ flagp) {
    __shared__ float sO[8 * DD];
    __shared__ float red1[2], red2[2];
    const int isf32 = *flagp;
    if (isf32) ln_body<true>(X, O, Wo, woOff, bo, boOff, ln, lnOff, Y, 1, sO, red1, red2);
    else       ln_body<false>(X, O, Wo, woOff, bo, boOff, ln, lnOff, Y, 0, sO, red1, red2);
}

__global__ __launch_bounds__(256) void bcast_kernel(
    const float* __restrict__ src, float* __restrict__ dst) {
    const int i = blockIdx.x * 256 + threadIdx.x;
    const int rowd = i >> 7, d = i & 127;
    const int sq = rowd >> 8, n = rowd & 255, b = sq >> 3;
    dst[i] = src[((size_t)(b * 256 + n)) * DD + d];
}

__global__ __launch_bounds__(64) void final_dot_kernel(
    const float* __restrict__ Y, const void* __restrict__ W3,
    const void* __restrict__ b3, void* __restrict__ out,
    const int* __restrict__ flagp) {
    const int isf32 = *flagp;
    const int row = blockIdx.x, lid = threadIdx.x;
    const float* yp = Y + (size_t)row * DD;
    float v = yp[lid] * ldx(W3, lid, isf32) + yp[lid + 64] * ldx(W3, (size_t)lid + 64, isf32);
#pragma unroll
    for (int o = 1; o < 64; o <<= 1) v += __shfl_xor(v, o);
    if (lid == 0) {
        const float r = v + ldx(b3, 0, isf32);
        if (isf32) ((float*)out)[row] = r;
        else ((unsigned short*)out)[row] = f2bf(r);
    }
}

// ---------------------------------------------------------------------------

extern "C" void kernel_launch(void* const* d_in, const int* in_sizes, int n_in,
                              void* d_out, int out_size, void* d_ws, size_t ws_size,
                              hipStream_t stream) {
    bool ok = (n_in >= 29) && in_sizes[0] == 12288 && in_sizes[1] == 4718592 &&
              in_sizes[2] == 1310720 && in_sizes[7] == 147456 &&
              in_sizes[13] == 98304 && in_sizes[25] == 1024 && in_sizes[27] == 128;
    if (!ok) {
        sentinel_kernel<<<(out_size + 255) / 256, 256, 0, stream>>>(
            (unsigned short*)d_out, out_size, 0x44FA);
        return;
    }
    const size_t SZ = (size_t)32768 * 128;
    const size_t NEED = (16384ull + 2ull * SZ + 2ull * 10240 * 128) * 4ull;
    if (ws_size < NEED) {
        sentinel_kernel<<<(out_size + 255) / 256, 256, 0, stream>>>(
            (unsigned short*)d_out, out_size, 0x447A);
        return;
    }

    const void* center = d_in[0];
    const void* detr   = d_in[1];
    const void* lang   = d_in[2];
    const void* fc1_W  = d_in[7];
    const void* fc1_b  = d_in[8];
    const void* bn0    = d_in[9];
    const void* prelu0 = d_in[10];
    const void* fc2_W  = d_in[11];
    const void* fc2_b  = d_in[12];
    const void* s_qkv  = d_in[13];
    const void* s_qkvb = d_in[14];
    const void* s_Wo   = d_in[15];
    const void* s_bo   = d_in[16];
    const void* s_ln   = d_in[17];
    const void* c_qkv  = d_in[18];
    const void* c_qkvb = d_in[19];
    const void* c_Wo   = d_in[20];
    const void* c_bo   = d_in[21];
    const void* c_ln   = d_in[22];
    const void* m_W    = d_in[23];
    const void* m_b    = d_in[24];
    const void* m_bn   = d_in[25];
    const void* m_al   = d_in[26];
    const void* m_W3   = d_in[27];
    const void* m_b3   = d_in[28];

    float* wsf  = (float*)d_ws;
    int*   flag = (int*)d_ws;
    float* rs   = wsf + 4096;
    float* X    = wsf + 16384;
    float* VO   = X + SZ;
    float* Kc   = VO + SZ;
    float* Vc   = Kc + (size_t)10240 * 128;

    detect_kernel<<<1, 256, 0, stream>>>((const unsigned short*)center, flag);
    rowsum_kernel<<<16, 256, 0, stream>>>(center, rs, flag);

    // fc1 (+BN+PReLU) -> VO[0:4096); fc2 -> X[0:4096) = x0
    gemm128_kernel<<<256, 256, 0, stream>>>(detr, 1, fc1_W, 0, fc1_b, 0, VO, 4096, 1152, 1,
                                            bn0, 0, prelu0, 0, 1, flag);
    gemm128_kernel<<<256, 256, 0, stream>>>(VO, 0, fc2_W, 0, fc2_b, 0, X, 4096, 128, 0,
                                            nullptr, 0, nullptr, 0, 0, flag);

    // self block 0: V -> VO; attn (fused Q,K, MFMA) O in-place VO; LN -> VO
    gemm128_kernel<<<256, 256, 0, stream>>>(X, 0, s_qkv, 2 * WMAT, s_qkvb, 256, VO, 4096, 128, 0,
                                            nullptr, 0, nullptr, 0, 0, flag);
    attn_kernel<1><<<dim3(16, 4), 512, 0, stream>>>(X, VO, nullptr, s_qkv, 0, WMAT, s_qkvb, 0, 128,
                                                    VO, center, rs, flag, 256, 1);
    proj_ln_kernel<<<512, 128, 0, stream>>>(X, VO, s_Wo, 0, s_bo, 0, s_ln, 0, VO, flag);

    // broadcast x1 -> X (32768 rows)
    bcast_kernel<<<16384, 256, 0, stream>>>(VO, X);

    // cross block 0
    gemm128_kernel<<<640, 256, 0, stream>>>(lang, 1, c_qkv, WMAT, c_qkvb, 128, Kc, 10240, 128, 0,
                                            nullptr, 0, nullptr, 0, 0, flag);
    gemm128_kernel<<<640, 256, 0, stream>>>(lang, 1, c_qkv, 2 * WMAT, c_qkvb, 256, Vc, 10240, 128, 0,
                                            nullptr, 0, nullptr, 0, 0, flag);
    attn_kernel<0><<<dim3(128, 4), 512, 0, stream>>>(X, Vc, Kc, c_qkv, 0, 0, c_qkvb, 0, 0,
                                                     VO, nullptr, nullptr, flag, 80, 1);
    proj_ln_kernel<<<4096, 128, 0, stream>>>(X, VO, c_Wo, 0, c_bo, 0, c_ln, 0, X, flag);

    // self block 1
    gemm128_kernel<<<2048, 256, 0, stream>>>(X, 0, s_qkv, 5 * WMAT, s_qkvb, 640, VO, 32768, 128, 0,
                                             nullptr, 0, nullptr, 0, 0, flag);
    attn_kernel<1><<<dim3(128, 4), 512, 0, stream>>>(X, VO, nullptr, s_qkv, 3 * WMAT, 4 * WMAT,
                                                     s_qkvb, 384, 512, VO, center, rs, flag, 256, 8);
    proj_ln_kernel<<<4096, 128, 0, stream>>>(X, VO, s_Wo, WMAT, s_bo, 128, s_ln, 256, X, flag);

    // cross block 1
    gemm128_kernel<<<640, 256, 0, stream>>>(lang, 1, c_qkv, 4 * WMAT, c_qkvb, 512, Kc, 10240, 128, 0,
                                            nullptr, 0, nullptr, 0, 0, flag);
    gemm128_kernel<<<640, 256, 0, stream>>>(lang, 1, c_qkv, 5 * WMAT, c_qkvb, 640, Vc, 10240, 128, 0,
                                            nullptr, 0, nullptr, 0, 0, flag);
    attn_kernel<0><<<dim3(128, 4), 512, 0, stream>>>(X, Vc, Kc, c_qkv, 3 * WMAT, 0, c_qkvb, 384, 0,
                                                     VO, nullptr, nullptr, flag, 80, 1);
    proj_ln_kernel<<<4096, 128, 0, stream>>>(X, VO, c_Wo, WMAT, c_bo, 128, c_ln, 256, X, flag);

    // match head
    gemm128_kernel<<<2048, 256, 0, stream>>>(X, 0, m_W, 0, m_b, 0, VO, 32768, 128, 1,
                                             m_bn, 0, m_al, 0, 0, flag);
    gemm128_kernel<<<2048, 256, 0, stream>>>(VO, 0, m_W, WMAT, m_b, 128, X, 32768, 128, 1,
                                             m_bn, 512, m_al, 1, 0, flag);
    final_dot_kernel<<<32768, 64, 0, stream>>>(X, m_W3, m_b3, d_out, flag);
}

// Round 9
// 924.656 us; speedup vs baseline: 1.8525x; 1.1039x over previous
//
#include <hip/hip_runtime.h>

// ---------------------------------------------------------------------------
// MatchModule forward. H=4 D=128 B=16 K=256 M=8 L=80 DET_C=1152, dk=32.
// R9: ALL dense projections moved to MFMA (mfma_f32_16x16x32_bf16) via a
// unified mfma_gemm: block = 64 rows x 128 cols, 4 waves, A-chunk + W^T staged
// bf16 in LDS (stride 136), f32 accum; epilogue = bias | BN+PReLU | residual.
// proj_ln split into mfma_gemm(residual) + in-place row-LN pass.
// Attention kernel unchanged from R8 (proven).
// ws layout unchanged (42.1 MiB): flag | rowsum | X | VO | Kc | Vc.
// ---------------------------------------------------------------------------

#define DD 128
#define WMAT 16384

typedef __attribute__((ext_vector_type(8))) short bf16x8;
typedef __attribute__((ext_vector_type(4))) float f32x4;

__device__ __forceinline__ float bf2f(unsigned short u) {
    union { unsigned int i; float f; } v; v.i = ((unsigned int)u) << 16; return v.f;
}
__device__ __forceinline__ unsigned short f2bf(float f) {
    union { float f; unsigned int i; } v; v.f = f;
    unsigned int x = v.i;
    return (unsigned short)((x + 0x7FFFu + ((x >> 16) & 1u)) >> 16);
}
__device__ __forceinline__ unsigned pack2bf(float a, float b) {
    return (unsigned)f2bf(a) | ((unsigned)f2bf(b) << 16);
}
__device__ __forceinline__ float ldx(const void* p, size_t i, int isf32) {
    return isf32 ? ((const float*)p)[i] : bf2f(((const unsigned short*)p)[i]);
}
__device__ __forceinline__ bf16x8 ld_frag8(const unsigned short* base) {  // 16B-capable
    union { bf16x8 v; uint2 u[2]; } r;
    r.u[0] = *(const uint2*)(base);
    r.u[1] = *(const uint2*)(base + 4);
    return r.v;
}

// ---------------------------------------------------------------------------
__global__ __launch_bounds__(256) void detect_kernel(
    const unsigned short* __restrict__ c, int* __restrict__ flag) {
    __shared__ int cnt;
    if (threadIdx.x == 0) cnt = 0;
    __syncthreads();
    float v = bf2f(c[threadIdx.x]);
    int sane = (v == v) && (fabsf(v) <= 1e4f) && (v == 0.f || fabsf(v) >= 1e-10f);
    atomicAdd(&cnt, sane);
    __syncthreads();
    if (threadIdx.x == 0) flag[0] = (cnt >= 224) ? 0 : 1;  // 0=bf16, 1=f32
}

__global__ void sentinel_kernel(unsigned short* out, int n, int val) {
    int i = blockIdx.x * 256 + threadIdx.x;
    if (i < n) out[i] = (unsigned short)val;
}

// ---------------------------------------------------------------------------
__global__ __launch_bounds__(256) void rowsum_kernel(
    const void* __restrict__ center, float* __restrict__ rs,
    const int* __restrict__ flagp) {
    const int isf32 = *flagp;
    const int b = blockIdx.x, i = threadIdx.x;
    __shared__ float c[768];
    for (int idx = i; idx < 768; idx += 256) c[idx] = ldx(center, (size_t)b * 768 + idx, isf32);
    __syncthreads();
    const float cx = c[i * 3], cy = c[i * 3 + 1], cz = c[i * 3 + 2];
    float s = 0.f;
    for (int j = 0; j < 256; ++j) {
        float dx = cx - c[j * 3], dy = cy - c[j * 3 + 1], dz = cz - c[j * 3 + 2];
        s += 1.f / (sqrtf(dx * dx + dy * dy + dz * dz) + 0.01f);
    }
    rs[b * 256 + i] = s;
}

// ---------------------------------------------------------------------------
// MFMA GEMM: out(nrows,128) = A(nrows,Kdim) @ W(Kdim,128) + bias [+res|+BN/PReLU]
// Block: 256 thr = 4 waves; 64 rows x 128 cols per block; K in chunks of 128.
// LDS: sA[64][136] bf16, sWT[128][136] bf16 (W^T). f32 accum (8x f32x4/lane).
// Frag convention (proven in R8 attn): mfma(A,B) = A.B^T, both frags
// row-major [row = l&15][k = (l>>4)*8..+7]; D: col=l&15, row=(l>>4)*4+reg.
// AEXT: A is external (flag dtype) else ws f32. RES: +Xres elementwise.
// EPI: BN+PReLU. In-place safe: block reads only its own A rows before writes.
// ---------------------------------------------------------------------------
template <int AEXT, int RES, int EPI>
__global__ __launch_bounds__(256, 3) void mfma_gemm_kernel(
    const void* __restrict__ A, const void* __restrict__ W, int wOff,
    const void* __restrict__ bias, int bOff,
    const float* __restrict__ Xres, float* __restrict__ out,
    int nrows, int Kdim,
    const void* __restrict__ bn, int bnOff,
    const void* __restrict__ alpha, int aOff, int alpha_pc,
    const int* __restrict__ flagp) {
    __shared__ __align__(16) unsigned short sA[64 * 136];
    __shared__ __align__(16) unsigned short sWT[128 * 136];
    const int isf32 = *flagp;
    const int aF = AEXT ? isf32 : 1;
    const int tid = threadIdx.x;
    const int l = tid & 63, w = tid >> 6;
    const int lg = l >> 4, ll = l & 15;
    const int m0 = blockIdx.x * 64;
    const f32x4 zf = {0.f, 0.f, 0.f, 0.f};
    f32x4 acc[8] = {zf, zf, zf, zf, zf, zf, zf, zf};

    const int nch = Kdim >> 7;
    for (int kc = 0; kc < nch; ++kc) {
        const int koff = kc * 128;
        // stage A chunk (64 x 128) -> bf16
#pragma unroll 8
        for (int i = 0; i < 32; ++i) {
            const int e = tid + i * 256;
            const int m = e >> 7, kk = e & 127;
            sA[m * 136 + kk] = f2bf(ldx(A, (size_t)(m0 + m) * Kdim + koff + kk, aF));
        }
        // stage W^T chunk (128 x 128) -> bf16
#pragma unroll 8
        for (int i = 0; i < 64; ++i) {
            const int e = tid + i * 256;
            const int k = e >> 7, n = e & 127;
            sWT[n * 136 + k] = f2bf(ldx(W, (size_t)wOff + (size_t)(koff + k) * 128 + n, isf32));
        }
        __syncthreads();
#pragma unroll
        for (int ks = 0; ks < 4; ++ks) {
            const bf16x8 af = ld_frag8(sA + (w * 16 + ll) * 136 + ks * 32 + lg * 8);
#pragma unroll
            for (int nt = 0; nt < 8; ++nt) {
                const bf16x8 bfr = ld_frag8(sWT + (nt * 16 + ll) * 136 + ks * 32 + lg * 8);
                acc[nt] = __builtin_amdgcn_mfma_f32_16x16x32_bf16(af, bfr, acc[nt], 0, 0, 0);
            }
        }
        __syncthreads();
    }

    // epilogue
    const int rbase = m0 + w * 16 + lg * 4;
#pragma unroll
    for (int nt = 0; nt < 8; ++nt) {
        const int col = nt * 16 + ll;
        const float bs = ldx(bias, (size_t)bOff + col, isf32);
        float g = 1.f, bb = 0.f, mmn = 0.f, rinv = 1.f, al = 0.f;
        if (EPI) {
            g    = ldx(bn, (size_t)bnOff + col, isf32);
            bb   = ldx(bn, (size_t)bnOff + 128 + col, isf32);
            mmn  = ldx(bn, (size_t)bnOff + 256 + col, isf32);
            rinv = rsqrtf(ldx(bn, (size_t)bnOff + 384 + col, isf32) + 1e-5f);
            al   = alpha_pc ? ldx(alpha, (size_t)aOff + col, isf32)
                            : ldx(alpha, (size_t)aOff, isf32);
        }
#pragma unroll
        for (int r = 0; r < 4; ++r) {
            const int row = rbase + r;
            float v = acc[nt][r] + bs;
            if (RES) v += Xres[(size_t)row * 128 + col];
            if (EPI) {
                v = g * (v - mmn) * rinv + bb;
                v = (v >= 0.f) ? v : al * v;
            }
            out[(size_t)row * 128 + col] = v;
        }
    }
}

// ---------------------------------------------------------------------------
// In-place row LayerNorm: Y[row] = gam*(Y[row]-mu)*rsqrt(var+eps)+bet.
// Wave per row (2 elems/lane); block = 4 rows.
// ---------------------------------------------------------------------------
__global__ __launch_bounds__(256) void ln_kernel(
    float* __restrict__ Y, const void* __restrict__ ln, int lnOff,
    const int* __restrict__ flagp) {
    const int isf32 = *flagp;
    const int lane = threadIdx.x & 63;
    const int row = blockIdx.x * 4 + (threadIdx.x >> 6);
    float* yp = Y + (size_t)row * 128;
    const float v0 = yp[lane], v1 = yp[lane + 64];
    float s1 = v0 + v1, s2 = v0 * v0 + v1 * v1;
#pragma unroll
    for (int o = 1; o < 64; o <<= 1) { s1 += __shfl_xor(s1, o); s2 += __shfl_xor(s2, o); }
    const float mu = s1 * (1.f / 128.f);
    const float var = s2 * (1.f / 128.f) - mu * mu;
    const float rq = rsqrtf(var + 1e-5f);
    const float g0 = ldx(ln, (size_t)lnOff + lane, isf32);
    const float g1 = ldx(ln, (size_t)lnOff + 64 + lane, isf32);
    const float b0 = ldx(ln, (size_t)lnOff + 128 + lane, isf32);
    const float b1 = ldx(ln, (size_t)lnOff + 192 + lane, isf32);
    yp[lane]      = g0 * (v0 - mu) * rq + b0;
    yp[lane + 64] = g1 * (v1 - mu) * rq + b1;
}

// ---------------------------------------------------------------------------
// Half-projection r[0:16] += sum_k x[k]*sW[k*32 + e*16 + i]  (attn Q/K proj)
// ---------------------------------------------------------------------------
#define PSTEP16(XS, KK)                                                       \
    {                                                                         \
        const float xs = (XS);                                                \
        const float4* w = (const float4*)(wb + (k4 * 4 + (KK)) * 32);         \
        _Pragma("unroll") for (int c = 0; c < 4; ++c) {                       \
            const float4 wv = w[c];                                           \
            r[4 * c]     = fmaf(xs, wv.x, r[4 * c]);                          \
            r[4 * c + 1] = fmaf(xs, wv.y, r[4 * c + 1]);                      \
            r[4 * c + 2] = fmaf(xs, wv.z, r[4 * c + 2]);                      \
            r[4 * c + 3] = fmaf(xs, wv.w, r[4 * c + 3]);                      \
        }                                                                     \
    }

__device__ __forceinline__ void proj16(float* r, const float* xq, const float* sW, int e) {
    const float4* x4 = (const float4*)xq;
    const float* wb = sW + e * 16;
    for (int k4 = 0; k4 < 32; ++k4) {
        const float4 xv = x4[k4];
        PSTEP16(xv.x, 0)
        PSTEP16(xv.y, 1)
        PSTEP16(xv.z, 2)
        PSTEP16(xv.w, 3)
    }
}

// ---------------------------------------------------------------------------
// MFMA flash attention (unchanged from R8 — proven).
// ---------------------------------------------------------------------------
template <int SELF>
__global__ __launch_bounds__(512, 2) void attn_kernel(
    const float* __restrict__ X, const float* __restrict__ Vg,
    const float* __restrict__ Kc,
    const void* __restrict__ Wqkv, int wqOff, int wkOff,
    const void* __restrict__ bqkv, int bqOff, int bkOff,
    float* __restrict__ O,
    const void* __restrict__ center, const float* __restrict__ rs,
    const int* __restrict__ flagp, int nk, int bDiv) {
    __shared__ __align__(16) char smem[54784 + (SELF ? 4096 : 0)];
    float* sW           = (float*)smem;                        // 16 KB (staging)
    unsigned short* sVT = (unsigned short*)smem;               // [32][264] bf16 (alias)
    unsigned short* sKb = (unsigned short*)(smem + 16896);     // [256][36] bf16
    unsigned short* sQP = (unsigned short*)(smem + 35328);     // [256][36] bf16 (Q then P)
    float* sF           = (float*)(smem + 53760);              // [256]
    float* sC           = (float*)(smem + 54784);              // [768] (SELF)
    float* sR           = sC + 768;                            // [256] (SELF)

    const int isf32 = *flagp;
    const int s = blockIdx.x, h = blockIdx.y, tid = threadIdx.x;
    const int l = tid & 63, w = tid >> 6;
    const int hc = h * 32;
    const int lg = l >> 4;
    const int ll = l & 15;
    const int qp = tid >> 1, e = tid & 1;

    // ---- phase 1: Wq stage + centers ----
    for (int idx = tid; idx < 4096; idx += 512) {
        const int k = idx >> 5, i = idx & 31;
        sW[idx] = ldx(Wqkv, (size_t)wqOff + (size_t)k * DD + hc + i, isf32);
    }
    if (SELF) {
        const int bb = s / bDiv;
        for (int idx = tid; idx < 768; idx += 512)
            sC[idx] = ldx(center, (size_t)bb * 768 + idx, isf32);
        if (tid < 256) sR[tid] = 1.0f / rs[(s / bDiv) * 256 + tid];
    }
    __syncthreads();

    // ---- phase 2: Q projection -> sQP bf16 ----
    const float* xq = X + (size_t)(s * 256 + qp) * DD;
    {
        float r[16];
#pragma unroll
        for (int i = 0; i < 16; ++i) r[i] = ldx(bqkv, (size_t)bqOff + hc + e * 16 + i, isf32);
        proj16(r, xq, sW, e);
        unsigned* dst = (unsigned*)((char*)sQP + qp * 72 + e * 32);
#pragma unroll
        for (int i = 0; i < 8; ++i) dst[i] = pack2bf(r[2 * i], r[2 * i + 1]);
    }
    __syncthreads();

    // ---- phase 3: K -> sKb bf16 ----
    if (SELF) {
        for (int idx = tid; idx < 4096; idx += 512) {
            const int k = idx >> 5, i = idx & 31;
            sW[idx] = ldx(Wqkv, (size_t)wkOff + (size_t)k * DD + hc + i, isf32);
        }
        __syncthreads();
        float r[16];
#pragma unroll
        for (int i = 0; i < 16; ++i) r[i] = ldx(bqkv, (size_t)bkOff + hc + e * 16 + i, isf32);
        proj16(r, xq, sW, e);
        unsigned* dst = (unsigned*)((char*)sKb + qp * 72 + e * 32);
#pragma unroll
        for (int i = 0; i < 8; ++i) dst[i] = pack2bf(r[2 * i], r[2 * i + 1]);
    } else {
        for (int idx = tid; idx < nk * 32; idx += 512) {
            const int j = idx >> 5, i = idx & 31;
            sKb[j * 36 + i] = f2bf(Kc[((size_t)(s * nk + j)) * DD + hc + i]);
        }
    }
    __syncthreads();

    // ---- phase 4: Q fragments ----
    bf16x8 qfrag[2];
#pragma unroll
    for (int sub = 0; sub < 2; ++sub) {
        const int qrow = w * 32 + sub * 16 + ll;
        qfrag[sub] = ld_frag8(sQP + qrow * 36 + lg * 8);
    }

    // ---- phase 5: V^T -> sVT bf16 ----
    const int nkR = (nk + 31) & ~31;
    for (int idx = tid; idx < nkR * 32; idx += 512) {
        const int j = idx >> 5, i = idx & 31;
        const float v = (j < nk) ? Vg[((size_t)(s * nk + j)) * DD + hc + i] : 0.f;
        sVT[i * 264 + j] = f2bf(v);
    }
    __syncthreads();

    // ---- phase 6: flash k-loop ----
    const float scale = 0.17677669529663687f;
    float cqx[2], cqy[2], cqz[2];
    if (SELF) {
#pragma unroll
        for (int sub = 0; sub < 2; ++sub) {
            const int qg = w * 32 + sub * 16 + ll;
            cqx[sub] = sC[qg * 3]; cqy[sub] = sC[qg * 3 + 1]; cqz[sub] = sC[qg * 3 + 2];
        }
    }
    float m_[2] = {-3.0e38f, -3.0e38f}, l_[2] = {0.f, 0.f};
    const f32x4 zf = {0.f, 0.f, 0.f, 0.f};
    f32x4 oacc[2][2] = {{zf, zf}, {zf, zf}};
    unsigned short* sPw = sQP + w * 32 * 36;

    for (int kb = 0; kb < nk; kb += 32) {
        const int full = (nk - kb) >= 32;
        const unsigned short* kbase = sKb + (kb + ll) * 36 + lg * 8;
        const bf16x8 kf0 = ld_frag8(kbase);
        bf16x8 kf1;
        if (full) kf1 = ld_frag8(kbase + 16 * 36);

#pragma unroll
        for (int sub = 0; sub < 2; ++sub) {
            f32x4 s0 = __builtin_amdgcn_mfma_f32_16x16x32_bf16(kf0, qfrag[sub], zf, 0, 0, 0);
            f32x4 s1 = zf;
            if (full) s1 = __builtin_amdgcn_mfma_f32_16x16x32_bf16(kf1, qfrag[sub], zf, 0, 0, 0);

            float sc[8];
#pragma unroll
            for (int r = 0; r < 4; ++r) {
                const int k0 = kb + lg * 4 + r;
                float v0 = s0[r] * scale;
                float v1 = full ? s1[r] * scale : -3.0e38f;
                if (SELF && h < 2) {
                    {
                        const float dx = cqx[sub] - sC[k0 * 3], dy = cqy[sub] - sC[k0 * 3 + 1],
                                    dz = cqz[sub] - sC[k0 * 3 + 2];
                        const float dist = sqrtf(dx * dx + dy * dy + dz * dz);
                        if (h == 0) v0 += __fdividef(1.f, dist + 0.01f) * sR[k0];
                        else v0 -= dist;
                    }
                    if (full) {
                        const int k1 = k0 + 16;
                        const float dx = cqx[sub] - sC[k1 * 3], dy = cqy[sub] - sC[k1 * 3 + 1],
                                    dz = cqz[sub] - sC[k1 * 3 + 2];
                        const float dist = sqrtf(dx * dx + dy * dy + dz * dz);
                        if (h == 0) v1 += __fdividef(1.f, dist + 0.01f) * sR[k1];
                        else v1 -= dist;
                    }
                }
                sc[r] = v0; sc[4 + r] = v1;
            }
            float tmax = fmaxf(fmaxf(fmaxf(sc[0], sc[1]), fmaxf(sc[2], sc[3])),
                               fmaxf(fmaxf(sc[4], sc[5]), fmaxf(sc[6], sc[7])));
            tmax = fmaxf(tmax, __shfl_xor(tmax, 16));
            tmax = fmaxf(tmax, __shfl_xor(tmax, 32));
            const float mnew = fmaxf(m_[sub], tmax);
            const float f = __expf(m_[sub] - mnew);
            m_[sub] = mnew;
            float p[8], lsum = 0.f;
#pragma unroll
            for (int u = 0; u < 8; ++u) { p[u] = __expf(sc[u] - mnew); lsum += p[u]; }
            lsum += __shfl_xor(lsum, 16);
            lsum += __shfl_xor(lsum, 32);
            l_[sub] = l_[sub] * f + lsum;
            if (lg == 0) sF[w * 32 + sub * 16 + ll] = f;
            unsigned* prow = (unsigned*)((char*)sPw + (sub * 16 + ll) * 72 + lg * 8);
            prow[0] = pack2bf(p[0], p[1]);
            prow[1] = pack2bf(p[2], p[3]);
            unsigned* prow1 = (unsigned*)((char*)prow + 32);
            prow1[0] = pack2bf(p[4], p[5]);
            prow1[1] = pack2bf(p[6], p[7]);
        }

        bf16x8 vf[2], pf[2];
#pragma unroll
        for (int dt = 0; dt < 2; ++dt)
            vf[dt] = *(const bf16x8*)(sVT + (dt * 16 + ll) * 264 + kb + lg * 8);
#pragma unroll
        for (int sub = 0; sub < 2; ++sub) {
            pf[sub] = ld_frag8(sPw + (sub * 16 + ll) * 36 + lg * 8);
            float fr[4];
#pragma unroll
            for (int r = 0; r < 4; ++r) fr[r] = sF[w * 32 + sub * 16 + lg * 4 + r];
#pragma unroll
            for (int dt = 0; dt < 2; ++dt) {
#pragma unroll
                for (int r = 0; r < 4; ++r) oacc[sub][dt][r] *= fr[r];
                oacc[sub][dt] = __builtin_amdgcn_mfma_f32_16x16x32_bf16(
                    pf[sub], vf[dt], oacc[sub][dt], 0, 0, 0);
            }
        }
    }

    // ---- phase 7: normalize + write O ----
    if (lg == 0) {
        sF[w * 32 + ll]      = 1.f / l_[0];
        sF[w * 32 + 16 + ll] = 1.f / l_[1];
    }
#pragma unroll
    for (int sub = 0; sub < 2; ++sub) {
#pragma unroll
        for (int r = 0; r < 4; ++r) {
            const float li = sF[w * 32 + sub * 16 + lg * 4 + r];
            const int qrow = w * 32 + sub * 16 + lg * 4 + r;
#pragma unroll
            for (int dt = 0; dt < 2; ++dt) {
                O[((size_t)(s * 256 + qrow)) * DD + hc + dt * 16 + ll] = oacc[sub][dt][r] * li;
            }
        }
    }
}

__global__ __launch_bounds__(256) void bcast_kernel(
    const float* __restrict__ src, float* __restrict__ dst) {
    const int i = blockIdx.x * 256 + threadIdx.x;
    const int rowd = i >> 7, d = i & 127;
    const int sq = rowd >> 8, n = rowd & 255, b = sq >> 3;
    dst[i] = src[((size_t)(b * 256 + n)) * DD + d];
}

__global__ __launch_bounds__(64) void final_dot_kernel(
    const float* __restrict__ Y, const void* __restrict__ W3,
    const void* __restrict__ b3, void* __restrict__ out,
    const int* __restrict__ flagp) {
    const int isf32 = *flagp;
    const int row = blockIdx.x, lid = threadIdx.x;
    const float* yp = Y + (size_t)row * DD;
    float v = yp[lid] * ldx(W3, lid, isf32) + yp[lid + 64] * ldx(W3, (size_t)lid + 64, isf32);
#pragma unroll
    for (int o = 1; o < 64; o <<= 1) v += __shfl_xor(v, o);
    if (lid == 0) {
        const float r = v + ldx(b3, 0, isf32);
        if (isf32) ((float*)out)[row] = r;
        else ((unsigned short*)out)[row] = f2bf(r);
    }
}

// ---------------------------------------------------------------------------

extern "C" void kernel_launch(void* const* d_in, const int* in_sizes, int n_in,
                              void* d_out, int out_size, void* d_ws, size_t ws_size,
                              hipStream_t stream) {
    bool ok = (n_in >= 29) && in_sizes[0] == 12288 && in_sizes[1] == 4718592 &&
              in_sizes[2] == 1310720 && in_sizes[7] == 147456 &&
              in_sizes[13] == 98304 && in_sizes[25] == 1024 && in_sizes[27] == 128;
    if (!ok) {
        sentinel_kernel<<<(out_size + 255) / 256, 256, 0, stream>>>(
            (unsigned short*)d_out, out_size, 0x44FA);
        return;
    }
    const size_t SZ = (size_t)32768 * 128;
    const size_t NEED = (16384ull + 2ull * SZ + 2ull * 10240 * 128) * 4ull;
    if (ws_size < NEED) {
        sentinel_kernel<<<(out_size + 255) / 256, 256, 0, stream>>>(
            (unsigned short*)d_out, out_size, 0x447A);
        return;
    }

    const void* center = d_in[0];
    const void* detr   = d_in[1];
    const void* lang   = d_in[2];
    const void* fc1_W  = d_in[7];
    const void* fc1_b  = d_in[8];
    const void* bn0    = d_in[9];
    const void* prelu0 = d_in[10];
    const void* fc2_W  = d_in[11];
    const void* fc2_b  = d_in[12];
    const void* s_qkv  = d_in[13];
    const void* s_qkvb = d_in[14];
    const void* s_Wo   = d_in[15];
    const void* s_bo   = d_in[16];
    const void* s_ln   = d_in[17];
    const void* c_qkv  = d_in[18];
    const void* c_qkvb = d_in[19];
    const void* c_Wo   = d_in[20];
    const void* c_bo   = d_in[21];
    const void* c_ln   = d_in[22];
    const void* m_W    = d_in[23];
    const void* m_b    = d_in[24];
    const void* m_bn   = d_in[25];
    const void* m_al   = d_in[26];
    const void* m_W3   = d_in[27];
    const void* m_b3   = d_in[28];

    float* wsf  = (float*)d_ws;
    int*   flag = (int*)d_ws;
    float* rs   = wsf + 4096;
    float* X    = wsf + 16384;
    float* VO   = X + SZ;
    float* Kc   = VO + SZ;
    float* Vc   = Kc + (size_t)10240 * 128;

    detect_kernel<<<1, 256, 0, stream>>>((const unsigned short*)center, flag);
    rowsum_kernel<<<16, 256, 0, stream>>>(center, rs, flag);

    // fc1 (+BN+PReLU per-channel) -> VO; fc2 -> X = x0
    mfma_gemm_kernel<1, 0, 1><<<64, 256, 0, stream>>>(detr, fc1_W, 0, fc1_b, 0, nullptr, VO,
                                                      4096, 1152, bn0, 0, prelu0, 0, 1, flag);
    mfma_gemm_kernel<0, 0, 0><<<64, 256, 0, stream>>>(VO, fc2_W, 0, fc2_b, 0, nullptr, X,
                                                      4096, 128, nullptr, 0, nullptr, 0, 0, flag);

    // self block 0: V -> VO; attn O in-place VO; proj(+res X) -> VO; LN VO
    mfma_gemm_kernel<0, 0, 0><<<64, 256, 0, stream>>>(X, s_qkv, 2 * WMAT, s_qkvb, 256, nullptr, VO,
                                                      4096, 128, nullptr, 0, nullptr, 0, 0, flag);
    attn_kernel<1><<<dim3(16, 4), 512, 0, stream>>>(X, VO, nullptr, s_qkv, 0, WMAT, s_qkvb, 0, 128,
                                                    VO, center, rs, flag, 256, 1);
    mfma_gemm_kernel<0, 1, 0><<<64, 256, 0, stream>>>(VO, s_Wo, 0, s_bo, 0, X, VO,
                                                      4096, 128, nullptr, 0, nullptr, 0, 0, flag);
    ln_kernel<<<1024, 256, 0, stream>>>(VO, s_ln, 0, flag);

    // broadcast x1 -> X (32768 rows)
    bcast_kernel<<<16384, 256, 0, stream>>>(VO, X);

    // cross block 0: K,V from lang; attn -> VO; proj(+res X) -> X; LN X
    mfma_gemm_kernel<1, 0, 0><<<160, 256, 0, stream>>>(lang, c_qkv, WMAT, c_qkvb, 128, nullptr, Kc,
                                                       10240, 128, nullptr, 0, nullptr, 0, 0, flag);
    mfma_gemm_kernel<1, 0, 0><<<160, 256, 0, stream>>>(lang, c_qkv, 2 * WMAT, c_qkvb, 256, nullptr, Vc,
                                                       10240, 128, nullptr, 0, nullptr, 0, 0, flag);
    attn_kernel<0><<<dim3(128, 4), 512, 0, stream>>>(X, Vc, Kc, c_qkv, 0, 0, c_qkvb, 0, 0,
                                                     VO, nullptr, nullptr, flag, 80, 1);
    mfma_gemm_kernel<0, 1, 0><<<512, 256, 0, stream>>>(VO, c_Wo, 0, c_bo, 0, X, X,
                                                       32768, 128, nullptr, 0, nullptr, 0, 0, flag);
    ln_kernel<<<8192, 256, 0, stream>>>(X, c_ln, 0, flag);

    // self block 1: V -> VO; attn -> VO; proj(+res X) -> X; LN X
    mfma_gemm_kernel<0, 0, 0><<<512, 256, 0, stream>>>(X, s_qkv, 5 * WMAT, s_qkvb, 640, nullptr, VO,
                                                       32768, 128, nullptr, 0, nullptr, 0, 0, flag);
    attn_kernel<1><<<dim3(128, 4), 512, 0, stream>>>(X, VO, nullptr, s_qkv, 3 * WMAT, 4 * WMAT,
                                                     s_qkvb, 384, 512, VO, center, rs, flag, 256, 8);
    mfma_gemm_kernel<0, 1, 0><<<512, 256, 0, stream>>>(VO, s_Wo, WMAT, s_bo, 128, X, X,
                                                       32768, 128, nullptr, 0, nullptr, 0, 0, flag);
    ln_kernel<<<8192, 256, 0, stream>>>(X, s_ln, 256, flag);

    // cross block 1
    mfma_gemm_kernel<1, 0, 0><<<160, 256, 0, stream>>>(lang, c_qkv, 4 * WMAT, c_qkvb, 512, nullptr, Kc,
                                                       10240, 128, nullptr, 0, nullptr, 0, 0, flag);
    mfma_gemm_kernel<1, 0, 0><<<160, 256, 0, stream>>>(lang, c_qkv, 5 * WMAT, c_qkvb, 640, nullptr, Vc,
                                                       10240, 128, nullptr, 0, nullptr, 0, 0, flag);
    attn_kernel<0><<<dim3(128, 4), 512, 0, stream>>>(X, Vc, Kc, c_qkv, 3 * WMAT, 0, c_qkvb, 384, 0,
                                                     VO, nullptr, nullptr, flag, 80, 1);
    mfma_gemm_kernel<0, 1, 0><<<512, 256, 0, stream>>>(VO, c_Wo, WMAT, c_bo, 128, X, X,
                                                       32768, 128, nullptr, 0, nullptr, 0, 0, flag);
    ln_kernel<<<8192, 256, 0, stream>>>(X, c_ln, 256, flag);

    // match head
    mfma_gemm_kernel<0, 0, 1><<<512, 256, 0, stream>>>(X, m_W, 0, m_b, 0, nullptr, VO,
                                                       32768, 128, m_bn, 0, m_al, 0, 0, flag);
    mfma_gemm_kernel<0, 0, 1><<<512, 256, 0, stream>>>(VO, m_W, WMAT, m_b, 128, nullptr, X,
                                                       32768, 128, m_bn, 512, m_al, 1, 0, flag);
    final_dot_kernel<<<32768, 64, 0, stream>>>(X, m_W3, m_b3, d_out, flag);
}

// Round 10
// 561.856 us; speedup vs baseline: 3.0487x; 1.6457x over previous
//
#include <hip/hip_runtime.h>

// ---------------------------------------------------------------------------
// MatchModule forward. H=4 D=128 B=16 K=256 M=8 L=80 DET_C=1152, dk=32.
// R10: GEMM de-staged. prep_wt transposes all weights ONCE to bf16 Wt[n][k]
// in ws; mfma_gemm reads A- and W^T-fragments DIRECTLY from global (no LDS,
// no barriers, no staging serialization; W is L1/L2-resident and shared by
// all blocks). Kc/Vc stored bf16 (attn consumes bf16 anyway; frees room for
// Wt). Attention kernel = R8/R9 (proven), with bf16 K/V inputs for cross.
//
// ws bytes: flag@0 | rs@16K | X@64K (f32 32768x128) | VO (f32) |
//           KcB bf16 10240x128 | VcB bf16 | Wt bf16 458752  = 39.78 MB
// (NEED check unchanged at 44.1 MB — proven available since R4.)
// ---------------------------------------------------------------------------

#define DD 128
#define WMAT 16384

typedef __attribute__((ext_vector_type(8))) short bf16x8;
typedef __attribute__((ext_vector_type(4))) float f32x4;

__device__ __forceinline__ float bf2f(unsigned short u) {
    union { unsigned int i; float f; } v; v.i = ((unsigned int)u) << 16; return v.f;
}
__device__ __forceinline__ unsigned short f2bf(float f) {
    union { float f; unsigned int i; } v; v.f = f;
    unsigned int x = v.i;
    return (unsigned short)((x + 0x7FFFu + ((x >> 16) & 1u)) >> 16);
}
__device__ __forceinline__ unsigned pack2bf(float a, float b) {
    return (unsigned)f2bf(a) | ((unsigned)f2bf(b) << 16);
}
__device__ __forceinline__ float ldx(const void* p, size_t i, int isf32) {
    return isf32 ? ((const float*)p)[i] : bf2f(((const unsigned short*)p)[i]);
}
__device__ __forceinline__ bf16x8 ld_frag8(const unsigned short* base) {  // 8B-aligned (LDS)
    union { bf16x8 v; uint2 u[2]; } r;
    r.u[0] = *(const uint2*)(base);
    r.u[1] = *(const uint2*)(base + 4);
    return r.v;
}
__device__ __forceinline__ bf16x8 ld_frag16g(const unsigned short* p) {   // 16B-aligned (global)
    union { bf16x8 v; uint4 u; } r;
    r.u = *(const uint4*)p;
    return r.v;
}

// ---------------------------------------------------------------------------
__global__ __launch_bounds__(256) void detect_kernel(
    const unsigned short* __restrict__ c, int* __restrict__ flag) {
    __shared__ int cnt;
    if (threadIdx.x == 0) cnt = 0;
    __syncthreads();
    float v = bf2f(c[threadIdx.x]);
    int sane = (v == v) && (fabsf(v) <= 1e4f) && (v == 0.f || fabsf(v) >= 1e-10f);
    atomicAdd(&cnt, sane);
    __syncthreads();
    if (threadIdx.x == 0) flag[0] = (cnt >= 224) ? 0 : 1;  // 0=bf16, 1=f32
}

__global__ void sentinel_kernel(unsigned short* out, int n, int val) {
    int i = blockIdx.x * 256 + threadIdx.x;
    if (i < n) out[i] = (unsigned short)val;
}

// ---------------------------------------------------------------------------
// prep_wt: Wt[region j] = bf16(W[k][n]) for all 20 weight matrices.
// region 0: fc1^T [n=128][k=1152] (j = n*1152+k). Then 19 mats of [128][128]:
// 0=fc2, 1..6=s_qkv, 7..8=s_Wo, 9..14=c_qkv, 15..16=c_Wo, 17..18=m_W.
// ---------------------------------------------------------------------------
__global__ __launch_bounds__(256) void prep_wt_kernel(
    const void* __restrict__ fc1_W, const void* __restrict__ fc2_W,
    const void* __restrict__ s_qkv, const void* __restrict__ s_Wo,
    const void* __restrict__ c_qkv, const void* __restrict__ c_Wo,
    const void* __restrict__ m_W, unsigned short* __restrict__ Wt,
    const int* __restrict__ flagp) {
    const int isf32 = *flagp;
    const int j = blockIdx.x * 256 + threadIdx.x;  // grid covers 458752 exactly
    float v;
    if (j < 147456) {
        const int n = j / 1152, k = j - n * 1152;
        v = ldx(fc1_W, (size_t)k * 128 + n, isf32);
    } else {
        const int t = j - 147456;
        const int mat = t >> 14, o = t & 16383;
        const int n = o >> 7, k = o & 127;
        const void* src; int loc;
        if (mat == 0)       { src = fc2_W; loc = 0; }
        else if (mat <= 6)  { src = s_qkv; loc = mat - 1; }
        else if (mat <= 8)  { src = s_Wo;  loc = mat - 7; }
        else if (mat <= 14) { src = c_qkv; loc = mat - 9; }
        else if (mat <= 16) { src = c_Wo;  loc = mat - 15; }
        else                { src = m_W;   loc = mat - 17; }
        v = ldx(src, (size_t)loc * 16384 + k * 128 + n, isf32);
    }
    Wt[j] = f2bf(v);
}

// ---------------------------------------------------------------------------
__global__ __launch_bounds__(256) void rowsum_kernel(
    const void* __restrict__ center, float* __restrict__ rs,
    const int* __restrict__ flagp) {
    const int isf32 = *flagp;
    const int b = blockIdx.x, i = threadIdx.x;
    __shared__ float c[768];
    for (int idx = i; idx < 768; idx += 256) c[idx] = ldx(center, (size_t)b * 768 + idx, isf32);
    __syncthreads();
    const float cx = c[i * 3], cy = c[i * 3 + 1], cz = c[i * 3 + 2];
    float s = 0.f;
    for (int j = 0; j < 256; ++j) {
        float dx = cx - c[j * 3], dy = cy - c[j * 3 + 1], dz = cz - c[j * 3 + 2];
        s += 1.f / (sqrtf(dx * dx + dy * dy + dz * dz) + 0.01f);
    }
    rs[b * 256 + i] = s;
}

// ---------------------------------------------------------------------------
// No-LDS MFMA GEMM: out(nrows,128) = A(nrows,Kdim) @ W + bias [+res | +BN/PReLU]
// Block: 256 thr = 4 waves, 64 rows x 128 cols. Wave w owns rows w*16..+15.
// A-frag: lane (lg,ll) reads A[m0+w*16+ll][kc+ks*32+lg*8 ..+7] from global.
// W-frag: reads Wt[(nt*16+ll)*Kdim + kc+ks*32+lg*8] (bf16, L1/L2-resident).
// D layout (proven R8/R9): col=ll (n), row=lg*4+r (m). No barriers, no LDS.
// In-place safe: each wave reads only its own 16 rows before writing them.
// ---------------------------------------------------------------------------
template <int OUTBF16, int RES, int EPI>
__global__ __launch_bounds__(256, 4) void mfma_gemm_kernel(
    const void* __restrict__ A, int aExt,
    const unsigned short* __restrict__ Wt, int wtOff,
    const void* __restrict__ bias, int bOff,
    const float* __restrict__ Xres, void* __restrict__ out,
    int nrows, int Kdim,
    const void* __restrict__ bn, int bnOff,
    const void* __restrict__ alpha, int aOff, int alpha_pc,
    const int* __restrict__ flagp) {
    const int isf32 = *flagp;
    const int aF32 = aExt ? isf32 : 1;
    const int tid = threadIdx.x;
    const int l = tid & 63, w = tid >> 6;
    const int lg = l >> 4, ll = l & 15;
    const int m0 = blockIdx.x * 64;
    const int arow = m0 + w * 16 + ll;
    const f32x4 zf = {0.f, 0.f, 0.f, 0.f};
    f32x4 acc[8] = {zf, zf, zf, zf, zf, zf, zf, zf};
    const float* Af = (const float*)A;
    const unsigned short* Au = (const unsigned short*)A;
    const unsigned short* Wb = Wt + wtOff;

    for (int kc = 0; kc < Kdim; kc += 128) {
        bf16x8 af[4];
        if (aF32) {
#pragma unroll
            for (int ks = 0; ks < 4; ++ks) {
                const float4* ap = (const float4*)(Af + (size_t)arow * Kdim + kc + ks * 32 + lg * 8);
                const float4 a0 = ap[0], a1 = ap[1];
                union { bf16x8 v; unsigned u[4]; } r;
                r.u[0] = pack2bf(a0.x, a0.y); r.u[1] = pack2bf(a0.z, a0.w);
                r.u[2] = pack2bf(a1.x, a1.y); r.u[3] = pack2bf(a1.z, a1.w);
                af[ks] = r.v;
            }
        } else {
#pragma unroll
            for (int ks = 0; ks < 4; ++ks)
                af[ks] = ld_frag16g(Au + (size_t)arow * Kdim + kc + ks * 32 + lg * 8);
        }
#pragma unroll
        for (int nt = 0; nt < 8; ++nt) {
#pragma unroll
            for (int ks = 0; ks < 4; ++ks) {
                const bf16x8 wf = ld_frag16g(Wb + (size_t)(nt * 16 + ll) * Kdim + kc + ks * 32 + lg * 8);
                acc[nt] = __builtin_amdgcn_mfma_f32_16x16x32_bf16(af[ks], wf, acc[nt], 0, 0, 0);
            }
        }
    }

    // epilogue
    const int rbase = m0 + w * 16 + lg * 4;
#pragma unroll
    for (int nt = 0; nt < 8; ++nt) {
        const int col = nt * 16 + ll;
        const float bs = ldx(bias, (size_t)bOff + col, isf32);
        float g = 1.f, bb = 0.f, mmn = 0.f, rinv = 1.f, al = 0.f;
        if (EPI) {
            g    = ldx(bn, (size_t)bnOff + col, isf32);
            bb   = ldx(bn, (size_t)bnOff + 128 + col, isf32);
            mmn  = ldx(bn, (size_t)bnOff + 256 + col, isf32);
            rinv = rsqrtf(ldx(bn, (size_t)bnOff + 384 + col, isf32) + 1e-5f);
            al   = alpha_pc ? ldx(alpha, (size_t)aOff + col, isf32)
                            : ldx(alpha, (size_t)aOff, isf32);
        }
#pragma unroll
        for (int r = 0; r < 4; ++r) {
            const int row = rbase + r;
            float v = acc[nt][r] + bs;
            if (RES) v += Xres[(size_t)row * 128 + col];
            if (EPI) {
                v = g * (v - mmn) * rinv + bb;
                v = (v >= 0.f) ? v : al * v;
            }
            if (OUTBF16) ((unsigned short*)out)[(size_t)row * 128 + col] = f2bf(v);
            else ((float*)out)[(size_t)row * 128 + col] = v;
        }
    }
}

// ---------------------------------------------------------------------------
// In-place row LayerNorm; wave per row, block = 4 rows.
// ---------------------------------------------------------------------------
__global__ __launch_bounds__(256) void ln_kernel(
    float* __restrict__ Y, const void* __restrict__ ln, int lnOff,
    const int* __restrict__ flagp) {
    const int isf32 = *flagp;
    const int lane = threadIdx.x & 63;
    const int row = blockIdx.x * 4 + (threadIdx.x >> 6);
    float* yp = Y + (size_t)row * 128;
    const float v0 = yp[lane], v1 = yp[lane + 64];
    float s1 = v0 + v1, s2 = v0 * v0 + v1 * v1;
#pragma unroll
    for (int o = 1; o < 64; o <<= 1) { s1 += __shfl_xor(s1, o); s2 += __shfl_xor(s2, o); }
    const float mu = s1 * (1.f / 128.f);
    const float var = s2 * (1.f / 128.f) - mu * mu;
    const float rq = rsqrtf(var + 1e-5f);
    const float g0 = ldx(ln, (size_t)lnOff + lane, isf32);
    const float g1 = ldx(ln, (size_t)lnOff + 64 + lane, isf32);
    const float b0 = ldx(ln, (size_t)lnOff + 128 + lane, isf32);
    const float b1 = ldx(ln, (size_t)lnOff + 192 + lane, isf32);
    yp[lane]      = g0 * (v0 - mu) * rq + b0;
    yp[lane + 64] = g1 * (v1 - mu) * rq + b1;
}

// ---------------------------------------------------------------------------
// attn Q/K half-projection (R7-proven)
// ---------------------------------------------------------------------------
#define PSTEP16(XS, KK)                                                       \
    {                                                                         \
        const float xs = (XS);                                                \
        const float4* w = (const float4*)(wb + (k4 * 4 + (KK)) * 32);         \
        _Pragma("unroll") for (int c = 0; c < 4; ++c) {                       \
            const float4 wv = w[c];                                           \
            r[4 * c]     = fmaf(xs, wv.x, r[4 * c]);                          \
            r[4 * c + 1] = fmaf(xs, wv.y, r[4 * c + 1]);                      \
            r[4 * c + 2] = fmaf(xs, wv.z, r[4 * c + 2]);                      \
            r[4 * c + 3] = fmaf(xs, wv.w, r[4 * c + 3]);                      \
        }                                                                     \
    }

__device__ __forceinline__ void proj16(float* r, const float* xq, const float* sW, int e) {
    const float4* x4 = (const float4*)xq;
    const float* wb = sW + e * 16;
    for (int k4 = 0; k4 < 32; ++k4) {
        const float4 xv = x4[k4];
        PSTEP16(xv.x, 0)
        PSTEP16(xv.y, 1)
        PSTEP16(xv.z, 2)
        PSTEP16(xv.w, 3)
    }
}

// ---------------------------------------------------------------------------
// MFMA flash attention (R8-proven). SELF: Vg = f32 (VO), Kc unused.
// cross: Vg/Kc = bf16 (VcB/KcB).
// ---------------------------------------------------------------------------
template <int SELF>
__global__ __launch_bounds__(512, 2) void attn_kernel(
    const float* __restrict__ X, const void* __restrict__ Vg,
    const void* __restrict__ Kc,
    const void* __restrict__ Wqkv, int wqOff, int wkOff,
    const void* __restrict__ bqkv, int bqOff, int bkOff,
    float* __restrict__ O,
    const void* __restrict__ center, const float* __restrict__ rs,
    const int* __restrict__ flagp, int nk, int bDiv) {
    __shared__ __align__(16) char smem[54784 + (SELF ? 4096 : 0)];
    float* sW           = (float*)smem;                        // 16 KB (staging)
    unsigned short* sVT = (unsigned short*)smem;               // [32][264] bf16 (alias)
    unsigned short* sKb = (unsigned short*)(smem + 16896);     // [256][36] bf16
    unsigned short* sQP = (unsigned short*)(smem + 35328);     // [256][36] bf16 (Q then P)
    float* sF           = (float*)(smem + 53760);              // [256]
    float* sC           = (float*)(smem + 54784);              // [768] (SELF)
    float* sR           = sC + 768;                            // [256] (SELF)

    const int isf32 = *flagp;
    const int s = blockIdx.x, h = blockIdx.y, tid = threadIdx.x;
    const int l = tid & 63, w = tid >> 6;
    const int hc = h * 32;
    const int lg = l >> 4;
    const int ll = l & 15;
    const int qp = tid >> 1, e = tid & 1;

    // ---- phase 1: Wq stage + centers ----
    for (int idx = tid; idx < 4096; idx += 512) {
        const int k = idx >> 5, i = idx & 31;
        sW[idx] = ldx(Wqkv, (size_t)wqOff + (size_t)k * DD + hc + i, isf32);
    }
    if (SELF) {
        const int bb = s / bDiv;
        for (int idx = tid; idx < 768; idx += 512)
            sC[idx] = ldx(center, (size_t)bb * 768 + idx, isf32);
        if (tid < 256) sR[tid] = 1.0f / rs[(s / bDiv) * 256 + tid];
    }
    __syncthreads();

    // ---- phase 2: Q projection -> sQP bf16 ----
    const float* xq = X + (size_t)(s * 256 + qp) * DD;
    {
        float r[16];
#pragma unroll
        for (int i = 0; i < 16; ++i) r[i] = ldx(bqkv, (size_t)bqOff + hc + e * 16 + i, isf32);
        proj16(r, xq, sW, e);
        unsigned* dst = (unsigned*)((char*)sQP + qp * 72 + e * 32);
#pragma unroll
        for (int i = 0; i < 8; ++i) dst[i] = pack2bf(r[2 * i], r[2 * i + 1]);
    }
    __syncthreads();

    // ---- phase 3: K -> sKb bf16 ----
    if (SELF) {
        for (int idx = tid; idx < 4096; idx += 512) {
            const int k = idx >> 5, i = idx & 31;
            sW[idx] = ldx(Wqkv, (size_t)wkOff + (size_t)k * DD + hc + i, isf32);
        }
        __syncthreads();
        float r[16];
#pragma unroll
        for (int i = 0; i < 16; ++i) r[i] = ldx(bqkv, (size_t)bkOff + hc + e * 16 + i, isf32);
        proj16(r, xq, sW, e);
        unsigned* dst = (unsigned*)((char*)sKb + qp * 72 + e * 32);
#pragma unroll
        for (int i = 0; i < 8; ++i) dst[i] = pack2bf(r[2 * i], r[2 * i + 1]);
    } else {
        const unsigned short* KcB = (const unsigned short*)Kc;
        for (int idx = tid; idx < nk * 32; idx += 512) {
            const int j = idx >> 5, i = idx & 31;
            sKb[j * 36 + i] = KcB[((size_t)(s * nk + j)) * DD + hc + i];
        }
    }
    __syncthreads();

    // ---- phase 4: Q fragments ----
    bf16x8 qfrag[2];
#pragma unroll
    for (int sub = 0; sub < 2; ++sub) {
        const int qrow = w * 32 + sub * 16 + ll;
        qfrag[sub] = ld_frag8(sQP + qrow * 36 + lg * 8);
    }

    // ---- phase 5: V^T -> sVT bf16 ----
    const int nkR = (nk + 31) & ~31;
    for (int idx = tid; idx < nkR * 32; idx += 512) {
        const int j = idx >> 5, i = idx & 31;
        unsigned short bv;
        if (SELF) {
            bv = (j < nk) ? f2bf(((const float*)Vg)[((size_t)(s * nk + j)) * DD + hc + i]) : 0;
        } else {
            bv = (j < nk) ? ((const unsigned short*)Vg)[((size_t)(s * nk + j)) * DD + hc + i] : 0;
        }
        sVT[i * 264 + j] = bv;
    }
    __syncthreads();

    // ---- phase 6: flash k-loop ----
    const float scale = 0.17677669529663687f;
    float cqx[2], cqy[2], cqz[2];
    if (SELF) {
#pragma unroll
        for (int sub = 0; sub < 2; ++sub) {
            const int qg = w * 32 + sub * 16 + ll;
            cqx[sub] = sC[qg * 3]; cqy[sub] = sC[qg * 3 + 1]; cqz[sub] = sC[qg * 3 + 2];
        }
    }
    float m_[2] = {-3.0e38f, -3.0e38f}, l_[2] = {0.f, 0.f};
    const f32x4 zf = {0.f, 0.f, 0.f, 0.f};
    f32x4 oacc[2][2] = {{zf, zf}, {zf, zf}};
    unsigned short* sPw = sQP + w * 32 * 36;

    for (int kb = 0; kb < nk; kb += 32) {
        const int full = (nk - kb) >= 32;
        const unsigned short* kbase = sKb + (kb + ll) * 36 + lg * 8;
        const bf16x8 kf0 = ld_frag8(kbase);
        bf16x8 kf1;
        if (full) kf1 = ld_frag8(kbase + 16 * 36);

#pragma unroll
        for (int sub = 0; sub < 2; ++sub) {
            f32x4 s0 = __builtin_amdgcn_mfma_f32_16x16x32_bf16(kf0, qfrag[sub], zf, 0, 0, 0);
            f32x4 s1 = zf;
            if (full) s1 = __builtin_amdgcn_mfma_f32_16x16x32_bf16(kf1, qfrag[sub], zf, 0, 0, 0);

            float sc[8];
#pragma unroll
            for (int r = 0; r < 4; ++r) {
                const int k0 = kb + lg * 4 + r;
                float v0 = s0[r] * scale;
                float v1 = full ? s1[r] * scale : -3.0e38f;
                if (SELF && h < 2) {
                    {
                        const float dx = cqx[sub] - sC[k0 * 3], dy = cqy[sub] - sC[k0 * 3 + 1],
                                    dz = cqz[sub] - sC[k0 * 3 + 2];
                        const float dist = sqrtf(dx * dx + dy * dy + dz * dz);
                        if (h == 0) v0 += __fdividef(1.f, dist + 0.01f) * sR[k0];
                        else v0 -= dist;
                    }
                    if (full) {
                        const int k1 = k0 + 16;
                        const float dx = cqx[sub] - sC[k1 * 3], dy = cqy[sub] - sC[k1 * 3 + 1],
                                    dz = cqz[sub] - sC[k1 * 3 + 2];
                        const float dist = sqrtf(dx * dx + dy * dy + dz * dz);
                        if (h == 0) v1 += __fdividef(1.f, dist + 0.01f) * sR[k1];
                        else v1 -= dist;
                    }
                }
                sc[r] = v0; sc[4 + r] = v1;
            }
            float tmax = fmaxf(fmaxf(fmaxf(sc[0], sc[1]), fmaxf(sc[2], sc[3])),
                               fmaxf(fmaxf(sc[4], sc[5]), fmaxf(sc[6], sc[7])));
            tmax = fmaxf(tmax, __shfl_xor(tmax, 16));
            tmax = fmaxf(tmax, __shfl_xor(tmax, 32));
            const float mnew = fmaxf(m_[sub], tmax);
            const float f = __expf(m_[sub] - mnew);
            m_[sub] = mnew;
            float p[8], lsum = 0.f;
#pragma unroll
            for (int u = 0; u < 8; ++u) { p[u] = __expf(sc[u] - mnew); lsum += p[u]; }
            lsum += __shfl_xor(lsum, 16);
            lsum += __shfl_xor(lsum, 32);
            l_[sub] = l_[sub] * f + lsum;
            if (lg == 0) sF[w * 32 + sub * 16 + ll] = f;
            unsigned* prow = (unsigned*)((char*)sPw + (sub * 16 + ll) * 72 + lg * 8);
            prow[0] = pack2bf(p[0], p[1]);
            prow[1] = pack2bf(p[2], p[3]);
            unsigned* prow1 = (unsigned*)((char*)prow + 32);
            prow1[0] = pack2bf(p[4], p[5]);
            prow1[1] = pack2bf(p[6], p[7]);
        }

        bf16x8 vf[2], pf[2];
#pragma unroll
        for (int dt = 0; dt < 2; ++dt)
            vf[dt] = *(const bf16x8*)(sVT + (dt * 16 + ll) * 264 + kb + lg * 8);
#pragma unroll
        for (int sub = 0; sub < 2; ++sub) {
            pf[sub] = ld_frag8(sPw + (sub * 16 + ll) * 36 + lg * 8);
            float fr[4];
#pragma unroll
            for (int r = 0; r < 4; ++r) fr[r] = sF[w * 32 + sub * 16 + lg * 4 + r];
#pragma unroll
            for (int dt = 0; dt < 2; ++dt) {
#pragma unroll
                for (int r = 0; r < 4; ++r) oacc[sub][dt][r] *= fr[r];
                oacc[sub][dt] = __builtin_amdgcn_mfma_f32_16x16x32_bf16(
                    pf[sub], vf[dt], oacc[sub][dt], 0, 0, 0);
            }
        }
    }

    // ---- phase 7: normalize + write O ----
    if (lg == 0) {
        sF[w * 32 + ll]      = 1.f / l_[0];
        sF[w * 32 + 16 + ll] = 1.f / l_[1];
    }
#pragma unroll
    for (int sub = 0; sub < 2; ++sub) {
#pragma unroll
        for (int r = 0; r < 4; ++r) {
            const float li = sF[w * 32 + sub * 16 + lg * 4 + r];
            const int qrow = w * 32 + sub * 16 + lg * 4 + r;
#pragma unroll
            for (int dt = 0; dt < 2; ++dt) {
                O[((size_t)(s * 256 + qrow)) * DD + hc + dt * 16 + ll] = oacc[sub][dt][r] * li;
            }
        }
    }
}

__global__ __launch_bounds__(256) void bcast_kernel(
    const float* __restrict__ src, float* __restrict__ dst) {
    const int i = blockIdx.x * 256 + threadIdx.x;
    const int rowd = i >> 7, d = i & 127;
    const int sq = rowd >> 8, n = rowd & 255, b = sq >> 3;
    dst[i] = src[((size_t)(b * 256 + n)) * DD + d];
}

__global__ __launch_bounds__(64) void final_dot_kernel(
    const float* __restrict__ Y, const void* __restrict__ W3,
    const void* __restrict__ b3, void* __restrict__ out,
    const int* __restrict__ flagp) {
    const int isf32 = *flagp;
    const int row = blockIdx.x, lid = threadIdx.x;
    const float* yp = Y + (size_t)row * DD;
    float v = yp[lid] * ldx(W3, lid, isf32) + yp[lid + 64] * ldx(W3, (size_t)lid + 64, isf32);
#pragma unroll
    for (int o = 1; o < 64; o <<= 1) v += __shfl_xor(v, o);
    if (lid == 0) {
        const float r = v + ldx(b3, 0, isf32);
        if (isf32) ((float*)out)[row] = r;
        else ((unsigned short*)out)[row] = f2bf(r);
    }
}

// ---------------------------------------------------------------------------

extern "C" void kernel_launch(void* const* d_in, const int* in_sizes, int n_in,
                              void* d_out, int out_size, void* d_ws, size_t ws_size,
                              hipStream_t stream) {
    bool ok = (n_in >= 29) && in_sizes[0] == 12288 && in_sizes[1] == 4718592 &&
              in_sizes[2] == 1310720 && in_sizes[7] == 147456 &&
              in_sizes[13] == 98304 && in_sizes[25] == 1024 && in_sizes[27] == 128;
    if (!ok) {
        sentinel_kernel<<<(out_size + 255) / 256, 256, 0, stream>>>(
            (unsigned short*)d_out, out_size, 0x44FA);
        return;
    }
    const size_t SZ = (size_t)32768 * 128;
    const size_t NEED = (16384ull + 2ull * SZ + 2ull * 10240 * 128) * 4ull;  // 44.1 MB (proven)
    if (ws_size < NEED) {
        sentinel_kernel<<<(out_size + 255) / 256, 256, 0, stream>>>(
            (unsigned short*)d_out, out_size, 0x447A);
        return;
    }

    const void* center = d_in[0];
    const void* detr   = d_in[1];
    const void* lang   = d_in[2];
    const void* fc1_W  = d_in[7];
    const void* fc1_b  = d_in[8];
    const void* bn0    = d_in[9];
    const void* prelu0 = d_in[10];
    const void* fc2_W  = d_in[11];
    const void* fc2_b  = d_in[12];
    const void* s_qkv  = d_in[13];
    const void* s_qkvb = d_in[14];
    const void* s_Wo   = d_in[15];
    const void* s_bo   = d_in[16];
    const void* s_ln   = d_in[17];
    const void* c_qkv  = d_in[18];
    const void* c_qkvb = d_in[19];
    const void* c_Wo   = d_in[20];
    const void* c_bo   = d_in[21];
    const void* c_ln   = d_in[22];
    const void* m_W    = d_in[23];
    const void* m_b    = d_in[24];
    const void* m_bn   = d_in[25];
    const void* m_al   = d_in[26];
    const void* m_W3   = d_in[27];
    const void* m_b3   = d_in[28];

    float* wsf  = (float*)d_ws;
    int*   flag = (int*)d_ws;
    float* rs   = wsf + 4096;
    float* X    = wsf + 16384;
    float* VO   = X + SZ;
    unsigned short* KcB = (unsigned short*)(VO + SZ);
    unsigned short* VcB = KcB + (size_t)10240 * 128;
    unsigned short* Wt  = VcB + (size_t)10240 * 128;

    // Wt element offsets: fc1^T at 0; 128x128 mats at 147456 + mat*16384
#define WTO(mat) (147456 + (mat) * 16384)

    detect_kernel<<<1, 256, 0, stream>>>((const unsigned short*)center, flag);
    prep_wt_kernel<<<1792, 256, 0, stream>>>(fc1_W, fc2_W, s_qkv, s_Wo, c_qkv, c_Wo, m_W, Wt, flag);
    rowsum_kernel<<<16, 256, 0, stream>>>(center, rs, flag);

    // fc1 (+BN+PReLU) -> VO; fc2 -> X = x0
    mfma_gemm_kernel<0, 0, 1><<<64, 256, 0, stream>>>(detr, 1, Wt, 0, fc1_b, 0, nullptr, VO,
                                                      4096, 1152, bn0, 0, prelu0, 0, 1, flag);
    mfma_gemm_kernel<0, 0, 0><<<64, 256, 0, stream>>>(VO, 0, Wt, WTO(0), fc2_b, 0, nullptr, X,
                                                      4096, 128, nullptr, 0, nullptr, 0, 0, flag);

    // self block 0: V -> VO; attn O in-place VO; Wo proj(+res X) -> VO; LN VO
    mfma_gemm_kernel<0, 0, 0><<<64, 256, 0, stream>>>(X, 0, Wt, WTO(3), s_qkvb, 256, nullptr, VO,
                                                      4096, 128, nullptr, 0, nullptr, 0, 0, flag);
    attn_kernel<1><<<dim3(16, 4), 512, 0, stream>>>(X, VO, nullptr, s_qkv, 0, WMAT, s_qkvb, 0, 128,
                                                    VO, center, rs, flag, 256, 1);
    mfma_gemm_kernel<0, 1, 0><<<64, 256, 0, stream>>>(VO, 0, Wt, WTO(7), s_bo, 0, X, VO,
                                                      4096, 128, nullptr, 0, nullptr, 0, 0, flag);
    ln_kernel<<<1024, 256, 0, stream>>>(VO, s_ln, 0, flag);

    // broadcast x1 -> X (32768 rows)
    bcast_kernel<<<16384, 256, 0, stream>>>(VO, X);

    // cross block 0: K,V (lang) -> KcB,VcB bf16; attn -> VO; Wo proj(+res X) -> X; LN X
    mfma_gemm_kernel<1, 0, 0><<<160, 256, 0, stream>>>(lang, 1, Wt, WTO(10), c_qkvb, 128, nullptr, KcB,
                                                       10240, 128, nullptr, 0, nullptr, 0, 0, flag);
    mfma_gemm_kernel<1, 0, 0><<<160, 256, 0, stream>>>(lang, 1, Wt, WTO(11), c_qkvb, 256, nullptr, VcB,
                                                       10240, 128, nullptr, 0, nullptr, 0, 0, flag);
    attn_kernel<0><<<dim3(128, 4), 512, 0, stream>>>(X, VcB, KcB, c_qkv, 0, 0, c_qkvb, 0, 0,
                                                     VO, nullptr, nullptr, flag, 80, 1);
    mfma_gemm_kernel<0, 1, 0><<<512, 256, 0, stream>>>(VO, 0, Wt, WTO(15), c_bo, 0, X, X,
                                                       32768, 128, nullptr, 0, nullptr, 0, 0, flag);
    ln_kernel<<<8192, 256, 0, stream>>>(X, c_ln, 0, flag);

    // self block 1: V -> VO; attn -> VO; Wo proj(+res X) -> X; LN X
    mfma_gemm_kernel<0, 0, 0><<<512, 256, 0, stream>>>(X, 0, Wt, WTO(6), s_qkvb, 640, nullptr, VO,
                                                       32768, 128, nullptr, 0, nullptr, 0, 0, flag);
    attn_kernel<1><<<dim3(128, 4), 512, 0, stream>>>(X, VO, nullptr, s_qkv, 3 * WMAT, 4 * WMAT,
                                                     s_qkvb, 384, 512, VO, center, rs, flag, 256, 8);
    mfma_gemm_kernel<0, 1, 0><<<512, 256, 0, stream>>>(VO, 0, Wt, WTO(8), s_bo, 128, X, X,
                                                       32768, 128, nullptr, 0, nullptr, 0, 0, flag);
    ln_kernel<<<8192, 256, 0, stream>>>(X, s_ln, 256, flag);

    // cross block 1
    mfma_gemm_kernel<1, 0, 0><<<160, 256, 0, stream>>>(lang, 1, Wt, WTO(13), c_qkvb, 512, nullptr, KcB,
                                                       10240, 128, nullptr, 0, nullptr, 0, 0, flag);
    mfma_gemm_kernel<1, 0, 0><<<160, 256, 0, stream>>>(lang, 1, Wt, WTO(14), c_qkvb, 640, nullptr, VcB,
                                                       10240, 128, nullptr, 0, nullptr, 0, 0, flag);
    attn_kernel<0><<<dim3(128, 4), 512, 0, stream>>>(X, VcB, KcB, c_qkv, 3 * WMAT, 0, c_qkvb, 384, 0,
                                                     VO, nullptr, nullptr, flag, 80, 1);
    mfma_gemm_kernel<0, 1, 0><<<512, 256, 0, stream>>>(VO, 0, Wt, WTO(16), c_bo, 128, X, X,
                                                       32768, 128, nullptr, 0, nullptr, 0, 0, flag);
    ln_kernel<<<8192, 256, 0, stream>>>(X, c_ln, 256, flag);

    // match head
    mfma_gemm_kernel<0, 0, 1><<<512, 256, 0, stream>>>(X, 0, Wt, WTO(17), m_b, 0, nullptr, VO,
                                                       32768, 128, m_bn, 0, m_al, 0, 0, flag);
    mfma_gemm_kernel<0, 0, 1><<<512, 256, 0, stream>>>(VO, 0, Wt, WTO(18), m_b, 128, nullptr, X,
                                                       32768, 128, m_bn, 512, m_al, 1, 0, flag);
    final_dot_kernel<<<32768, 64, 0, stream>>>(X, m_W3, m_b3, d_out, flag);
#undef WTO
}

// Round 11
// 458.751 us; speedup vs baseline: 3.7338x; 1.2248x over previous
//
#include <hip/hip_runtime.h>

// ---------------------------------------------------------------------------
// MatchModule forward. H=4 D=128 B=16 K=256 M=8 L=80 DET_C=1152, dk=32.
// R11: projections hoisted OUT of attention into mfma_gemm (bf16 out).
//  - attn is now pure flash: Q frags direct from global bf16, K/V staged bf16,
//    O written bf16 in-place over QB (block-private (rows,head-cols) region).
//  - attn LDS templated on NK: cross (NK=80) ~32 KB -> 4 blocks/CU.
//  - all f32->bf16 pair converts via v_cvt_pk_bf16_f32 (1 instr vs ~9).
// ws (elems): flag | rs@4096 | X f32 @16384 | QB bf16 | KB bf16 | VB bf16 |
//             Wt bf16 458752.  Total 42,926,080 B = 40.9 MB (< 44.1 checked).
// ---------------------------------------------------------------------------

#define DD 128
#define WMAT 16384

typedef __attribute__((ext_vector_type(8))) short bf16x8;
typedef __attribute__((ext_vector_type(4))) float f32x4;

__device__ __forceinline__ float bf2f(unsigned short u) {
    union { unsigned int i; float f; } v; v.i = ((unsigned int)u) << 16; return v.f;
}
__device__ __forceinline__ unsigned short f2bf(float f) {   // manual RTNE (cold paths)
    union { float f; unsigned int i; } v; v.f = f;
    unsigned int x = v.i;
    return (unsigned short)((x + 0x7FFFu + ((x >> 16) & 1u)) >> 16);
}
__device__ __forceinline__ unsigned pack2bf(float a, float b) {  // lo=a, hi=b
    unsigned r;
    asm("v_cvt_pk_bf16_f32 %0, %1, %2" : "=v"(r) : "v"(a), "v"(b));
    return r;
}
__device__ __forceinline__ unsigned short f2bf_hw(float a) {
    unsigned r;
    asm("v_cvt_pk_bf16_f32 %0, %1, %1" : "=v"(r) : "v"(a));
    return (unsigned short)r;
}
__device__ __forceinline__ float ldx(const void* p, size_t i, int isf32) {
    return isf32 ? ((const float*)p)[i] : bf2f(((const unsigned short*)p)[i]);
}
__device__ __forceinline__ bf16x8 ld_frag8(const unsigned short* base) {  // 8B-aligned (LDS)
    union { bf16x8 v; uint2 u[2]; } r;
    r.u[0] = *(const uint2*)(base);
    r.u[1] = *(const uint2*)(base + 4);
    return r.v;
}
__device__ __forceinline__ bf16x8 ld_frag16g(const unsigned short* p) {   // 16B-aligned
    union { bf16x8 v; uint4 u; } r;
    r.u = *(const uint4*)p;
    return r.v;
}

// ---------------------------------------------------------------------------
__global__ __launch_bounds__(256) void detect_kernel(
    const unsigned short* __restrict__ c, int* __restrict__ flag) {
    __shared__ int cnt;
    if (threadIdx.x == 0) cnt = 0;
    __syncthreads();
    float v = bf2f(c[threadIdx.x]);
    int sane = (v == v) && (fabsf(v) <= 1e4f) && (v == 0.f || fabsf(v) >= 1e-10f);
    atomicAdd(&cnt, sane);
    __syncthreads();
    if (threadIdx.x == 0) flag[0] = (cnt >= 224) ? 0 : 1;  // 0=bf16, 1=f32
}

__global__ void sentinel_kernel(unsigned short* out, int n, int val) {
    int i = blockIdx.x * 256 + threadIdx.x;
    if (i < n) out[i] = (unsigned short)val;
}

// ---------------------------------------------------------------------------
// prep_wt: Wt = bf16(W^T) for all 20 weight matrices.
// region 0: fc1^T [128][1152]. Then 19 mats [128][128]:
// 0=fc2, 1..6=s_qkv, 7..8=s_Wo, 9..14=c_qkv, 15..16=c_Wo, 17..18=m_W.
// ---------------------------------------------------------------------------
__global__ __launch_bounds__(256) void prep_wt_kernel(
    const void* __restrict__ fc1_W, const void* __restrict__ fc2_W,
    const void* __restrict__ s_qkv, const void* __restrict__ s_Wo,
    const void* __restrict__ c_qkv, const void* __restrict__ c_Wo,
    const void* __restrict__ m_W, unsigned short* __restrict__ Wt,
    const int* __restrict__ flagp) {
    const int isf32 = *flagp;
    const int j = blockIdx.x * 256 + threadIdx.x;  // grid covers 458752 exactly
    float v;
    if (j < 147456) {
        const int n = j / 1152, k = j - n * 1152;
        v = ldx(fc1_W, (size_t)k * 128 + n, isf32);
    } else {
        const int t = j - 147456;
        const int mat = t >> 14, o = t & 16383;
        const int n = o >> 7, k = o & 127;
        const void* src; int loc;
        if (mat == 0)       { src = fc2_W; loc = 0; }
        else if (mat <= 6)  { src = s_qkv; loc = mat - 1; }
        else if (mat <= 8)  { src = s_Wo;  loc = mat - 7; }
        else if (mat <= 14) { src = c_qkv; loc = mat - 9; }
        else if (mat <= 16) { src = c_Wo;  loc = mat - 15; }
        else                { src = m_W;   loc = mat - 17; }
        v = ldx(src, (size_t)loc * 16384 + k * 128 + n, isf32);
    }
    Wt[j] = f2bf(v);
}

// ---------------------------------------------------------------------------
__global__ __launch_bounds__(256) void rowsum_kernel(
    const void* __restrict__ center, float* __restrict__ rs,
    const int* __restrict__ flagp) {
    const int isf32 = *flagp;
    const int b = blockIdx.x, i = threadIdx.x;
    __shared__ float c[768];
    for (int idx = i; idx < 768; idx += 256) c[idx] = ldx(center, (size_t)b * 768 + idx, isf32);
    __syncthreads();
    const float cx = c[i * 3], cy = c[i * 3 + 1], cz = c[i * 3 + 2];
    float s = 0.f;
    for (int j = 0; j < 256; ++j) {
        float dx = cx - c[j * 3], dy = cy - c[j * 3 + 1], dz = cz - c[j * 3 + 2];
        s += 1.f / (sqrtf(dx * dx + dy * dy + dz * dz) + 0.01f);
    }
    rs[b * 256 + i] = s;
}

// ---------------------------------------------------------------------------
// No-LDS MFMA GEMM (R10-proven). AMODE: 0 = ws f32, 1 = external flag-dtype,
// 2 = ws bf16. OUTBF16: store bf16. RES: + Xres. EPI: BN + PReLU.
// Block: 256 thr = 4 waves, 64 rows x 128 cols. In-place safe (wave-local rows).
// ---------------------------------------------------------------------------
template <int AMODE, int OUTBF16, int RES, int EPI>
__global__ __launch_bounds__(256, 4) void mfma_gemm_kernel(
    const void* __restrict__ A,
    const unsigned short* __restrict__ Wt, int wtOff,
    const void* __restrict__ bias, int bOff,
    const float* __restrict__ Xres, void* __restrict__ out,
    int nrows, int Kdim,
    const void* __restrict__ bn, int bnOff,
    const void* __restrict__ alpha, int aOff, int alpha_pc,
    const int* __restrict__ flagp) {
    const int isf32 = *flagp;
    const bool f32A = (AMODE == 0) || (AMODE == 1 && isf32);
    const int tid = threadIdx.x;
    const int l = tid & 63, w = tid >> 6;
    const int lg = l >> 4, ll = l & 15;
    const int m0 = blockIdx.x * 64;
    const int arow = m0 + w * 16 + ll;
    const f32x4 zf = {0.f, 0.f, 0.f, 0.f};
    f32x4 acc[8] = {zf, zf, zf, zf, zf, zf, zf, zf};
    const float* Af = (const float*)A;
    const unsigned short* Au = (const unsigned short*)A;
    const unsigned short* Wb = Wt + wtOff;

    for (int kc = 0; kc < Kdim; kc += 128) {
        bf16x8 af[4];
        if (f32A) {
#pragma unroll
            for (int ks = 0; ks < 4; ++ks) {
                const float4* ap = (const float4*)(Af + (size_t)arow * Kdim + kc + ks * 32 + lg * 8);
                const float4 a0 = ap[0], a1 = ap[1];
                union { bf16x8 v; unsigned u[4]; } r;
                r.u[0] = pack2bf(a0.x, a0.y); r.u[1] = pack2bf(a0.z, a0.w);
                r.u[2] = pack2bf(a1.x, a1.y); r.u[3] = pack2bf(a1.z, a1.w);
                af[ks] = r.v;
            }
        } else {
#pragma unroll
            for (int ks = 0; ks < 4; ++ks)
                af[ks] = ld_frag16g(Au + (size_t)arow * Kdim + kc + ks * 32 + lg * 8);
        }
#pragma unroll
        for (int nt = 0; nt < 8; ++nt) {
#pragma unroll
            for (int ks = 0; ks < 4; ++ks) {
                const bf16x8 wf = ld_frag16g(Wb + (size_t)(nt * 16 + ll) * Kdim + kc + ks * 32 + lg * 8);
                acc[nt] = __builtin_amdgcn_mfma_f32_16x16x32_bf16(af[ks], wf, acc[nt], 0, 0, 0);
            }
        }
    }

    const int rbase = m0 + w * 16 + lg * 4;
#pragma unroll
    for (int nt = 0; nt < 8; ++nt) {
        const int col = nt * 16 + ll;
        const float bs = ldx(bias, (size_t)bOff + col, isf32);
        float g = 1.f, bb = 0.f, mmn = 0.f, rinv = 1.f, al = 0.f;
        if (EPI) {
            g    = ldx(bn, (size_t)bnOff + col, isf32);
            bb   = ldx(bn, (size_t)bnOff + 128 + col, isf32);
            mmn  = ldx(bn, (size_t)bnOff + 256 + col, isf32);
            rinv = rsqrtf(ldx(bn, (size_t)bnOff + 384 + col, isf32) + 1e-5f);
            al   = alpha_pc ? ldx(alpha, (size_t)aOff + col, isf32)
                            : ldx(alpha, (size_t)aOff, isf32);
        }
#pragma unroll
        for (int r = 0; r < 4; ++r) {
            const int row = rbase + r;
            float v = acc[nt][r] + bs;
            if (RES) v += Xres[(size_t)row * 128 + col];
            if (EPI) {
                v = g * (v - mmn) * rinv + bb;
                v = (v >= 0.f) ? v : al * v;
            }
            if (OUTBF16) ((unsigned short*)out)[(size_t)row * 128 + col] = f2bf_hw(v);
            else ((float*)out)[(size_t)row * 128 + col] = v;
        }
    }
}

// ---------------------------------------------------------------------------
// In-place row LayerNorm; wave per row, block = 4 rows.
// ---------------------------------------------------------------------------
__global__ __launch_bounds__(256) void ln_kernel(
    float* __restrict__ Y, const void* __restrict__ ln, int lnOff,
    const int* __restrict__ flagp) {
    const int isf32 = *flagp;
    const int lane = threadIdx.x & 63;
    const int row = blockIdx.x * 4 + (threadIdx.x >> 6);
    float* yp = Y + (size_t)row * 128;
    const float v0 = yp[lane], v1 = yp[lane + 64];
    float s1 = v0 + v1, s2 = v0 * v0 + v1 * v1;
#pragma unroll
    for (int o = 1; o < 64; o <<= 1) { s1 += __shfl_xor(s1, o); s2 += __shfl_xor(s2, o); }
    const float mu = s1 * (1.f / 128.f);
    const float var = s2 * (1.f / 128.f) - mu * mu;
    const float rq = rsqrtf(var + 1e-5f);
    const float g0 = ldx(ln, (size_t)lnOff + lane, isf32);
    const float g1 = ldx(ln, (size_t)lnOff + 64 + lane, isf32);
    const float b0 = ldx(ln, (size_t)lnOff + 128 + lane, isf32);
    const float b1 = ldx(ln, (size_t)lnOff + 192 + lane, isf32);
    yp[lane]      = g0 * (v0 - mu) * rq + b0;
    yp[lane + 64] = g1 * (v1 - mu) * rq + b1;
}

// ---------------------------------------------------------------------------
// Pure-flash MFMA attention. Block = (seq s, head h), 512 thr = 8 waves.
// Q/K/V are pre-projected bf16 (QB/KB/VB). Q frags direct from global;
// K staged [NK][36]; V^T staged [32][NKR+8]. O stored bf16 IN PLACE over QB
// (each (row,col) is written only by the block that read it — safe).
// SELF bias: h0 = (1/(dist+.01))/rowsum[k], h1 = -dist (on-the-fly from sC).
// ---------------------------------------------------------------------------
template <int SELF, int NK>
__global__ __launch_bounds__(512, 2) void attn_kernel(
    const unsigned short* __restrict__ Qb,
    const unsigned short* __restrict__ Kb,
    const unsigned short* __restrict__ Vb,
    unsigned short* __restrict__ O,
    const void* __restrict__ center, const float* __restrict__ rs,
    const int* __restrict__ flagp, int bDiv) {
    constexpr int NKR = (NK + 31) & ~31;
    constexpr int VSTR = NKR + 8;
    __shared__ __align__(16) unsigned short sKb[NK * 36];
    __shared__ __align__(16) unsigned short sVT[32 * VSTR];
    __shared__ __align__(16) unsigned short sP[8 * 32 * 36];
    __shared__ float sF[256];
    __shared__ float sC[SELF ? 768 : 1];
    __shared__ float sR[SELF ? 256 : 1];

    const int isf32 = *flagp;
    const int s = blockIdx.x, h = blockIdx.y, tid = threadIdx.x;
    const int l = tid & 63, w = tid >> 6;
    const int hc = h * 32;
    const int lg = l >> 4, ll = l & 15;

    // ---- stage K tile [NK][36] (16B loads, 8B LDS stores) ----
    for (int idx = tid; idx < NK * 4; idx += 512) {
        const int j = idx >> 2, g = idx & 3;
        const uint4 t = *(const uint4*)(Kb + ((size_t)(s * NK + j)) * 128 + hc + g * 8);
        uint2* d = (uint2*)(sKb + j * 36 + g * 8);
        d[0] = make_uint2(t.x, t.y);
        d[1] = make_uint2(t.z, t.w);
    }
    // ---- stage V^T [32][VSTR] ----
    for (int idx = tid; idx < NK * 4; idx += 512) {
        const int j = idx >> 2, g = idx & 3;
        const uint4 t = *(const uint4*)(Vb + ((size_t)(s * NK + j)) * 128 + hc + g * 8);
        const unsigned short* e = (const unsigned short*)&t;
#pragma unroll
        for (int u = 0; u < 8; ++u) sVT[(g * 8 + u) * VSTR + j] = e[u];
    }
    if constexpr (NKR != NK) {
        for (int idx = tid; idx < 32 * (NKR - NK); idx += 512) {
            const int i = idx / (NKR - NK), j = NK + idx % (NKR - NK);
            sVT[i * VSTR + j] = 0;
        }
    }
    if (SELF) {
        const int bb = s / bDiv;
        for (int idx = tid; idx < 768; idx += 512)
            sC[idx] = ldx(center, (size_t)bb * 768 + idx, isf32);
        if (tid < 256) sR[tid] = 1.0f / rs[bb * 256 + tid];
    }

    // ---- Q fragments: direct from global (own rows) ----
    bf16x8 qfrag[2];
#pragma unroll
    for (int sub = 0; sub < 2; ++sub)
        qfrag[sub] = ld_frag16g(Qb + ((size_t)(s * 256 + w * 32 + sub * 16 + ll)) * 128 + hc + lg * 8);

    __syncthreads();

    // ---- flash k-loop ----
    const float scale = 0.17677669529663687f;  // 1/sqrt(32)
    float cqx[2], cqy[2], cqz[2];
    if (SELF) {
#pragma unroll
        for (int sub = 0; sub < 2; ++sub) {
            const int qg = w * 32 + sub * 16 + ll;
            cqx[sub] = sC[qg * 3]; cqy[sub] = sC[qg * 3 + 1]; cqz[sub] = sC[qg * 3 + 2];
        }
    }
    float m_[2] = {-3.0e38f, -3.0e38f}, l_[2] = {0.f, 0.f};
    const f32x4 zf = {0.f, 0.f, 0.f, 0.f};
    f32x4 oacc[2][2] = {{zf, zf}, {zf, zf}};
    unsigned short* sPw = sP + w * 32 * 36;

    for (int kb = 0; kb < NK; kb += 32) {
        const int full = (NK - kb) >= 32;
        const unsigned short* kbase = sKb + (kb + ll) * 36 + lg * 8;
        const bf16x8 kf0 = ld_frag8(kbase);
        bf16x8 kf1;
        if (full) kf1 = ld_frag8(kbase + 16 * 36);

#pragma unroll
        for (int sub = 0; sub < 2; ++sub) {
            f32x4 s0 = __builtin_amdgcn_mfma_f32_16x16x32_bf16(kf0, qfrag[sub], zf, 0, 0, 0);
            f32x4 s1 = zf;
            if (full) s1 = __builtin_amdgcn_mfma_f32_16x16x32_bf16(kf1, qfrag[sub], zf, 0, 0, 0);

            float sc[8];
#pragma unroll
            for (int r = 0; r < 4; ++r) {
                const int k0 = kb + lg * 4 + r;
                float v0 = s0[r] * scale;
                float v1 = full ? s1[r] * scale : -3.0e38f;
                if (SELF && h < 2) {
                    {
                        const float dx = cqx[sub] - sC[k0 * 3], dy = cqy[sub] - sC[k0 * 3 + 1],
                                    dz = cqz[sub] - sC[k0 * 3 + 2];
                        const float dist = sqrtf(dx * dx + dy * dy + dz * dz);
                        if (h == 0) v0 += __fdividef(1.f, dist + 0.01f) * sR[k0];
                        else v0 -= dist;
                    }
                    if (full) {
                        const int k1 = k0 + 16;
                        const float dx = cqx[sub] - sC[k1 * 3], dy = cqy[sub] - sC[k1 * 3 + 1],
                                    dz = cqz[sub] - sC[k1 * 3 + 2];
                        const float dist = sqrtf(dx * dx + dy * dy + dz * dz);
                        if (h == 0) v1 += __fdividef(1.f, dist + 0.01f) * sR[k1];
                        else v1 -= dist;
                    }
                }
                sc[r] = v0; sc[4 + r] = v1;
            }
            float tmax = fmaxf(fmaxf(fmaxf(sc[0], sc[1]), fmaxf(sc[2], sc[3])),
                               fmaxf(fmaxf(sc[4], sc[5]), fmaxf(sc[6], sc[7])));
            tmax = fmaxf(tmax, __shfl_xor(tmax, 16));
            tmax = fmaxf(tmax, __shfl_xor(tmax, 32));
            const float mnew = fmaxf(m_[sub], tmax);
            const float f = __expf(m_[sub] - mnew);
            m_[sub] = mnew;
            float p[8], lsum = 0.f;
#pragma unroll
            for (int u = 0; u < 8; ++u) { p[u] = __expf(sc[u] - mnew); lsum += p[u]; }
            lsum += __shfl_xor(lsum, 16);
            lsum += __shfl_xor(lsum, 32);
            l_[sub] = l_[sub] * f + lsum;
            if (lg == 0) sF[w * 32 + sub * 16 + ll] = f;
            unsigned* prow = (unsigned*)((char*)sPw + (sub * 16 + ll) * 72 + lg * 8);
            prow[0] = pack2bf(p[0], p[1]);
            prow[1] = pack2bf(p[2], p[3]);
            unsigned* prow1 = (unsigned*)((char*)prow + 32);
            prow1[0] = pack2bf(p[4], p[5]);
            prow1[1] = pack2bf(p[6], p[7]);
        }

        bf16x8 vf[2], pf[2];
#pragma unroll
        for (int dt = 0; dt < 2; ++dt)
            vf[dt] = *(const bf16x8*)(sVT + (dt * 16 + ll) * VSTR + kb + lg * 8);
#pragma unroll
        for (int sub = 0; sub < 2; ++sub) {
            pf[sub] = ld_frag8(sPw + (sub * 16 + ll) * 36 + lg * 8);
            float fr[4];
#pragma unroll
            for (int r = 0; r < 4; ++r) fr[r] = sF[w * 32 + sub * 16 + lg * 4 + r];
#pragma unroll
            for (int dt = 0; dt < 2; ++dt) {
#pragma unroll
                for (int r = 0; r < 4; ++r) oacc[sub][dt][r] *= fr[r];
                oacc[sub][dt] = __builtin_amdgcn_mfma_f32_16x16x32_bf16(
                    pf[sub], vf[dt], oacc[sub][dt], 0, 0, 0);
            }
        }
    }

    // ---- normalize + write O (bf16, in place over QB region) ----
    if (lg == 0) {
        sF[w * 32 + ll]      = 1.f / l_[0];
        sF[w * 32 + 16 + ll] = 1.f / l_[1];
    }
#pragma unroll
    for (int sub = 0; sub < 2; ++sub) {
#pragma unroll
        for (int r = 0; r < 4; ++r) {
            const float li = sF[w * 32 + sub * 16 + lg * 4 + r];
            const int qrow = w * 32 + sub * 16 + lg * 4 + r;
#pragma unroll
            for (int dt = 0; dt < 2; ++dt) {
                O[((size_t)(s * 256 + qrow)) * 128 + hc + dt * 16 + ll] =
                    f2bf_hw(oacc[sub][dt][r] * li);
            }
        }
    }
}

// f1_0[(b*M+m)*256+n, d] = x1[b*256+n, d]
__global__ __launch_bounds__(256) void bcast_kernel(
    const float* __restrict__ src, float* __restrict__ dst) {
    const int i = blockIdx.x * 256 + threadIdx.x;
    const int rowd = i >> 7, d = i & 127;
    const int sq = rowd >> 8, n = rowd & 255, b = sq >> 3;
    dst[i] = src[((size_t)(b * 256 + n)) * 128 + d];
}

// out[row] = Y[row,:] . W3 + b3   (Y bf16; 4 rows per block, wave per row)
__global__ __launch_bounds__(256) void final_dot_kernel(
    const unsigned short* __restrict__ Y, const void* __restrict__ W3,
    const void* __restrict__ b3, void* __restrict__ out,
    const int* __restrict__ flagp) {
    const int isf32 = *flagp;
    const int lane = threadIdx.x & 63;
    const int row = blockIdx.x * 4 + (threadIdx.x >> 6);
    const unsigned short* yp = Y + (size_t)row * 128;
    float v = bf2f(yp[lane]) * ldx(W3, lane, isf32) +
              bf2f(yp[lane + 64]) * ldx(W3, (size_t)lane + 64, isf32);
#pragma unroll
    for (int o = 1; o < 64; o <<= 1) v += __shfl_xor(v, o);
    if (lane == 0) {
        const float r = v + ldx(b3, 0, isf32);
        if (isf32) ((float*)out)[row] = r;
        else ((unsigned short*)out)[row] = f2bf(r);
    }
}

// ---------------------------------------------------------------------------

extern "C" void kernel_launch(void* const* d_in, const int* in_sizes, int n_in,
                              void* d_out, int out_size, void* d_ws, size_t ws_size,
                              hipStream_t stream) {
    bool ok = (n_in >= 29) && in_sizes[0] == 12288 && in_sizes[1] == 4718592 &&
              in_sizes[2] == 1310720 && in_sizes[7] == 147456 &&
              in_sizes[13] == 98304 && in_sizes[25] == 1024 && in_sizes[27] == 128;
    if (!ok) {
        sentinel_kernel<<<(out_size + 255) / 256, 256, 0, stream>>>(
            (unsigned short*)d_out, out_size, 0x44FA);
        return;
    }
    const size_t SZ = (size_t)32768 * 128;
    const size_t NEED = (16384ull + 2ull * SZ + 2ull * 10240 * 128) * 4ull;  // 44.1 MB (proven)
    if (ws_size < NEED) {
        sentinel_kernel<<<(out_size + 255) / 256, 256, 0, stream>>>(
            (unsigned short*)d_out, out_size, 0x447A);
        return;
    }

    const void* center = d_in[0];
    const void* detr   = d_in[1];
    const void* lang   = d_in[2];
    const void* fc1_W  = d_in[7];
    const void* fc1_b  = d_in[8];
    const void* bn0    = d_in[9];
    const void* prelu0 = d_in[10];
    const void* fc2_W  = d_in[11];
    const void* fc2_b  = d_in[12];
    const void* s_qkv  = d_in[13];
    const void* s_qkvb = d_in[14];
    const void* s_Wo   = d_in[15];
    const void* s_bo   = d_in[16];
    const void* s_ln   = d_in[17];
    const void* c_qkv  = d_in[18];
    const void* c_qkvb = d_in[19];
    const void* c_Wo   = d_in[20];
    const void* c_bo   = d_in[21];
    const void* c_ln   = d_in[22];
    const void* m_W    = d_in[23];
    const void* m_b    = d_in[24];
    const void* m_bn   = d_in[25];
    const void* m_al   = d_in[26];
    const void* m_W3   = d_in[27];
    const void* m_b3   = d_in[28];

    float* wsf  = (float*)d_ws;
    int*   flag = (int*)d_ws;
    float* rs   = wsf + 4096;
    float* X    = wsf + 16384;                      // f32 [32768][128]
    unsigned short* QB = (unsigned short*)(X + SZ); // bf16 [32768][128]
    unsigned short* KB = QB + SZ;
    unsigned short* VB = KB + SZ;
    unsigned short* Wt = VB + SZ;                   // bf16 458752

#define WTO(mat) (147456 + (mat) * 16384)
#define GEMM(AM, OB, RE, EP, grid, Aptr, wto, bptr, boff, res, outp, nr, kd, bnp, bnoff, alp, aoff, apc) \
    mfma_gemm_kernel<AM, OB, RE, EP><<<grid, 256, 0, stream>>>(                                          \
        Aptr, Wt, wto, bptr, boff, res, outp, nr, kd, bnp, bnoff, alp, aoff, apc, flag)

    detect_kernel<<<1, 256, 0, stream>>>((const unsigned short*)center, flag);
    prep_wt_kernel<<<1792, 256, 0, stream>>>(fc1_W, fc2_W, s_qkv, s_Wo, c_qkv, c_Wo, m_W, Wt, flag);
    rowsum_kernel<<<16, 256, 0, stream>>>(center, rs, flag);

    // fc1 (+BN+PReLU) -> KB bf16; fc2 -> X f32 (= x0)
    GEMM(1, 1, 0, 1, 64, detr, 0, fc1_b, 0, nullptr, KB, 4096, 1152, bn0, 0, prelu0, 0, 1);
    GEMM(2, 0, 0, 0, 64, KB, WTO(0), fc2_b, 0, nullptr, X, 4096, 128, nullptr, 0, nullptr, 0, 0);

    // self block 0 (4096 rows): Q,K,V -> QB,KB,VB; attn O in-place QB;
    // Wo(+res X) -> x1 f32 in VB-region; LN; bcast -> X
    GEMM(0, 1, 0, 0, 64, X, WTO(1), s_qkvb, 0,   nullptr, QB, 4096, 128, nullptr, 0, nullptr, 0, 0);
    GEMM(0, 1, 0, 0, 64, X, WTO(2), s_qkvb, 128, nullptr, KB, 4096, 128, nullptr, 0, nullptr, 0, 0);
    GEMM(0, 1, 0, 0, 64, X, WTO(3), s_qkvb, 256, nullptr, VB, 4096, 128, nullptr, 0, nullptr, 0, 0);
    attn_kernel<1, 256><<<dim3(16, 4), 512, 0, stream>>>(QB, KB, VB, QB, center, rs, flag, 1);
    GEMM(2, 0, 1, 0, 64, QB, WTO(7), s_bo, 0, X, (float*)VB, 4096, 128, nullptr, 0, nullptr, 0, 0);
    ln_kernel<<<1024, 256, 0, stream>>>((float*)VB, s_ln, 0, flag);
    bcast_kernel<<<16384, 256, 0, stream>>>((const float*)VB, X);

    // cross block 0: Q(X) -> QB; K,V(lang) -> KB,VB; attn; Wo(+res X) -> X; LN
    GEMM(0, 1, 0, 0, 512, X, WTO(9), c_qkvb, 0, nullptr, QB, 32768, 128, nullptr, 0, nullptr, 0, 0);
    GEMM(1, 1, 0, 0, 160, lang, WTO(10), c_qkvb, 128, nullptr, KB, 10240, 128, nullptr, 0, nullptr, 0, 0);
    GEMM(1, 1, 0, 0, 160, lang, WTO(11), c_qkvb, 256, nullptr, VB, 10240, 128, nullptr, 0, nullptr, 0, 0);
    attn_kernel<0, 80><<<dim3(128, 4), 512, 0, stream>>>(QB, KB, VB, QB, nullptr, nullptr, flag, 1);
    GEMM(2, 0, 1, 0, 512, QB, WTO(15), c_bo, 0, X, X, 32768, 128, nullptr, 0, nullptr, 0, 0);
    ln_kernel<<<8192, 256, 0, stream>>>(X, c_ln, 0, flag);

    // self block 1: Q,K,V -> QB,KB,VB; attn (bias b = s/8); Wo(+res X) -> X; LN
    GEMM(0, 1, 0, 0, 512, X, WTO(4), s_qkvb, 384, nullptr, QB, 32768, 128, nullptr, 0, nullptr, 0, 0);
    GEMM(0, 1, 0, 0, 512, X, WTO(5), s_qkvb, 512, nullptr, KB, 32768, 128, nullptr, 0, nullptr, 0, 0);
    GEMM(0, 1, 0, 0, 512, X, WTO(6), s_qkvb, 640, nullptr, VB, 32768, 128, nullptr, 0, nullptr, 0, 0);
    attn_kernel<1, 256><<<dim3(128, 4), 512, 0, stream>>>(QB, KB, VB, QB, center, rs, flag, 8);
    GEMM(2, 0, 1, 0, 512, QB, WTO(8), s_bo, 128, X, X, 32768, 128, nullptr, 0, nullptr, 0, 0);
    ln_kernel<<<8192, 256, 0, stream>>>(X, s_ln, 256, flag);

    // cross block 1
    GEMM(0, 1, 0, 0, 512, X, WTO(12), c_qkvb, 384, nullptr, QB, 32768, 128, nullptr, 0, nullptr, 0, 0);
    GEMM(1, 1, 0, 0, 160, lang, WTO(13), c_qkvb, 512, nullptr, KB, 10240, 128, nullptr, 0, nullptr, 0, 0);
    GEMM(1, 1, 0, 0, 160, lang, WTO(14), c_qkvb, 640, nullptr, VB, 10240, 128, nullptr, 0, nullptr, 0, 0);
    attn_kernel<0, 80><<<dim3(128, 4), 512, 0, stream>>>(QB, KB, VB, QB, nullptr, nullptr, flag, 1);
    GEMM(2, 0, 1, 0, 512, QB, WTO(16), c_bo, 128, X, X, 32768, 128, nullptr, 0, nullptr, 0, 0);
    ln_kernel<<<8192, 256, 0, stream>>>(X, c_ln, 256, flag);

    // match head: X -> KB (BN+PReLU) -> QB (BN+PReLU) -> dot
    GEMM(0, 1, 0, 1, 512, X, WTO(17), m_b, 0, nullptr, KB, 32768, 128, m_bn, 0, m_al, 0, 0);
    GEMM(2, 1, 0, 1, 512, KB, WTO(18), m_b, 128, nullptr, QB, 32768, 128, m_bn, 512, m_al, 1, 0);
    final_dot_kernel<<<8192, 256, 0, stream>>>(QB, m_W3, m_b3, d_out, flag);
#undef GEMM
#undef WTO
}

// Round 12
// 376.556 us; speedup vs baseline: 4.5489x; 1.2183x over previous
//
#include <hip/hip_runtime.h>

// ---------------------------------------------------------------------------
// MatchModule forward. H=4 D=128 B=16 K=256 M=8 L=80 DET_C=1152, dk=32.
// R12: parallelism + pass-count attack.
//  - gemm_s: 512-thr 16-row blocks (8 waves, wave = one 16-col tile), NOUT
//    fused outputs (QKV in one pass, cross-K/V in one pass). fc1 grid 64->256.
//  - gemm_b: 256-thr 64-row blocks, full-row waves; fused epilogues:
//    residual + LayerNorm in-wave (16-lane shfl reduce)  -> no ln_kernel
//    final W3-dot                                        -> no final_dot
//    row-remap on A / residual                           -> no bcast
//  - x1 (4096xf32) lives in XS = unused tail of KB region (byte-range checked).
// ws layout (bytes): flag|rs @0..65536 | X f32 16.8M | QB | KB (XS@+3.5M) |
//   VB | Wt 0.92M = 42.9 MB total (< 44.1 checked).
// ---------------------------------------------------------------------------

#define DD 128

typedef __attribute__((ext_vector_type(8))) short bf16x8;
typedef __attribute__((ext_vector_type(4))) float f32x4;

__device__ __forceinline__ float bf2f(unsigned short u) {
    union { unsigned int i; float f; } v; v.i = ((unsigned int)u) << 16; return v.f;
}
__device__ __forceinline__ unsigned short f2bf(float f) {   // manual RTNE (cold paths)
    union { float f; unsigned int i; } v; v.f = f;
    unsigned int x = v.i;
    return (unsigned short)((x + 0x7FFFu + ((x >> 16) & 1u)) >> 16);
}
__device__ __forceinline__ unsigned pack2bf(float a, float b) {  // lo=a, hi=b
    unsigned r;
    asm("v_cvt_pk_bf16_f32 %0, %1, %2" : "=v"(r) : "v"(a), "v"(b));
    return r;
}
__device__ __forceinline__ unsigned short f2bf_hw(float a) {
    unsigned r;
    asm("v_cvt_pk_bf16_f32 %0, %1, %1" : "=v"(r) : "v"(a));
    return (unsigned short)r;
}
__device__ __forceinline__ float ldx(const void* p, size_t i, int isf32) {
    return isf32 ? ((const float*)p)[i] : bf2f(((const unsigned short*)p)[i]);
}
__device__ __forceinline__ bf16x8 ld_frag8(const unsigned short* base) {  // 8B-aligned (LDS)
    union { bf16x8 v; uint2 u[2]; } r;
    r.u[0] = *(const uint2*)(base);
    r.u[1] = *(const uint2*)(base + 4);
    return r.v;
}
__device__ __forceinline__ bf16x8 ld_frag16g(const unsigned short* p) {   // 16B-aligned
    union { bf16x8 v; uint4 u; } r;
    r.u = *(const uint4*)p;
    return r.v;
}

// ---------------------------------------------------------------------------
__global__ __launch_bounds__(256) void detect_kernel(
    const unsigned short* __restrict__ c, int* __restrict__ flag) {
    __shared__ int cnt;
    if (threadIdx.x == 0) cnt = 0;
    __syncthreads();
    float v = bf2f(c[threadIdx.x]);
    int sane = (v == v) && (fabsf(v) <= 1e4f) && (v == 0.f || fabsf(v) >= 1e-10f);
    atomicAdd(&cnt, sane);
    __syncthreads();
    if (threadIdx.x == 0) flag[0] = (cnt >= 224) ? 0 : 1;  // 0=bf16, 1=f32
}

__global__ void sentinel_kernel(unsigned short* out, int n, int val) {
    int i = blockIdx.x * 256 + threadIdx.x;
    if (i < n) out[i] = (unsigned short)val;
}

// ---------------------------------------------------------------------------
// prep_wt: Wt = bf16(W^T). region 0: fc1^T [128][1152]. Then 19 [128][128]:
// 0=fc2, 1..6=s_qkv, 7..8=s_Wo, 9..14=c_qkv, 15..16=c_Wo, 17..18=m_W.
// ---------------------------------------------------------------------------
__global__ __launch_bounds__(256) void prep_wt_kernel(
    const void* __restrict__ fc1_W, const void* __restrict__ fc2_W,
    const void* __restrict__ s_qkv, const void* __restrict__ s_Wo,
    const void* __restrict__ c_qkv, const void* __restrict__ c_Wo,
    const void* __restrict__ m_W, unsigned short* __restrict__ Wt,
    const int* __restrict__ flagp) {
    const int isf32 = *flagp;
    const int j = blockIdx.x * 256 + threadIdx.x;
    float v;
    if (j < 147456) {
        const int n = j / 1152, k = j - n * 1152;
        v = ldx(fc1_W, (size_t)k * 128 + n, isf32);
    } else {
        const int t = j - 147456;
        const int mat = t >> 14, o = t & 16383;
        const int n = o >> 7, k = o & 127;
        const void* src; int loc;
        if (mat == 0)       { src = fc2_W; loc = 0; }
        else if (mat <= 6)  { src = s_qkv; loc = mat - 1; }
        else if (mat <= 8)  { src = s_Wo;  loc = mat - 7; }
        else if (mat <= 14) { src = c_qkv; loc = mat - 9; }
        else if (mat <= 16) { src = c_Wo;  loc = mat - 15; }
        else                { src = m_W;   loc = mat - 17; }
        v = ldx(src, (size_t)loc * 16384 + k * 128 + n, isf32);
    }
    Wt[j] = f2bf(v);
}

// ---------------------------------------------------------------------------
__global__ __launch_bounds__(256) void rowsum_kernel(
    const void* __restrict__ center, float* __restrict__ rs,
    const int* __restrict__ flagp) {
    const int isf32 = *flagp;
    const int b = blockIdx.x, i = threadIdx.x;
    __shared__ float c[768];
    for (int idx = i; idx < 768; idx += 256) c[idx] = ldx(center, (size_t)b * 768 + idx, isf32);
    __syncthreads();
    const float cx = c[i * 3], cy = c[i * 3 + 1], cz = c[i * 3 + 2];
    float s = 0.f;
    for (int j = 0; j < 256; ++j) {
        float dx = cx - c[j * 3], dy = cy - c[j * 3 + 1], dz = cz - c[j * 3 + 2];
        s += 1.f / (sqrtf(dx * dx + dy * dy + dz * dz) + 0.01f);
    }
    rs[b * 256 + i] = s;
}

// ---------------------------------------------------------------------------
// gemm_s: 512 thr = 8 waves; block = 16 rows; wave w = col tile [w*16, w*16+16).
// NOUT consecutive weight mats (stride 128*Kdim) -> NOUT outputs (bf16 or f32).
// AMODE: 0 = f32 buf, 1 = external flag-dtype, 2 = bf16 buf.
// EPI: BN+PReLU. REMAP: A row -> (row>>11)*256 + (row&255) (broadcast read).
// D layout (R8-proven): col = w*16 + (l&15), row = m0 + (l>>4)*4 + r.
// ---------------------------------------------------------------------------
template <int NOUT, int AMODE, int EPI, int OUTF32, int REMAP>
__global__ __launch_bounds__(512, 2) void gemm_s_kernel(
    const void* __restrict__ A,
    const unsigned short* __restrict__ Wt, int wtOff,
    const void* __restrict__ bias, int bOff,
    void* __restrict__ out0, void* __restrict__ out1, void* __restrict__ out2,
    int Kdim,
    const void* __restrict__ bn, int bnOff,
    const void* __restrict__ alpha, int aOff, int alpha_pc,
    const int* __restrict__ flagp) {
    const int isf32 = *flagp;
    const bool f32A = (AMODE == 0) || (AMODE == 1 && isf32);
    const int tid = threadIdx.x;
    const int l = tid & 63, w = tid >> 6;
    const int lg = l >> 4, ll = l & 15;
    const int m0 = blockIdx.x * 16;
    int arow = m0 + ll;
    if (REMAP) arow = (arow >> 11) * 256 + (arow & 255);
    const f32x4 zf = {0.f, 0.f, 0.f, 0.f};
    f32x4 acc[NOUT];
#pragma unroll
    for (int o = 0; o < NOUT; ++o) acc[o] = zf;
    const float* Af = (const float*)A;
    const unsigned short* Au = (const unsigned short*)A;
    const unsigned short* Wb = Wt + wtOff;
    const int wrow = w * 16 + ll;   // W row (= out col)

    for (int kc = 0; kc < Kdim; kc += 128) {
        bf16x8 af[4];
        if (f32A) {
#pragma unroll
            for (int ks = 0; ks < 4; ++ks) {
                const float4* ap = (const float4*)(Af + (size_t)arow * Kdim + kc + ks * 32 + lg * 8);
                const float4 a0 = ap[0], a1 = ap[1];
                union { bf16x8 v; unsigned u[4]; } r;
                r.u[0] = pack2bf(a0.x, a0.y); r.u[1] = pack2bf(a0.z, a0.w);
                r.u[2] = pack2bf(a1.x, a1.y); r.u[3] = pack2bf(a1.z, a1.w);
                af[ks] = r.v;
            }
        } else {
#pragma unroll
            for (int ks = 0; ks < 4; ++ks)
                af[ks] = ld_frag16g(Au + (size_t)arow * Kdim + kc + ks * 32 + lg * 8);
        }
#pragma unroll
        for (int o = 0; o < NOUT; ++o) {
#pragma unroll
            for (int ks = 0; ks < 4; ++ks) {
                const bf16x8 wf = ld_frag16g(
                    Wb + (size_t)o * 128 * Kdim + (size_t)wrow * Kdim + kc + ks * 32 + lg * 8);
                acc[o] = __builtin_amdgcn_mfma_f32_16x16x32_bf16(af[ks], wf, acc[o], 0, 0, 0);
            }
        }
    }

    const int col = w * 16 + ll;
    const int rbase = m0 + lg * 4;
#pragma unroll
    for (int o = 0; o < NOUT; ++o) {
        void* outp = (o == 0) ? out0 : (o == 1) ? out1 : out2;
        const float bs = ldx(bias, (size_t)bOff + o * 128 + col, isf32);
        float g = 1.f, bb = 0.f, mmn = 0.f, rinv = 1.f, al = 0.f;
        if (EPI) {
            g    = ldx(bn, (size_t)bnOff + col, isf32);
            bb   = ldx(bn, (size_t)bnOff + 128 + col, isf32);
            mmn  = ldx(bn, (size_t)bnOff + 256 + col, isf32);
            rinv = rsqrtf(ldx(bn, (size_t)bnOff + 384 + col, isf32) + 1e-5f);
            al   = alpha_pc ? ldx(alpha, (size_t)aOff + col, isf32)
                            : ldx(alpha, (size_t)aOff, isf32);
        }
#pragma unroll
        for (int r = 0; r < 4; ++r) {
            float v = acc[o][r] + bs;
            if (EPI) {
                v = g * (v - mmn) * rinv + bb;
                v = (v >= 0.f) ? v : al * v;
            }
            const size_t oi = (size_t)(rbase + r) * 128 + col;
            if (OUTF32) ((float*)outp)[oi] = v;
            else ((unsigned short*)outp)[oi] = f2bf_hw(v);
        }
    }
}

// ---------------------------------------------------------------------------
// gemm_b: 256 thr = 4 waves; block = 64 rows; wave owns 16 FULL rows (all 128
// cols as 8 nt tiles). A always bf16. Epilogue variants:
//   LNF: v = acc+bias+Xres[remap?]; in-wave LN (16-lane shfl) -> f32 out
//   FDOT (+EPI BN/PReLU): out[row] = sum_col v*W3[col] + b3 -> d_out
// ---------------------------------------------------------------------------
template <int REMAPR, int LNF, int EPI, int FDOT>
__global__ __launch_bounds__(256, 4) void gemm_b_kernel(
    const unsigned short* __restrict__ A,
    const unsigned short* __restrict__ Wt, int wtOff,
    const void* __restrict__ bias, int bOff,
    const float* __restrict__ Xres,
    const void* __restrict__ lnp, int lnOff,
    const void* __restrict__ bn, int bnOff,
    const void* __restrict__ alpha, int aOff, int alpha_pc,
    const void* __restrict__ W3, const void* __restrict__ b3,
    void* __restrict__ out, const int* __restrict__ flagp) {
    const int isf32 = *flagp;
    const int tid = threadIdx.x;
    const int l = tid & 63, w = tid >> 6;
    const int lg = l >> 4, ll = l & 15;
    const int m0 = blockIdx.x * 64;
    const int arow = m0 + w * 16 + ll;
    const f32x4 zf = {0.f, 0.f, 0.f, 0.f};
    f32x4 acc[8] = {zf, zf, zf, zf, zf, zf, zf, zf};
    const unsigned short* Wb = Wt + wtOff;

    bf16x8 af[4];
#pragma unroll
    for (int ks = 0; ks < 4; ++ks)
        af[ks] = ld_frag16g(A + (size_t)arow * 128 + ks * 32 + lg * 8);
#pragma unroll
    for (int nt = 0; nt < 8; ++nt) {
#pragma unroll
        for (int ks = 0; ks < 4; ++ks) {
            const bf16x8 wf = ld_frag16g(Wb + (size_t)(nt * 16 + ll) * 128 + ks * 32 + lg * 8);
            acc[nt] = __builtin_amdgcn_mfma_f32_16x16x32_bf16(af[ks], wf, acc[nt], 0, 0, 0);
        }
    }

    const int rbase = m0 + w * 16 + lg * 4;
    float v[8][4];
#pragma unroll
    for (int nt = 0; nt < 8; ++nt) {
        const int col = nt * 16 + ll;
        const float bs = ldx(bias, (size_t)bOff + col, isf32);
        float g = 1.f, bb = 0.f, mmn = 0.f, rinv = 1.f, al = 0.f;
        if (EPI) {
            g    = ldx(bn, (size_t)bnOff + col, isf32);
            bb   = ldx(bn, (size_t)bnOff + 128 + col, isf32);
            mmn  = ldx(bn, (size_t)bnOff + 256 + col, isf32);
            rinv = rsqrtf(ldx(bn, (size_t)bnOff + 384 + col, isf32) + 1e-5f);
            al   = alpha_pc ? ldx(alpha, (size_t)aOff + col, isf32)
                            : ldx(alpha, (size_t)aOff, isf32);
        }
#pragma unroll
        for (int r = 0; r < 4; ++r) {
            const int row = rbase + r;
            float x = acc[nt][r] + bs;
            if (LNF) {
                const int src = REMAPR ? ((row >> 11) * 256 + (row & 255)) : row;
                x += Xres[(size_t)src * 128 + col];
            }
            if (EPI) {
                x = g * (x - mmn) * rinv + bb;
                x = (x >= 0.f) ? x : al * x;
            }
            v[nt][r] = x;
        }
    }

    if (LNF) {
        float s1[4], s2[4];
#pragma unroll
        for (int r = 0; r < 4; ++r) {
            float a = 0.f, b = 0.f;
#pragma unroll
            for (int nt = 0; nt < 8; ++nt) { a += v[nt][r]; b += v[nt][r] * v[nt][r]; }
#pragma unroll
            for (int o = 1; o < 16; o <<= 1) { a += __shfl_xor(a, o); b += __shfl_xor(b, o); }
            s1[r] = a; s2[r] = b;
        }
#pragma unroll
        for (int nt = 0; nt < 8; ++nt) {
            const int col = nt * 16 + ll;
            const float gam = ldx(lnp, (size_t)lnOff + col, isf32);
            const float bet = ldx(lnp, (size_t)lnOff + 128 + col, isf32);
#pragma unroll
            for (int r = 0; r < 4; ++r) {
                const float mu = s1[r] * (1.f / 128.f);
                const float var = s2[r] * (1.f / 128.f) - mu * mu;
                ((float*)out)[(size_t)(rbase + r) * 128 + col] =
                    gam * (v[nt][r] - mu) * rsqrtf(var + 1e-5f) + bet;
            }
        }
    } else if (FDOT) {
        float part[4] = {0.f, 0.f, 0.f, 0.f};
#pragma unroll
        for (int nt = 0; nt < 8; ++nt) {
            const int col = nt * 16 + ll;
            const float w3 = ldx(W3, col, isf32);
#pragma unroll
            for (int r = 0; r < 4; ++r) part[r] += v[nt][r] * w3;
        }
#pragma unroll
        for (int r = 0; r < 4; ++r) {
#pragma unroll
            for (int o = 1; o < 16; o <<= 1) part[r] += __shfl_xor(part[r], o);
        }
        if (ll == 0) {
            const float bb3 = ldx(b3, 0, isf32);
#pragma unroll
            for (int r = 0; r < 4; ++r) {
                const int row = rbase + r;
                if (isf32) ((float*)out)[row] = part[r] + bb3;
                else ((unsigned short*)out)[row] = f2bf(part[r] + bb3);
            }
        }
    }
}

// ---------------------------------------------------------------------------
// Pure-flash MFMA attention (R11-proven, unchanged).
// ---------------------------------------------------------------------------
template <int SELF, int NK>
__global__ __launch_bounds__(512, 2) void attn_kernel(
    const unsigned short* __restrict__ Qb,
    const unsigned short* __restrict__ Kb,
    const unsigned short* __restrict__ Vb,
    unsigned short* __restrict__ O,
    const void* __restrict__ center, const float* __restrict__ rs,
    const int* __restrict__ flagp, int bDiv) {
    constexpr int NKR = (NK + 31) & ~31;
    constexpr int VSTR = NKR + 8;
    __shared__ __align__(16) unsigned short sKb[NK * 36];
    __shared__ __align__(16) unsigned short sVT[32 * VSTR];
    __shared__ __align__(16) unsigned short sP[8 * 32 * 36];
    __shared__ float sF[256];
    __shared__ float sC[SELF ? 768 : 1];
    __shared__ float sR[SELF ? 256 : 1];

    const int isf32 = *flagp;
    const int s = blockIdx.x, h = blockIdx.y, tid = threadIdx.x;
    const int l = tid & 63, w = tid >> 6;
    const int hc = h * 32;
    const int lg = l >> 4, ll = l & 15;

    for (int idx = tid; idx < NK * 4; idx += 512) {
        const int j = idx >> 2, g = idx & 3;
        const uint4 t = *(const uint4*)(Kb + ((size_t)(s * NK + j)) * 128 + hc + g * 8);
        uint2* d = (uint2*)(sKb + j * 36 + g * 8);
        d[0] = make_uint2(t.x, t.y);
        d[1] = make_uint2(t.z, t.w);
    }
    for (int idx = tid; idx < NK * 4; idx += 512) {
        const int j = idx >> 2, g = idx & 3;
        const uint4 t = *(const uint4*)(Vb + ((size_t)(s * NK + j)) * 128 + hc + g * 8);
        const unsigned short* e = (const unsigned short*)&t;
#pragma unroll
        for (int u = 0; u < 8; ++u) sVT[(g * 8 + u) * VSTR + j] = e[u];
    }
    if constexpr (NKR != NK) {
        for (int idx = tid; idx < 32 * (NKR - NK); idx += 512) {
            const int i = idx / (NKR - NK), j = NK + idx % (NKR - NK);
            sVT[i * VSTR + j] = 0;
        }
    }
    if (SELF) {
        const int bb = s / bDiv;
        for (int idx = tid; idx < 768; idx += 512)
            sC[idx] = ldx(center, (size_t)bb * 768 + idx, isf32);
        if (tid < 256) sR[tid] = 1.0f / rs[bb * 256 + tid];
    }

    bf16x8 qfrag[2];
#pragma unroll
    for (int sub = 0; sub < 2; ++sub)
        qfrag[sub] = ld_frag16g(Qb + ((size_t)(s * 256 + w * 32 + sub * 16 + ll)) * 128 + hc + lg * 8);

    __syncthreads();

    const float scale = 0.17677669529663687f;
    float cqx[2], cqy[2], cqz[2];
    if (SELF) {
#pragma unroll
        for (int sub = 0; sub < 2; ++sub) {
            const int qg = w * 32 + sub * 16 + ll;
            cqx[sub] = sC[qg * 3]; cqy[sub] = sC[qg * 3 + 1]; cqz[sub] = sC[qg * 3 + 2];
        }
    }
    float m_[2] = {-3.0e38f, -3.0e38f}, l_[2] = {0.f, 0.f};
    const f32x4 zf = {0.f, 0.f, 0.f, 0.f};
    f32x4 oacc[2][2] = {{zf, zf}, {zf, zf}};
    unsigned short* sPw = sP + w * 32 * 36;

    for (int kb = 0; kb < NK; kb += 32) {
        const int full = (NK - kb) >= 32;
        const unsigned short* kbase = sKb + (kb + ll) * 36 + lg * 8;
        const bf16x8 kf0 = ld_frag8(kbase);
        bf16x8 kf1;
        if (full) kf1 = ld_frag8(kbase + 16 * 36);

#pragma unroll
        for (int sub = 0; sub < 2; ++sub) {
            f32x4 s0 = __builtin_amdgcn_mfma_f32_16x16x32_bf16(kf0, qfrag[sub], zf, 0, 0, 0);
            f32x4 s1 = zf;
            if (full) s1 = __builtin_amdgcn_mfma_f32_16x16x32_bf16(kf1, qfrag[sub], zf, 0, 0, 0);

            float sc[8];
#pragma unroll
            for (int r = 0; r < 4; ++r) {
                const int k0 = kb + lg * 4 + r;
                float v0 = s0[r] * scale;
                float v1 = full ? s1[r] * scale : -3.0e38f;
                if (SELF && h < 2) {
                    {
                        const float dx = cqx[sub] - sC[k0 * 3], dy = cqy[sub] - sC[k0 * 3 + 1],
                                    dz = cqz[sub] - sC[k0 * 3 + 2];
                        const float dist = sqrtf(dx * dx + dy * dy + dz * dz);
                        if (h == 0) v0 += __fdividef(1.f, dist + 0.01f) * sR[k0];
                        else v0 -= dist;
                    }
                    if (full) {
                        const int k1 = k0 + 16;
                        const float dx = cqx[sub] - sC[k1 * 3], dy = cqy[sub] - sC[k1 * 3 + 1],
                                    dz = cqz[sub] - sC[k1 * 3 + 2];
                        const float dist = sqrtf(dx * dx + dy * dy + dz * dz);
                        if (h == 0) v1 += __fdividef(1.f, dist + 0.01f) * sR[k1];
                        else v1 -= dist;
                    }
                }
                sc[r] = v0; sc[4 + r] = v1;
            }
            float tmax = fmaxf(fmaxf(fmaxf(sc[0], sc[1]), fmaxf(sc[2], sc[3])),
                               fmaxf(fmaxf(sc[4], sc[5]), fmaxf(sc[6], sc[7])));
            tmax = fmaxf(tmax, __shfl_xor(tmax, 16));
            tmax = fmaxf(tmax, __shfl_xor(tmax, 32));
            const float mnew = fmaxf(m_[sub], tmax);
            const float f = __expf(m_[sub] - mnew);
            m_[sub] = mnew;
            float p[8], lsum = 0.f;
#pragma unroll
            for (int u = 0; u < 8; ++u) { p[u] = __expf(sc[u] - mnew); lsum += p[u]; }
            lsum += __shfl_xor(lsum, 16);
            lsum += __shfl_xor(lsum, 32);
            l_[sub] = l_[sub] * f + lsum;
            if (lg == 0) sF[w * 32 + sub * 16 + ll] = f;
            unsigned* prow = (unsigned*)((char*)sPw + (sub * 16 + ll) * 72 + lg * 8);
            prow[0] = pack2bf(p[0], p[1]);
            prow[1] = pack2bf(p[2], p[3]);
            unsigned* prow1 = (unsigned*)((char*)prow + 32);
            prow1[0] = pack2bf(p[4], p[5]);
            prow1[1] = pack2bf(p[6], p[7]);
        }

        bf16x8 vf[2], pf[2];
#pragma unroll
        for (int dt = 0; dt < 2; ++dt)
            vf[dt] = *(const bf16x8*)(sVT + (dt * 16 + ll) * VSTR + kb + lg * 8);
#pragma unroll
        for (int sub = 0; sub < 2; ++sub) {
            pf[sub] = ld_frag8(sPw + (sub * 16 + ll) * 36 + lg * 8);
            float fr[4];
#pragma unroll
            for (int r = 0; r < 4; ++r) fr[r] = sF[w * 32 + sub * 16 + lg * 4 + r];
#pragma unroll
            for (int dt = 0; dt < 2; ++dt) {
#pragma unroll
                for (int r = 0; r < 4; ++r) oacc[sub][dt][r] *= fr[r];
                oacc[sub][dt] = __builtin_amdgcn_mfma_f32_16x16x32_bf16(
                    pf[sub], vf[dt], oacc[sub][dt], 0, 0, 0);
            }
        }
    }

    if (lg == 0) {
        sF[w * 32 + ll]      = 1.f / l_[0];
        sF[w * 32 + 16 + ll] = 1.f / l_[1];
    }
#pragma unroll
    for (int sub = 0; sub < 2; ++sub) {
#pragma unroll
        for (int r = 0; r < 4; ++r) {
            const float li = sF[w * 32 + sub * 16 + lg * 4 + r];
            const int qrow = w * 32 + sub * 16 + lg * 4 + r;
#pragma unroll
            for (int dt = 0; dt < 2; ++dt) {
                O[((size_t)(s * 256 + qrow)) * 128 + hc + dt * 16 + ll] =
                    f2bf_hw(oacc[sub][dt][r] * li);
            }
        }
    }
}

// ---------------------------------------------------------------------------

extern "C" void kernel_launch(void* const* d_in, const int* in_sizes, int n_in,
                              void* d_out, int out_size, void* d_ws, size_t ws_size,
                              hipStream_t stream) {
    bool ok = (n_in >= 29) && in_sizes[0] == 12288 && in_sizes[1] == 4718592 &&
              in_sizes[2] == 1310720 && in_sizes[7] == 147456 &&
              in_sizes[13] == 98304 && in_sizes[25] == 1024 && in_sizes[27] == 128;
    if (!ok) {
        sentinel_kernel<<<(out_size + 255) / 256, 256, 0, stream>>>(
            (unsigned short*)d_out, out_size, 0x44FA);
        return;
    }
    const size_t SZ = (size_t)32768 * 128;
    const size_t NEED = (16384ull + 2ull * SZ + 2ull * 10240 * 128) * 4ull;  // 44.1 MB (proven)
    if (ws_size < NEED) {
        sentinel_kernel<<<(out_size + 255) / 256, 256, 0, stream>>>(
            (unsigned short*)d_out, out_size, 0x447A);
        return;
    }

    const void* center = d_in[0];
    const void* detr   = d_in[1];
    const void* lang   = d_in[2];
    const void* fc1_W  = d_in[7];
    const void* fc1_b  = d_in[8];
    const void* bn0    = d_in[9];
    const void* prelu0 = d_in[10];
    const void* fc2_W  = d_in[11];
    const void* fc2_b  = d_in[12];
    const void* s_qkv  = d_in[13];
    const void* s_qkvb = d_in[14];
    const void* s_Wo   = d_in[15];
    const void* s_bo   = d_in[16];
    const void* s_ln   = d_in[17];
    const void* c_qkv  = d_in[18];
    const void* c_qkvb = d_in[19];
    const void* c_Wo   = d_in[20];
    const void* c_bo   = d_in[21];
    const void* c_ln   = d_in[22];
    const void* m_W    = d_in[23];
    const void* m_b    = d_in[24];
    const void* m_bn   = d_in[25];
    const void* m_al   = d_in[26];
    const void* m_W3   = d_in[27];
    const void* m_b3   = d_in[28];

    float* wsf  = (float*)d_ws;
    int*   flag = (int*)d_ws;
    float* rs   = wsf + 4096;
    float* X    = wsf + 16384;                      // f32 [32768][128]
    unsigned short* QB = (unsigned short*)(X + SZ); // bf16 [32768][128]
    unsigned short* KB = QB + SZ;
    unsigned short* VB = KB + SZ;
    unsigned short* Wt = VB + SZ;                   // bf16 458752
    float* XS = (float*)((char*)KB + 3670016);      // f32 [4096][128] (KB tail; disjoint
                                                    // from cross-K rows [0,10240) = 2.62 MB)

#define WTO(mat) (147456 + (mat) * 16384)

    detect_kernel<<<1, 256, 0, stream>>>((const unsigned short*)center, flag);
    prep_wt_kernel<<<1792, 256, 0, stream>>>(fc1_W, fc2_W, s_qkv, s_Wo, c_qkv, c_Wo, m_W, Wt, flag);
    rowsum_kernel<<<16, 256, 0, stream>>>(center, rs, flag);

    // fc1 (+BN+PReLU) -> KB bf16 [0,4096); fc2 -> X f32 (= x0)
    gemm_s_kernel<1, 1, 1, 0, 0><<<256, 512, 0, stream>>>(
        detr, Wt, 0, fc1_b, 0, KB, nullptr, nullptr, 1152, bn0, 0, prelu0, 0, 1, flag);
    gemm_s_kernel<1, 2, 0, 1, 0><<<256, 512, 0, stream>>>(
        KB, Wt, WTO(0), fc2_b, 0, X, nullptr, nullptr, 128, nullptr, 0, nullptr, 0, 0, flag);

    // self block 0: QKV (one pass) -> QB,KB,VB; attn O in-place QB;
    // Wo + res(x0 in X) + LN -> XS f32
    gemm_s_kernel<3, 0, 0, 0, 0><<<256, 512, 0, stream>>>(
        X, Wt, WTO(1), s_qkvb, 0, QB, KB, VB, 128, nullptr, 0, nullptr, 0, 0, flag);
    attn_kernel<1, 256><<<dim3(16, 4), 512, 0, stream>>>(QB, KB, VB, QB, center, rs, flag, 1);
    gemm_b_kernel<0, 1, 0, 0><<<64, 256, 0, stream>>>(
        QB, Wt, WTO(7), s_bo, 0, X, s_ln, 0, nullptr, 0, nullptr, 0, 0,
        nullptr, nullptr, XS, flag);

    // cross block 0: Q (remap-read XS) -> QB; K,V (lang, one pass) -> KB,VB;
    // attn; Wo + res(remap XS) + LN -> X
    gemm_s_kernel<1, 0, 0, 0, 1><<<2048, 512, 0, stream>>>(
        XS, Wt, WTO(9), c_qkvb, 0, QB, nullptr, nullptr, 128, nullptr, 0, nullptr, 0, 0, flag);
    gemm_s_kernel<2, 1, 0, 0, 0><<<640, 512, 0, stream>>>(
        lang, Wt, WTO(10), c_qkvb, 128, KB, VB, nullptr, 128, nullptr, 0, nullptr, 0, 0, flag);
    attn_kernel<0, 80><<<dim3(128, 4), 512, 0, stream>>>(QB, KB, VB, QB, nullptr, nullptr, flag, 1);
    gemm_b_kernel<1, 1, 0, 0><<<512, 256, 0, stream>>>(
        QB, Wt, WTO(15), c_bo, 0, XS, c_ln, 0, nullptr, 0, nullptr, 0, 0,
        nullptr, nullptr, X, flag);

    // self block 1: QKV -> QB,KB,VB; attn (bias b = s/8); Wo + res + LN -> X
    gemm_s_kernel<3, 0, 0, 0, 0><<<2048, 512, 0, stream>>>(
        X, Wt, WTO(4), s_qkvb, 384, QB, KB, VB, 128, nullptr, 0, nullptr, 0, 0, flag);
    attn_kernel<1, 256><<<dim3(128, 4), 512, 0, stream>>>(QB, KB, VB, QB, center, rs, flag, 8);
    gemm_b_kernel<0, 1, 0, 0><<<512, 256, 0, stream>>>(
        QB, Wt, WTO(8), s_bo, 128, X, s_ln, 256, nullptr, 0, nullptr, 0, 0,
        nullptr, nullptr, X, flag);

    // cross block 1
    gemm_s_kernel<1, 0, 0, 0, 0><<<2048, 512, 0, stream>>>(
        X, Wt, WTO(12), c_qkvb, 384, QB, nullptr, nullptr, 128, nullptr, 0, nullptr, 0, 0, flag);
    gemm_s_kernel<2, 1, 0, 0, 0><<<640, 512, 0, stream>>>(
        lang, Wt, WTO(13), c_qkvb, 512, KB, VB, nullptr, 128, nullptr, 0, nullptr, 0, 0, flag);
    attn_kernel<0, 80><<<dim3(128, 4), 512, 0, stream>>>(QB, KB, VB, QB, nullptr, nullptr, flag, 1);
    gemm_b_kernel<0, 1, 0, 0><<<512, 256, 0, stream>>>(
        QB, Wt, WTO(16), c_bo, 128, X, c_ln, 256, nullptr, 0, nullptr, 0, 0,
        nullptr, nullptr, X, flag);

    // match head: GEMM1 (BN+PReLU) -> KB bf16; GEMM2 (BN+PReLU + W3 dot) -> d_out
    gemm_s_kernel<1, 0, 1, 0, 0><<<2048, 512, 0, stream>>>(
        X, Wt, WTO(17), m_b, 0, KB, nullptr, nullptr, 128, m_bn, 0, m_al, 0, 0, flag);
    gemm_b_kernel<0, 0, 1, 1><<<512, 256, 0, stream>>>(
        KB, Wt, WTO(18), m_b, 128, nullptr, nullptr, 0, m_bn, 512, m_al, 1, 0,
        m_W3, m_b3, d_out, flag);
#undef WTO
}

// Round 13
// 334.805 us; speedup vs baseline: 5.1161x; 1.1247x over previous
//
#include <hip/hip_runtime.h>

// ---------------------------------------------------------------------------
// MatchModule forward. H=4 D=128 B=16 K=256 M=8 L=80 DET_C=1152, dk=32.
// R13: 32768-row GEMMs moved from gemm_s (16-row blocks, latency-bound:
// 12 MFMA/wave vs 44 dependent loads) to gemm_r (64-row blocks, wave = 16
// full rows, NOUT fused outputs, 32-96 MFMA/wave hides L2 latency).
// gemm_s kept for small-row / large-K (fc1, fc2, self0 QKV, cross K/V).
// attn / gemm_b (LN, FDOT epilogues) unchanged (proven).
// ws layout (bytes): flag|rs | X f32 16.8M | QB | KB (XS@+3.5M) | VB | Wt.
// ---------------------------------------------------------------------------

#define DD 128

typedef __attribute__((ext_vector_type(8))) short bf16x8;
typedef __attribute__((ext_vector_type(4))) float f32x4;

__device__ __forceinline__ float bf2f(unsigned short u) {
    union { unsigned int i; float f; } v; v.i = ((unsigned int)u) << 16; return v.f;
}
__device__ __forceinline__ unsigned short f2bf(float f) {   // manual RTNE (cold paths)
    union { float f; unsigned int i; } v; v.f = f;
    unsigned int x = v.i;
    return (unsigned short)((x + 0x7FFFu + ((x >> 16) & 1u)) >> 16);
}
__device__ __forceinline__ unsigned pack2bf(float a, float b) {  // lo=a, hi=b
    unsigned r;
    asm("v_cvt_pk_bf16_f32 %0, %1, %2" : "=v"(r) : "v"(a), "v"(b));
    return r;
}
__device__ __forceinline__ unsigned short f2bf_hw(float a) {
    unsigned r;
    asm("v_cvt_pk_bf16_f32 %0, %1, %1" : "=v"(r) : "v"(a));
    return (unsigned short)r;
}
__device__ __forceinline__ float ldx(const void* p, size_t i, int isf32) {
    return isf32 ? ((const float*)p)[i] : bf2f(((const unsigned short*)p)[i]);
}
__device__ __forceinline__ bf16x8 ld_frag8(const unsigned short* base) {  // 8B-aligned (LDS)
    union { bf16x8 v; uint2 u[2]; } r;
    r.u[0] = *(const uint2*)(base);
    r.u[1] = *(const uint2*)(base + 4);
    return r.v;
}
__device__ __forceinline__ bf16x8 ld_frag16g(const unsigned short* p) {   // 16B-aligned
    union { bf16x8 v; uint4 u; } r;
    r.u = *(const uint4*)p;
    return r.v;
}

// ---------------------------------------------------------------------------
__global__ __launch_bounds__(256) void detect_kernel(
    const unsigned short* __restrict__ c, int* __restrict__ flag) {
    __shared__ int cnt;
    if (threadIdx.x == 0) cnt = 0;
    __syncthreads();
    float v = bf2f(c[threadIdx.x]);
    int sane = (v == v) && (fabsf(v) <= 1e4f) && (v == 0.f || fabsf(v) >= 1e-10f);
    atomicAdd(&cnt, sane);
    __syncthreads();
    if (threadIdx.x == 0) flag[0] = (cnt >= 224) ? 0 : 1;  // 0=bf16, 1=f32
}

__global__ void sentinel_kernel(unsigned short* out, int n, int val) {
    int i = blockIdx.x * 256 + threadIdx.x;
    if (i < n) out[i] = (unsigned short)val;
}

// ---------------------------------------------------------------------------
// prep_wt: Wt = bf16(W^T). region 0: fc1^T [128][1152]. Then 19 [128][128]:
// 0=fc2, 1..6=s_qkv, 7..8=s_Wo, 9..14=c_qkv, 15..16=c_Wo, 17..18=m_W.
// ---------------------------------------------------------------------------
__global__ __launch_bounds__(256) void prep_wt_kernel(
    const void* __restrict__ fc1_W, const void* __restrict__ fc2_W,
    const void* __restrict__ s_qkv, const void* __restrict__ s_Wo,
    const void* __restrict__ c_qkv, const void* __restrict__ c_Wo,
    const void* __restrict__ m_W, unsigned short* __restrict__ Wt,
    const int* __restrict__ flagp) {
    const int isf32 = *flagp;
    const int j = blockIdx.x * 256 + threadIdx.x;
    float v;
    if (j < 147456) {
        const int n = j / 1152, k = j - n * 1152;
        v = ldx(fc1_W, (size_t)k * 128 + n, isf32);
    } else {
        const int t = j - 147456;
        const int mat = t >> 14, o = t & 16383;
        const int n = o >> 7, k = o & 127;
        const void* src; int loc;
        if (mat == 0)       { src = fc2_W; loc = 0; }
        else if (mat <= 6)  { src = s_qkv; loc = mat - 1; }
        else if (mat <= 8)  { src = s_Wo;  loc = mat - 7; }
        else if (mat <= 14) { src = c_qkv; loc = mat - 9; }
        else if (mat <= 16) { src = c_Wo;  loc = mat - 15; }
        else                { src = m_W;   loc = mat - 17; }
        v = ldx(src, (size_t)loc * 16384 + k * 128 + n, isf32);
    }
    Wt[j] = f2bf(v);
}

// ---------------------------------------------------------------------------
__global__ __launch_bounds__(256) void rowsum_kernel(
    const void* __restrict__ center, float* __restrict__ rs,
    const int* __restrict__ flagp) {
    const int isf32 = *flagp;
    const int b = blockIdx.x, i = threadIdx.x;
    __shared__ float c[768];
    for (int idx = i; idx < 768; idx += 256) c[idx] = ldx(center, (size_t)b * 768 + idx, isf32);
    __syncthreads();
    const float cx = c[i * 3], cy = c[i * 3 + 1], cz = c[i * 3 + 2];
    float s = 0.f;
    for (int j = 0; j < 256; ++j) {
        float dx = cx - c[j * 3], dy = cy - c[j * 3 + 1], dz = cz - c[j * 3 + 2];
        s += 1.f / (sqrtf(dx * dx + dy * dy + dz * dz) + 0.01f);
    }
    rs[b * 256 + i] = s;
}

// ---------------------------------------------------------------------------
// gemm_s: 512 thr = 8 waves; block = 16 rows; wave w = one 16-col tile.
// For SMALL nrows or large Kdim (fc1/fc2/self0/cross-KV). (R12-proven.)
// ---------------------------------------------------------------------------
template <int NOUT, int AMODE, int EPI, int OUTF32, int REMAP>
__global__ __launch_bounds__(512, 2) void gemm_s_kernel(
    const void* __restrict__ A,
    const unsigned short* __restrict__ Wt, int wtOff,
    const void* __restrict__ bias, int bOff,
    void* __restrict__ out0, void* __restrict__ out1, void* __restrict__ out2,
    int Kdim,
    const void* __restrict__ bn, int bnOff,
    const void* __restrict__ alpha, int aOff, int alpha_pc,
    const int* __restrict__ flagp) {
    const int isf32 = *flagp;
    const bool f32A = (AMODE == 0) || (AMODE == 1 && isf32);
    const int tid = threadIdx.x;
    const int l = tid & 63, w = tid >> 6;
    const int lg = l >> 4, ll = l & 15;
    const int m0 = blockIdx.x * 16;
    int arow = m0 + ll;
    if (REMAP) arow = (arow >> 11) * 256 + (arow & 255);
    const f32x4 zf = {0.f, 0.f, 0.f, 0.f};
    f32x4 acc[NOUT];
#pragma unroll
    for (int o = 0; o < NOUT; ++o) acc[o] = zf;
    const float* Af = (const float*)A;
    const unsigned short* Au = (const unsigned short*)A;
    const unsigned short* Wb = Wt + wtOff;
    const int wrow = w * 16 + ll;

    for (int kc = 0; kc < Kdim; kc += 128) {
        bf16x8 af[4];
        if (f32A) {
#pragma unroll
            for (int ks = 0; ks < 4; ++ks) {
                const float4* ap = (const float4*)(Af + (size_t)arow * Kdim + kc + ks * 32 + lg * 8);
                const float4 a0 = ap[0], a1 = ap[1];
                union { bf16x8 v; unsigned u[4]; } r;
                r.u[0] = pack2bf(a0.x, a0.y); r.u[1] = pack2bf(a0.z, a0.w);
                r.u[2] = pack2bf(a1.x, a1.y); r.u[3] = pack2bf(a1.z, a1.w);
                af[ks] = r.v;
            }
        } else {
#pragma unroll
            for (int ks = 0; ks < 4; ++ks)
                af[ks] = ld_frag16g(Au + (size_t)arow * Kdim + kc + ks * 32 + lg * 8);
        }
#pragma unroll
        for (int o = 0; o < NOUT; ++o) {
#pragma unroll
            for (int ks = 0; ks < 4; ++ks) {
                const bf16x8 wf = ld_frag16g(
                    Wb + (size_t)o * 128 * Kdim + (size_t)wrow * Kdim + kc + ks * 32 + lg * 8);
                acc[o] = __builtin_amdgcn_mfma_f32_16x16x32_bf16(af[ks], wf, acc[o], 0, 0, 0);
            }
        }
    }

    const int col = w * 16 + ll;
    const int rbase = m0 + lg * 4;
#pragma unroll
    for (int o = 0; o < NOUT; ++o) {
        void* outp = (o == 0) ? out0 : (o == 1) ? out1 : out2;
        const float bs = ldx(bias, (size_t)bOff + o * 128 + col, isf32);
        float g = 1.f, bb = 0.f, mmn = 0.f, rinv = 1.f, al = 0.f;
        if (EPI) {
            g    = ldx(bn, (size_t)bnOff + col, isf32);
            bb   = ldx(bn, (size_t)bnOff + 128 + col, isf32);
            mmn  = ldx(bn, (size_t)bnOff + 256 + col, isf32);
            rinv = rsqrtf(ldx(bn, (size_t)bnOff + 384 + col, isf32) + 1e-5f);
            al   = alpha_pc ? ldx(alpha, (size_t)aOff + col, isf32)
                            : ldx(alpha, (size_t)aOff, isf32);
        }
#pragma unroll
        for (int r = 0; r < 4; ++r) {
            float v = acc[o][r] + bs;
            if (EPI) {
                v = g * (v - mmn) * rinv + bb;
                v = (v >= 0.f) ? v : al * v;
            }
            const size_t oi = (size_t)(rbase + r) * 128 + col;
            if (OUTF32) ((float*)outp)[oi] = v;
            else ((unsigned short*)outp)[oi] = f2bf_hw(v);
        }
    }
}

// ---------------------------------------------------------------------------
// gemm_r: 256 thr = 4 waves; block = 64 rows; wave owns 16 FULL rows; Kdim=128.
// NOUT fused outputs (bf16). AMODE: 0 = f32 buf, 2 = bf16 buf. EPI: BN+PReLU.
// REMAP: A row -> (row>>11)*256 + (row&255). For LARGE-nrows Kdim-128 GEMMs:
// 32-96 MFMA/wave hides load latency (vs gemm_s's 12).
// ---------------------------------------------------------------------------
template <int NOUT, int AMODE, int EPI, int REMAP>
__global__ __launch_bounds__(256, 4) void gemm_r_kernel(
    const void* __restrict__ A,
    const unsigned short* __restrict__ Wt, int wtOff,
    const void* __restrict__ bias, int bOff,
    void* __restrict__ out0, void* __restrict__ out1, void* __restrict__ out2,
    const void* __restrict__ bn, int bnOff,
    const void* __restrict__ alpha, int aOff, int alpha_pc,
    const int* __restrict__ flagp) {
    const int isf32 = *flagp;
    const int tid = threadIdx.x;
    const int l = tid & 63, w = tid >> 6;
    const int lg = l >> 4, ll = l & 15;
    const int m0 = blockIdx.x * 64;
    int arow = m0 + w * 16 + ll;
    if (REMAP) arow = (arow >> 11) * 256 + (arow & 255);
    const f32x4 zf = {0.f, 0.f, 0.f, 0.f};
    f32x4 acc[NOUT][8];
#pragma unroll
    for (int o = 0; o < NOUT; ++o)
#pragma unroll
        for (int nt = 0; nt < 8; ++nt) acc[o][nt] = zf;
    const unsigned short* Wb = Wt + wtOff;

    bf16x8 af[4];
    if (AMODE == 0) {
        const float* Af = (const float*)A;
#pragma unroll
        for (int ks = 0; ks < 4; ++ks) {
            const float4* ap = (const float4*)(Af + (size_t)arow * 128 + ks * 32 + lg * 8);
            const float4 a0 = ap[0], a1 = ap[1];
            union { bf16x8 v; unsigned u[4]; } r;
            r.u[0] = pack2bf(a0.x, a0.y); r.u[1] = pack2bf(a0.z, a0.w);
            r.u[2] = pack2bf(a1.x, a1.y); r.u[3] = pack2bf(a1.z, a1.w);
            af[ks] = r.v;
        }
    } else {
        const unsigned short* Au = (const unsigned short*)A;
#pragma unroll
        for (int ks = 0; ks < 4; ++ks)
            af[ks] = ld_frag16g(Au + (size_t)arow * 128 + ks * 32 + lg * 8);
    }
#pragma unroll
    for (int o = 0; o < NOUT; ++o) {
#pragma unroll
        for (int nt = 0; nt < 8; ++nt) {
#pragma unroll
            for (int ks = 0; ks < 4; ++ks) {
                const bf16x8 wf = ld_frag16g(
                    Wb + (size_t)o * 16384 + (size_t)(nt * 16 + ll) * 128 + ks * 32 + lg * 8);
                acc[o][nt] = __builtin_amdgcn_mfma_f32_16x16x32_bf16(af[ks], wf, acc[o][nt], 0, 0, 0);
            }
        }
    }

    const int rbase = m0 + w * 16 + lg * 4;
#pragma unroll
    for (int o = 0; o < NOUT; ++o) {
        unsigned short* outp = (unsigned short*)((o == 0) ? out0 : (o == 1) ? out1 : out2);
#pragma unroll
        for (int nt = 0; nt < 8; ++nt) {
            const int col = nt * 16 + ll;
            const float bs = ldx(bias, (size_t)bOff + o * 128 + col, isf32);
            float g = 1.f, bb = 0.f, mmn = 0.f, rinv = 1.f, al = 0.f;
            if (EPI) {
                g    = ldx(bn, (size_t)bnOff + col, isf32);
                bb   = ldx(bn, (size_t)bnOff + 128 + col, isf32);
                mmn  = ldx(bn, (size_t)bnOff + 256 + col, isf32);
                rinv = rsqrtf(ldx(bn, (size_t)bnOff + 384 + col, isf32) + 1e-5f);
                al   = alpha_pc ? ldx(alpha, (size_t)aOff + col, isf32)
                                : ldx(alpha, (size_t)aOff, isf32);
            }
#pragma unroll
            for (int r = 0; r < 4; ++r) {
                float v = acc[o][nt][r] + bs;
                if (EPI) {
                    v = g * (v - mmn) * rinv + bb;
                    v = (v >= 0.f) ? v : al * v;
                }
                outp[(size_t)(rbase + r) * 128 + col] = f2bf_hw(v);
            }
        }
    }
}

// ---------------------------------------------------------------------------
// gemm_b: 256 thr = 4 waves; block = 64 rows; wave owns 16 FULL rows.
// LNF: residual + in-wave LayerNorm -> f32 out. FDOT: W3 dot -> d_out.
// (R12-proven.)
// ---------------------------------------------------------------------------
template <int REMAPR, int LNF, int EPI, int FDOT>
__global__ __launch_bounds__(256, 4) void gemm_b_kernel(
    const unsigned short* __restrict__ A,
    const unsigned short* __restrict__ Wt, int wtOff,
    const void* __restrict__ bias, int bOff,
    const float* __restrict__ Xres,
    const void* __restrict__ lnp, int lnOff,
    const void* __restrict__ bn, int bnOff,
    const void* __restrict__ alpha, int aOff, int alpha_pc,
    const void* __restrict__ W3, const void* __restrict__ b3,
    void* __restrict__ out, const int* __restrict__ flagp) {
    const int isf32 = *flagp;
    const int tid = threadIdx.x;
    const int l = tid & 63, w = tid >> 6;
    const int lg = l >> 4, ll = l & 15;
    const int m0 = blockIdx.x * 64;
    const int arow = m0 + w * 16 + ll;
    const f32x4 zf = {0.f, 0.f, 0.f, 0.f};
    f32x4 acc[8] = {zf, zf, zf, zf, zf, zf, zf, zf};
    const unsigned short* Wb = Wt + wtOff;

    bf16x8 af[4];
#pragma unroll
    for (int ks = 0; ks < 4; ++ks)
        af[ks] = ld_frag16g(A + (size_t)arow * 128 + ks * 32 + lg * 8);
#pragma unroll
    for (int nt = 0; nt < 8; ++nt) {
#pragma unroll
        for (int ks = 0; ks < 4; ++ks) {
            const bf16x8 wf = ld_frag16g(Wb + (size_t)(nt * 16 + ll) * 128 + ks * 32 + lg * 8);
            acc[nt] = __builtin_amdgcn_mfma_f32_16x16x32_bf16(af[ks], wf, acc[nt], 0, 0, 0);
        }
    }

    const int rbase = m0 + w * 16 + lg * 4;
    float v[8][4];
#pragma unroll
    for (int nt = 0; nt < 8; ++nt) {
        const int col = nt * 16 + ll;
        const float bs = ldx(bias, (size_t)bOff + col, isf32);
        float g = 1.f, bb = 0.f, mmn = 0.f, rinv = 1.f, al = 0.f;
        if (EPI) {
            g    = ldx(bn, (size_t)bnOff + col, isf32);
            bb   = ldx(bn, (size_t)bnOff + 128 + col, isf32);
            mmn  = ldx(bn, (size_t)bnOff + 256 + col, isf32);
            rinv = rsqrtf(ldx(bn, (size_t)bnOff + 384 + col, isf32) + 1e-5f);
            al   = alpha_pc ? ldx(alpha, (size_t)aOff + col, isf32)
                            : ldx(alpha, (size_t)aOff, isf32);
        }
#pragma unroll
        for (int r = 0; r < 4; ++r) {
            const int row = rbase + r;
            float x = acc[nt][r] + bs;
            if (LNF) {
                const int src = REMAPR ? ((row >> 11) * 256 + (row & 255)) : row;
                x += Xres[(size_t)src * 128 + col];
            }
            if (EPI) {
                x = g * (x - mmn) * rinv + bb;
                x = (x >= 0.f) ? x : al * x;
            }
            v[nt][r] = x;
        }
    }

    if (LNF) {
        float s1[4], s2[4];
#pragma unroll
        for (int r = 0; r < 4; ++r) {
            float a = 0.f, b = 0.f;
#pragma unroll
            for (int nt = 0; nt < 8; ++nt) { a += v[nt][r]; b += v[nt][r] * v[nt][r]; }
#pragma unroll
            for (int o = 1; o < 16; o <<= 1) { a += __shfl_xor(a, o); b += __shfl_xor(b, o); }
            s1[r] = a; s2[r] = b;
        }
#pragma unroll
        for (int nt = 0; nt < 8; ++nt) {
            const int col = nt * 16 + ll;
            const float gam = ldx(lnp, (size_t)lnOff + col, isf32);
            const float bet = ldx(lnp, (size_t)lnOff + 128 + col, isf32);
#pragma unroll
            for (int r = 0; r < 4; ++r) {
                const float mu = s1[r] * (1.f / 128.f);
                const float var = s2[r] * (1.f / 128.f) - mu * mu;
                ((float*)out)[(size_t)(rbase + r) * 128 + col] =
                    gam * (v[nt][r] - mu) * rsqrtf(var + 1e-5f) + bet;
            }
        }
    } else if (FDOT) {
        float part[4] = {0.f, 0.f, 0.f, 0.f};
#pragma unroll
        for (int nt = 0; nt < 8; ++nt) {
            const int col = nt * 16 + ll;
            const float w3 = ldx(W3, col, isf32);
#pragma unroll
            for (int r = 0; r < 4; ++r) part[r] += v[nt][r] * w3;
        }
#pragma unroll
        for (int r = 0; r < 4; ++r) {
#pragma unroll
            for (int o = 1; o < 16; o <<= 1) part[r] += __shfl_xor(part[r], o);
        }
        if (ll == 0) {
            const float bb3 = ldx(b3, 0, isf32);
#pragma unroll
            for (int r = 0; r < 4; ++r) {
                const int row = rbase + r;
                if (isf32) ((float*)out)[row] = part[r] + bb3;
                else ((unsigned short*)out)[row] = f2bf(part[r] + bb3);
            }
        }
    }
}

// ---------------------------------------------------------------------------
// Pure-flash MFMA attention (R11-proven, unchanged).
// ---------------------------------------------------------------------------
template <int SELF, int NK>
__global__ __launch_bounds__(512, 2) void attn_kernel(
    const unsigned short* __restrict__ Qb,
    const unsigned short* __restrict__ Kb,
    const unsigned short* __restrict__ Vb,
    unsigned short* __restrict__ O,
    const void* __restrict__ center, const float* __restrict__ rs,
    const int* __restrict__ flagp, int bDiv) {
    constexpr int NKR = (NK + 31) & ~31;
    constexpr int VSTR = NKR + 8;
    __shared__ __align__(16) unsigned short sKb[NK * 36];
    __shared__ __align__(16) unsigned short sVT[32 * VSTR];
    __shared__ __align__(16) unsigned short sP[8 * 32 * 36];
    __shared__ float sF[256];
    __shared__ float sC[SELF ? 768 : 1];
    __shared__ float sR[SELF ? 256 : 1];

    const int isf32 = *flagp;
    const int s = blockIdx.x, h = blockIdx.y, tid = threadIdx.x;
    const int l = tid & 63, w = tid >> 6;
    const int hc = h * 32;
    const int lg = l >> 4, ll = l & 15;

    for (int idx = tid; idx < NK * 4; idx += 512) {
        const int j = idx >> 2, g = idx & 3;
        const uint4 t = *(const uint4*)(Kb + ((size_t)(s * NK + j)) * 128 + hc + g * 8);
        uint2* d = (uint2*)(sKb + j * 36 + g * 8);
        d[0] = make_uint2(t.x, t.y);
        d[1] = make_uint2(t.z, t.w);
    }
    for (int idx = tid; idx < NK * 4; idx += 512) {
        const int j = idx >> 2, g = idx & 3;
        const uint4 t = *(const uint4*)(Vb + ((size_t)(s * NK + j)) * 128 + hc + g * 8);
        const unsigned short* e = (const unsigned short*)&t;
#pragma unroll
        for (int u = 0; u < 8; ++u) sVT[(g * 8 + u) * VSTR + j] = e[u];
    }
    if constexpr (NKR != NK) {
        for (int idx = tid; idx < 32 * (NKR - NK); idx += 512) {
            const int i = idx / (NKR - NK), j = NK + idx % (NKR - NK);
            sVT[i * VSTR + j] = 0;
        }
    }
    if (SELF) {
        const int bb = s / bDiv;
        for (int idx = tid; idx < 768; idx += 512)
            sC[idx] = ldx(center, (size_t)bb * 768 + idx, isf32);
        if (tid < 256) sR[tid] = 1.0f / rs[bb * 256 + tid];
    }

    bf16x8 qfrag[2];
#pragma unroll
    for (int sub = 0; sub < 2; ++sub)
        qfrag[sub] = ld_frag16g(Qb + ((size_t)(s * 256 + w * 32 + sub * 16 + ll)) * 128 + hc + lg * 8);

    __syncthreads();

    const float scale = 0.17677669529663687f;
    float cqx[2], cqy[2], cqz[2];
    if (SELF) {
#pragma unroll
        for (int sub = 0; sub < 2; ++sub) {
            const int qg = w * 32 + sub * 16 + ll;
            cqx[sub] = sC[qg * 3]; cqy[sub] = sC[qg * 3 + 1]; cqz[sub] = sC[qg * 3 + 2];
        }
    }
    float m_[2] = {-3.0e38f, -3.0e38f}, l_[2] = {0.f, 0.f};
    const f32x4 zf = {0.f, 0.f, 0.f, 0.f};
    f32x4 oacc[2][2] = {{zf, zf}, {zf, zf}};
    unsigned short* sPw = sP + w * 32 * 36;

    for (int kb = 0; kb < NK; kb += 32) {
        const int full = (NK - kb) >= 32;
        const unsigned short* kbase = sKb + (kb + ll) * 36 + lg * 8;
        const bf16x8 kf0 = ld_frag8(kbase);
        bf16x8 kf1;
        if (full) kf1 = ld_frag8(kbase + 16 * 36);

#pragma unroll
        for (int sub = 0; sub < 2; ++sub) {
            f32x4 s0 = __builtin_amdgcn_mfma_f32_16x16x32_bf16(kf0, qfrag[sub], zf, 0, 0, 0);
            f32x4 s1 = zf;
            if (full) s1 = __builtin_amdgcn_mfma_f32_16x16x32_bf16(kf1, qfrag[sub], zf, 0, 0, 0);

            float sc[8];
#pragma unroll
            for (int r = 0; r < 4; ++r) {
                const int k0 = kb + lg * 4 + r;
                float v0 = s0[r] * scale;
                float v1 = full ? s1[r] * scale : -3.0e38f;
                if (SELF && h < 2) {
                    {
                        const float dx = cqx[sub] - sC[k0 * 3], dy = cqy[sub] - sC[k0 * 3 + 1],
                                    dz = cqz[sub] - sC[k0 * 3 + 2];
                        const float dist = sqrtf(dx * dx + dy * dy + dz * dz);
                        if (h == 0) v0 += __fdividef(1.f, dist + 0.01f) * sR[k0];
                        else v0 -= dist;
                    }
                    if (full) {
                        const int k1 = k0 + 16;
                        const float dx = cqx[sub] - sC[k1 * 3], dy = cqy[sub] - sC[k1 * 3 + 1],
                                    dz = cqz[sub] - sC[k1 * 3 + 2];
                        const float dist = sqrtf(dx * dx + dy * dy + dz * dz);
                        if (h == 0) v1 += __fdividef(1.f, dist + 0.01f) * sR[k1];
                        else v1 -= dist;
                    }
                }
                sc[r] = v0; sc[4 + r] = v1;
            }
            float tmax = fmaxf(fmaxf(fmaxf(sc[0], sc[1]), fmaxf(sc[2], sc[3])),
                               fmaxf(fmaxf(sc[4], sc[5]), fmaxf(sc[6], sc[7])));
            tmax = fmaxf(tmax, __shfl_xor(tmax, 16));
            tmax = fmaxf(tmax, __shfl_xor(tmax, 32));
            const float mnew = fmaxf(m_[sub], tmax);
            const float f = __expf(m_[sub] - mnew);
            m_[sub] = mnew;
            float p[8], lsum = 0.f;
#pragma unroll
            for (int u = 0; u < 8; ++u) { p[u] = __expf(sc[u] - mnew); lsum += p[u]; }
            lsum += __shfl_xor(lsum, 16);
            lsum += __shfl_xor(lsum, 32);
            l_[sub] = l_[sub] * f + lsum;
            if (lg == 0) sF[w * 32 + sub * 16 + ll] = f;
            unsigned* prow = (unsigned*)((char*)sPw + (sub * 16 + ll) * 72 + lg * 8);
            prow[0] = pack2bf(p[0], p[1]);
            prow[1] = pack2bf(p[2], p[3]);
            unsigned* prow1 = (unsigned*)((char*)prow + 32);
            prow1[0] = pack2bf(p[4], p[5]);
            prow1[1] = pack2bf(p[6], p[7]);
        }

        bf16x8 vf[2], pf[2];
#pragma unroll
        for (int dt = 0; dt < 2; ++dt)
            vf[dt] = *(const bf16x8*)(sVT + (dt * 16 + ll) * VSTR + kb + lg * 8);
#pragma unroll
        for (int sub = 0; sub < 2; ++sub) {
            pf[sub] = ld_frag8(sPw + (sub * 16 + ll) * 36 + lg * 8);
            float fr[4];
#pragma unroll
            for (int r = 0; r < 4; ++r) fr[r] = sF[w * 32 + sub * 16 + lg * 4 + r];
#pragma unroll
            for (int dt = 0; dt < 2; ++dt) {
#pragma unroll
                for (int r = 0; r < 4; ++r) oacc[sub][dt][r] *= fr[r];
                oacc[sub][dt] = __builtin_amdgcn_mfma_f32_16x16x32_bf16(
                    pf[sub], vf[dt], oacc[sub][dt], 0, 0, 0);
            }
        }
    }

    if (lg == 0) {
        sF[w * 32 + ll]      = 1.f / l_[0];
        sF[w * 32 + 16 + ll] = 1.f / l_[1];
    }
#pragma unroll
    for (int sub = 0; sub < 2; ++sub) {
#pragma unroll
        for (int r = 0; r < 4; ++r) {
            const float li = sF[w * 32 + sub * 16 + lg * 4 + r];
            const int qrow = w * 32 + sub * 16 + lg * 4 + r;
#pragma unroll
            for (int dt = 0; dt < 2; ++dt) {
                O[((size_t)(s * 256 + qrow)) * 128 + hc + dt * 16 + ll] =
                    f2bf_hw(oacc[sub][dt][r] * li);
            }
        }
    }
}

// ---------------------------------------------------------------------------

extern "C" void kernel_launch(void* const* d_in, const int* in_sizes, int n_in,
                              void* d_out, int out_size, void* d_ws, size_t ws_size,
                              hipStream_t stream) {
    bool ok = (n_in >= 29) && in_sizes[0] == 12288 && in_sizes[1] == 4718592 &&
              in_sizes[2] == 1310720 && in_sizes[7] == 147456 &&
              in_sizes[13] == 98304 && in_sizes[25] == 1024 && in_sizes[27] == 128;
    if (!ok) {
        sentinel_kernel<<<(out_size + 255) / 256, 256, 0, stream>>>(
            (unsigned short*)d_out, out_size, 0x44FA);
        return;
    }
    const size_t SZ = (size_t)32768 * 128;
    const size_t NEED = (16384ull + 2ull * SZ + 2ull * 10240 * 128) * 4ull;  // 44.1 MB (proven)
    if (ws_size < NEED) {
        sentinel_kernel<<<(out_size + 255) / 256, 256, 0, stream>>>(
            (unsigned short*)d_out, out_size, 0x447A);
        return;
    }

    const void* center = d_in[0];
    const void* detr   = d_in[1];
    const void* lang   = d_in[2];
    const void* fc1_W  = d_in[7];
    const void* fc1_b  = d_in[8];
    const void* bn0    = d_in[9];
    const void* prelu0 = d_in[10];
    const void* fc2_W  = d_in[11];
    const void* fc2_b  = d_in[12];
    const void* s_qkv  = d_in[13];
    const void* s_qkvb = d_in[14];
    const void* s_Wo   = d_in[15];
    const void* s_bo   = d_in[16];
    const void* s_ln   = d_in[17];
    const void* c_qkv  = d_in[18];
    const void* c_qkvb = d_in[19];
    const void* c_Wo   = d_in[20];
    const void* c_bo   = d_in[21];
    const void* c_ln   = d_in[22];
    const void* m_W    = d_in[23];
    const void* m_b    = d_in[24];
    const void* m_bn   = d_in[25];
    const void* m_al   = d_in[26];
    const void* m_W3   = d_in[27];
    const void* m_b3   = d_in[28];

    float* wsf  = (float*)d_ws;
    int*   flag = (int*)d_ws;
    float* rs   = wsf + 4096;
    float* X    = wsf + 16384;                      // f32 [32768][128]
    unsigned short* QB = (unsigned short*)(X + SZ); // bf16 [32768][128]
    unsigned short* KB = QB + SZ;
    unsigned short* VB = KB + SZ;
    unsigned short* Wt = VB + SZ;                   // bf16 458752
    float* XS = (float*)((char*)KB + 3670016);      // f32 [4096][128] (KB tail; disjoint
                                                    // from cross-K rows [0,10240))

#define WTO(mat) (147456 + (mat) * 16384)

    detect_kernel<<<1, 256, 0, stream>>>((const unsigned short*)center, flag);
    prep_wt_kernel<<<1792, 256, 0, stream>>>(fc1_W, fc2_W, s_qkv, s_Wo, c_qkv, c_Wo, m_W, Wt, flag);
    rowsum_kernel<<<16, 256, 0, stream>>>(center, rs, flag);

    // fc1 (+BN+PReLU) -> KB bf16 [0,4096); fc2 -> X f32 (= x0)
    gemm_s_kernel<1, 1, 1, 0, 0><<<256, 512, 0, stream>>>(
        detr, Wt, 0, fc1_b, 0, KB, nullptr, nullptr, 1152, bn0, 0, prelu0, 0, 1, flag);
    gemm_s_kernel<1, 2, 0, 1, 0><<<256, 512, 0, stream>>>(
        KB, Wt, WTO(0), fc2_b, 0, X, nullptr, nullptr, 128, nullptr, 0, nullptr, 0, 0, flag);

    // self block 0 (4096 rows): QKV (one pass) -> QB,KB,VB; attn O in-place QB;
    // Wo + res(x0 in X) + LN -> XS f32
    gemm_s_kernel<3, 0, 0, 0, 0><<<256, 512, 0, stream>>>(
        X, Wt, WTO(1), s_qkvb, 0, QB, KB, VB, 128, nullptr, 0, nullptr, 0, 0, flag);
    attn_kernel<1, 256><<<dim3(16, 4), 512, 0, stream>>>(QB, KB, VB, QB, center, rs, flag, 1);
    gemm_b_kernel<0, 1, 0, 0><<<64, 256, 0, stream>>>(
        QB, Wt, WTO(7), s_bo, 0, X, s_ln, 0, nullptr, 0, nullptr, 0, 0,
        nullptr, nullptr, XS, flag);

    // cross block 0: Q (remap-read XS) -> QB; K,V (lang, one pass) -> KB,VB;
    // attn; Wo + res(remap XS) + LN -> X
    gemm_r_kernel<1, 0, 0, 1><<<512, 256, 0, stream>>>(
        XS, Wt, WTO(9), c_qkvb, 0, QB, nullptr, nullptr, nullptr, 0, nullptr, 0, 0, flag);
    gemm_s_kernel<2, 1, 0, 0, 0><<<640, 512, 0, stream>>>(
        lang, Wt, WTO(10), c_qkvb, 128, KB, VB, nullptr, 128, nullptr, 0, nullptr, 0, 0, flag);
    attn_kernel<0, 80><<<dim3(128, 4), 512, 0, stream>>>(QB, KB, VB, QB, nullptr, nullptr, flag, 1);
    gemm_b_kernel<1, 1, 0, 0><<<512, 256, 0, stream>>>(
        QB, Wt, WTO(15), c_bo, 0, XS, c_ln, 0, nullptr, 0, nullptr, 0, 0,
        nullptr, nullptr, X, flag);

    // self block 1: QKV (one pass, gemm_r NOUT=3) -> QB,KB,VB; attn (b = s/8);
    // Wo + res + LN -> X
    gemm_r_kernel<3, 0, 0, 0><<<512, 256, 0, stream>>>(
        X, Wt, WTO(4), s_qkvb, 384, QB, KB, VB, nullptr, 0, nullptr, 0, 0, flag);
    attn_kernel<1, 256><<<dim3(128, 4), 512, 0, stream>>>(QB, KB, VB, QB, center, rs, flag, 8);
    gemm_b_kernel<0, 1, 0, 0><<<512, 256, 0, stream>>>(
        QB, Wt, WTO(8), s_bo, 128, X, s_ln, 256, nullptr, 0, nullptr, 0, 0,
        nullptr, nullptr, X, flag);

    // cross block 1
    gemm_r_kernel<1, 0, 0, 0><<<512, 256, 0, stream>>>(
        X, Wt, WTO(12), c_qkvb, 384, QB, nullptr, nullptr, nullptr, 0, nullptr, 0, 0, flag);
    gemm_s_kernel<2, 1, 0, 0, 0><<<640, 512, 0, stream>>>(
        lang, Wt, WTO(13), c_qkvb, 512, KB, VB, nullptr, 128, nullptr, 0, nullptr, 0, 0, flag);
    attn_kernel<0, 80><<<dim3(128, 4), 512, 0, stream>>>(QB, KB, VB, QB, nullptr, nullptr, flag, 1);
    gemm_b_kernel<0, 1, 0, 0><<<512, 256, 0, stream>>>(
        QB, Wt, WTO(16), c_bo, 128, X, c_ln, 256, nullptr, 0, nullptr, 0, 0,
        nullptr, nullptr, X, flag);

    // match head: GEMM1 (BN+PReLU, gemm_r) -> KB; GEMM2 (BN+PReLU + W3 dot) -> d_out
    gemm_r_kernel<1, 0, 1, 0><<<512, 256, 0, stream>>>(
        X, Wt, WTO(17), m_b, 0, KB, nullptr, nullptr, m_bn, 0, m_al, 0, 0, flag);
    gemm_b_kernel<0, 0, 1, 1><<<512, 256, 0, stream>>>(
        KB, Wt, WTO(18), m_b, 128, nullptr, nullptr, 0, m_bn, 512, m_al, 1, 0,
        m_W3, m_b3, d_out, flag);
#undef WTO
}

// Round 17
// 334.708 us; speedup vs baseline: 5.1176x; 1.0003x over previous
//
#include <hip/hip_runtime.h>

// ---------------------------------------------------------------------------
// MatchModule forward. H=4 D=128 B=16 K=256 M=8 L=80 DET_C=1152, dk=32.
// R17: byte-exact revert to R13 (last green, 335 us). R14/R15's "sub-serial
// per-wave 16-row P tile" is implicated in both accuracy failures (adjacent
// LDS write->read of P/sF with mixed access types -> compiler reorder hazard).
// R13 keeps P writes (both subs) separated from P reads by loop structure.
// ---------------------------------------------------------------------------

#define DD 128

typedef __attribute__((ext_vector_type(8))) short bf16x8;
typedef __attribute__((ext_vector_type(4))) float f32x4;

__device__ __forceinline__ float bf2f(unsigned short u) {
    union { unsigned int i; float f; } v; v.i = ((unsigned int)u) << 16; return v.f;
}
__device__ __forceinline__ unsigned short f2bf(float f) {   // manual RTNE (cold paths)
    union { float f; unsigned int i; } v; v.f = f;
    unsigned int x = v.i;
    return (unsigned short)((x + 0x7FFFu + ((x >> 16) & 1u)) >> 16);
}
__device__ __forceinline__ unsigned pack2bf(float a, float b) {  // lo=a, hi=b
    unsigned r;
    asm("v_cvt_pk_bf16_f32 %0, %1, %2" : "=v"(r) : "v"(a), "v"(b));
    return r;
}
__device__ __forceinline__ unsigned short f2bf_hw(float a) {
    unsigned r;
    asm("v_cvt_pk_bf16_f32 %0, %1, %1" : "=v"(r) : "v"(a));
    return (unsigned short)r;
}
__device__ __forceinline__ float ldx(const void* p, size_t i, int isf32) {
    return isf32 ? ((const float*)p)[i] : bf2f(((const unsigned short*)p)[i]);
}
__device__ __forceinline__ bf16x8 ld_frag8(const unsigned short* base) {  // 8B-aligned (LDS)
    union { bf16x8 v; uint2 u[2]; } r;
    r.u[0] = *(const uint2*)(base);
    r.u[1] = *(const uint2*)(base + 4);
    return r.v;
}
__device__ __forceinline__ bf16x8 ld_frag16g(const unsigned short* p) {   // 16B-aligned
    union { bf16x8 v; uint4 u; } r;
    r.u = *(const uint4*)p;
    return r.v;
}

// ---------------------------------------------------------------------------
__global__ __launch_bounds__(256) void detect_kernel(
    const unsigned short* __restrict__ c, int* __restrict__ flag) {
    __shared__ int cnt;
    if (threadIdx.x == 0) cnt = 0;
    __syncthreads();
    float v = bf2f(c[threadIdx.x]);
    int sane = (v == v) && (fabsf(v) <= 1e4f) && (v == 0.f || fabsf(v) >= 1e-10f);
    atomicAdd(&cnt, sane);
    __syncthreads();
    if (threadIdx.x == 0) flag[0] = (cnt >= 224) ? 0 : 1;  // 0=bf16, 1=f32
}

__global__ void sentinel_kernel(unsigned short* out, int n, int val) {
    int i = blockIdx.x * 256 + threadIdx.x;
    if (i < n) out[i] = (unsigned short)val;
}

// ---------------------------------------------------------------------------
// prep_wt: Wt = bf16(W^T). region 0: fc1^T [128][1152]. Then 19 [128][128]:
// 0=fc2, 1..6=s_qkv, 7..8=s_Wo, 9..14=c_qkv, 15..16=c_Wo, 17..18=m_W.
// ---------------------------------------------------------------------------
__global__ __launch_bounds__(256) void prep_wt_kernel(
    const void* __restrict__ fc1_W, const void* __restrict__ fc2_W,
    const void* __restrict__ s_qkv, const void* __restrict__ s_Wo,
    const void* __restrict__ c_qkv, const void* __restrict__ c_Wo,
    const void* __restrict__ m_W, unsigned short* __restrict__ Wt,
    const int* __restrict__ flagp) {
    const int isf32 = *flagp;
    const int j = blockIdx.x * 256 + threadIdx.x;
    float v;
    if (j < 147456) {
        const int n = j / 1152, k = j - n * 1152;
        v = ldx(fc1_W, (size_t)k * 128 + n, isf32);
    } else {
        const int t = j - 147456;
        const int mat = t >> 14, o = t & 16383;
        const int n = o >> 7, k = o & 127;
        const void* src; int loc;
        if (mat == 0)       { src = fc2_W; loc = 0; }
        else if (mat <= 6)  { src = s_qkv; loc = mat - 1; }
        else if (mat <= 8)  { src = s_Wo;  loc = mat - 7; }
        else if (mat <= 14) { src = c_qkv; loc = mat - 9; }
        else if (mat <= 16) { src = c_Wo;  loc = mat - 15; }
        else                { src = m_W;   loc = mat - 17; }
        v = ldx(src, (size_t)loc * 16384 + k * 128 + n, isf32);
    }
    Wt[j] = f2bf(v);
}

// ---------------------------------------------------------------------------
__global__ __launch_bounds__(256) void rowsum_kernel(
    const void* __restrict__ center, float* __restrict__ rs,
    const int* __restrict__ flagp) {
    const int isf32 = *flagp;
    const int b = blockIdx.x, i = threadIdx.x;
    __shared__ float c[768];
    for (int idx = i; idx < 768; idx += 256) c[idx] = ldx(center, (size_t)b * 768 + idx, isf32);
    __syncthreads();
    const float cx = c[i * 3], cy = c[i * 3 + 1], cz = c[i * 3 + 2];
    float s = 0.f;
    for (int j = 0; j < 256; ++j) {
        float dx = cx - c[j * 3], dy = cy - c[j * 3 + 1], dz = cz - c[j * 3 + 2];
        s += 1.f / (sqrtf(dx * dx + dy * dy + dz * dz) + 0.01f);
    }
    rs[b * 256 + i] = s;
}

// ---------------------------------------------------------------------------
// gemm_s: 512 thr = 8 waves; block = 16 rows; wave w = one 16-col tile.
// For SMALL nrows or large Kdim (fc1/fc2/self0/cross-KV). (R12-proven.)
// ---------------------------------------------------------------------------
template <int NOUT, int AMODE, int EPI, int OUTF32, int REMAP>
__global__ __launch_bounds__(512, 2) void gemm_s_kernel(
    const void* __restrict__ A,
    const unsigned short* __restrict__ Wt, int wtOff,
    const void* __restrict__ bias, int bOff,
    void* __restrict__ out0, void* __restrict__ out1, void* __restrict__ out2,
    int Kdim,
    const void* __restrict__ bn, int bnOff,
    const void* __restrict__ alpha, int aOff, int alpha_pc,
    const int* __restrict__ flagp) {
    const int isf32 = *flagp;
    const bool f32A = (AMODE == 0) || (AMODE == 1 && isf32);
    const int tid = threadIdx.x;
    const int l = tid & 63, w = tid >> 6;
    const int lg = l >> 4, ll = l & 15;
    const int m0 = blockIdx.x * 16;
    int arow = m0 + ll;
    if (REMAP) arow = (arow >> 11) * 256 + (arow & 255);
    const f32x4 zf = {0.f, 0.f, 0.f, 0.f};
    f32x4 acc[NOUT];
#pragma unroll
    for (int o = 0; o < NOUT; ++o) acc[o] = zf;
    const float* Af = (const float*)A;
    const unsigned short* Au = (const unsigned short*)A;
    const unsigned short* Wb = Wt + wtOff;
    const int wrow = w * 16 + ll;

    for (int kc = 0; kc < Kdim; kc += 128) {
        bf16x8 af[4];
        if (f32A) {
#pragma unroll
            for (int ks = 0; ks < 4; ++ks) {
                const float4* ap = (const float4*)(Af + (size_t)arow * Kdim + kc + ks * 32 + lg * 8);
                const float4 a0 = ap[0], a1 = ap[1];
                union { bf16x8 v; unsigned u[4]; } r;
                r.u[0] = pack2bf(a0.x, a0.y); r.u[1] = pack2bf(a0.z, a0.w);
                r.u[2] = pack2bf(a1.x, a1.y); r.u[3] = pack2bf(a1.z, a1.w);
                af[ks] = r.v;
            }
        } else {
#pragma unroll
            for (int ks = 0; ks < 4; ++ks)
                af[ks] = ld_frag16g(Au + (size_t)arow * Kdim + kc + ks * 32 + lg * 8);
        }
#pragma unroll
        for (int o = 0; o < NOUT; ++o) {
#pragma unroll
            for (int ks = 0; ks < 4; ++ks) {
                const bf16x8 wf = ld_frag16g(
                    Wb + (size_t)o * 128 * Kdim + (size_t)wrow * Kdim + kc + ks * 32 + lg * 8);
                acc[o] = __builtin_amdgcn_mfma_f32_16x16x32_bf16(af[ks], wf, acc[o], 0, 0, 0);
            }
        }
    }

    const int col = w * 16 + ll;
    const int rbase = m0 + lg * 4;
#pragma unroll
    for (int o = 0; o < NOUT; ++o) {
        void* outp = (o == 0) ? out0 : (o == 1) ? out1 : out2;
        const float bs = ldx(bias, (size_t)bOff + o * 128 + col, isf32);
        float g = 1.f, bb = 0.f, mmn = 0.f, rinv = 1.f, al = 0.f;
        if (EPI) {
            g    = ldx(bn, (size_t)bnOff + col, isf32);
            bb   = ldx(bn, (size_t)bnOff + 128 + col, isf32);
            mmn  = ldx(bn, (size_t)bnOff + 256 + col, isf32);
            rinv = rsqrtf(ldx(bn, (size_t)bnOff + 384 + col, isf32) + 1e-5f);
            al   = alpha_pc ? ldx(alpha, (size_t)aOff + col, isf32)
                            : ldx(alpha, (size_t)aOff, isf32);
        }
#pragma unroll
        for (int r = 0; r < 4; ++r) {
            float v = acc[o][r] + bs;
            if (EPI) {
                v = g * (v - mmn) * rinv + bb;
                v = (v >= 0.f) ? v : al * v;
            }
            const size_t oi = (size_t)(rbase + r) * 128 + col;
            if (OUTF32) ((float*)outp)[oi] = v;
            else ((unsigned short*)outp)[oi] = f2bf_hw(v);
        }
    }
}

// ---------------------------------------------------------------------------
// gemm_r: 256 thr = 4 waves; block = 64 rows; wave owns 16 FULL rows; Kdim=128.
// (R13-proven.)
// ---------------------------------------------------------------------------
template <int NOUT, int AMODE, int EPI, int REMAP>
__global__ __launch_bounds__(256, 4) void gemm_r_kernel(
    const void* __restrict__ A,
    const unsigned short* __restrict__ Wt, int wtOff,
    const void* __restrict__ bias, int bOff,
    void* __restrict__ out0, void* __restrict__ out1, void* __restrict__ out2,
    const void* __restrict__ bn, int bnOff,
    const void* __restrict__ alpha, int aOff, int alpha_pc,
    const int* __restrict__ flagp) {
    const int isf32 = *flagp;
    const int tid = threadIdx.x;
    const int l = tid & 63, w = tid >> 6;
    const int lg = l >> 4, ll = l & 15;
    const int m0 = blockIdx.x * 64;
    int arow = m0 + w * 16 + ll;
    if (REMAP) arow = (arow >> 11) * 256 + (arow & 255);
    const f32x4 zf = {0.f, 0.f, 0.f, 0.f};
    f32x4 acc[NOUT][8];
#pragma unroll
    for (int o = 0; o < NOUT; ++o)
#pragma unroll
        for (int nt = 0; nt < 8; ++nt) acc[o][nt] = zf;
    const unsigned short* Wb = Wt + wtOff;

    bf16x8 af[4];
    if (AMODE == 0) {
        const float* Af = (const float*)A;
#pragma unroll
        for (int ks = 0; ks < 4; ++ks) {
            const float4* ap = (const float4*)(Af + (size_t)arow * 128 + ks * 32 + lg * 8);
            const float4 a0 = ap[0], a1 = ap[1];
            union { bf16x8 v; unsigned u[4]; } r;
            r.u[0] = pack2bf(a0.x, a0.y); r.u[1] = pack2bf(a0.z, a0.w);
            r.u[2] = pack2bf(a1.x, a1.y); r.u[3] = pack2bf(a1.z, a1.w);
            af[ks] = r.v;
        }
    } else {
        const unsigned short* Au = (const unsigned short*)A;
#pragma unroll
        for (int ks = 0; ks < 4; ++ks)
            af[ks] = ld_frag16g(Au + (size_t)arow * 128 + ks * 32 + lg * 8);
    }
#pragma unroll
    for (int o = 0; o < NOUT; ++o) {
#pragma unroll
        for (int nt = 0; nt < 8; ++nt) {
#pragma unroll
            for (int ks = 0; ks < 4; ++ks) {
                const bf16x8 wf = ld_frag16g(
                    Wb + (size_t)o * 16384 + (size_t)(nt * 16 + ll) * 128 + ks * 32 + lg * 8);
                acc[o][nt] = __builtin_amdgcn_mfma_f32_16x16x32_bf16(af[ks], wf, acc[o][nt], 0, 0, 0);
            }
        }
    }

    const int rbase = m0 + w * 16 + lg * 4;
#pragma unroll
    for (int o = 0; o < NOUT; ++o) {
        unsigned short* outp = (unsigned short*)((o == 0) ? out0 : (o == 1) ? out1 : out2);
#pragma unroll
        for (int nt = 0; nt < 8; ++nt) {
            const int col = nt * 16 + ll;
            const float bs = ldx(bias, (size_t)bOff + o * 128 + col, isf32);
            float g = 1.f, bb = 0.f, mmn = 0.f, rinv = 1.f, al = 0.f;
            if (EPI) {
                g    = ldx(bn, (size_t)bnOff + col, isf32);
                bb   = ldx(bn, (size_t)bnOff + 128 + col, isf32);
                mmn  = ldx(bn, (size_t)bnOff + 256 + col, isf32);
                rinv = rsqrtf(ldx(bn, (size_t)bnOff + 384 + col, isf32) + 1e-5f);
                al   = alpha_pc ? ldx(alpha, (size_t)aOff + col, isf32)
                                : ldx(alpha, (size_t)aOff, isf32);
            }
#pragma unroll
            for (int r = 0; r < 4; ++r) {
                float v = acc[o][nt][r] + bs;
                if (EPI) {
                    v = g * (v - mmn) * rinv + bb;
                    v = (v >= 0.f) ? v : al * v;
                }
                outp[(size_t)(rbase + r) * 128 + col] = f2bf_hw(v);
            }
        }
    }
}

// ---------------------------------------------------------------------------
// gemm_b: 256 thr = 4 waves; block = 64 rows; wave owns 16 FULL rows.
// LNF: residual + in-wave LayerNorm -> f32 out. FDOT: W3 dot -> d_out.
// (R12-proven.)
// ---------------------------------------------------------------------------
template <int REMAPR, int LNF, int EPI, int FDOT>
__global__ __launch_bounds__(256, 4) void gemm_b_kernel(
    const unsigned short* __restrict__ A,
    const unsigned short* __restrict__ Wt, int wtOff,
    const void* __restrict__ bias, int bOff,
    const float* __restrict__ Xres,
    const void* __restrict__ lnp, int lnOff,
    const void* __restrict__ bn, int bnOff,
    const void* __restrict__ alpha, int aOff, int alpha_pc,
    const void* __restrict__ W3, const void* __restrict__ b3,
    void* __restrict__ out, const int* __restrict__ flagp) {
    const int isf32 = *flagp;
    const int tid = threadIdx.x;
    const int l = tid & 63, w = tid >> 6;
    const int lg = l >> 4, ll = l & 15;
    const int m0 = blockIdx.x * 64;
    const int arow = m0 + w * 16 + ll;
    const f32x4 zf = {0.f, 0.f, 0.f, 0.f};
    f32x4 acc[8] = {zf, zf, zf, zf, zf, zf, zf, zf};
    const unsigned short* Wb = Wt + wtOff;

    bf16x8 af[4];
#pragma unroll
    for (int ks = 0; ks < 4; ++ks)
        af[ks] = ld_frag16g(A + (size_t)arow * 128 + ks * 32 + lg * 8);
#pragma unroll
    for (int nt = 0; nt < 8; ++nt) {
#pragma unroll
        for (int ks = 0; ks < 4; ++ks) {
            const bf16x8 wf = ld_frag16g(Wb + (size_t)(nt * 16 + ll) * 128 + ks * 32 + lg * 8);
            acc[nt] = __builtin_amdgcn_mfma_f32_16x16x32_bf16(af[ks], wf, acc[nt], 0, 0, 0);
        }
    }

    const int rbase = m0 + w * 16 + lg * 4;
    float v[8][4];
#pragma unroll
    for (int nt = 0; nt < 8; ++nt) {
        const int col = nt * 16 + ll;
        const float bs = ldx(bias, (size_t)bOff + col, isf32);
        float g = 1.f, bb = 0.f, mmn = 0.f, rinv = 1.f, al = 0.f;
        if (EPI) {
            g    = ldx(bn, (size_t)bnOff + col, isf32);
            bb   = ldx(bn, (size_t)bnOff + 128 + col, isf32);
            mmn  = ldx(bn, (size_t)bnOff + 256 + col, isf32);
            rinv = rsqrtf(ldx(bn, (size_t)bnOff + 384 + col, isf32) + 1e-5f);
            al   = alpha_pc ? ldx(alpha, (size_t)aOff + col, isf32)
                            : ldx(alpha, (size_t)aOff, isf32);
        }
#pragma unroll
        for (int r = 0; r < 4; ++r) {
            const int row = rbase + r;
            float x = acc[nt][r] + bs;
            if (LNF) {
                const int src = REMAPR ? ((row >> 11) * 256 + (row & 255)) : row;
                x += Xres[(size_t)src * 128 + col];
            }
            if (EPI) {
                x = g * (x - mmn) * rinv + bb;
                x = (x >= 0.f) ? x : al * x;
            }
            v[nt][r] = x;
        }
    }

    if (LNF) {
        float s1[4], s2[4];
#pragma unroll
        for (int r = 0; r < 4; ++r) {
            float a = 0.f, b = 0.f;
#pragma unroll
            for (int nt = 0; nt < 8; ++nt) { a += v[nt][r]; b += v[nt][r] * v[nt][r]; }
#pragma unroll
            for (int o = 1; o < 16; o <<= 1) { a += __shfl_xor(a, o); b += __shfl_xor(b, o); }
            s1[r] = a; s2[r] = b;
        }
#pragma unroll
        for (int nt = 0; nt < 8; ++nt) {
            const int col = nt * 16 + ll;
            const float gam = ldx(lnp, (size_t)lnOff + col, isf32);
            const float bet = ldx(lnp, (size_t)lnOff + 128 + col, isf32);
#pragma unroll
            for (int r = 0; r < 4; ++r) {
                const float mu = s1[r] * (1.f / 128.f);
                const float var = s2[r] * (1.f / 128.f) - mu * mu;
                ((float*)out)[(size_t)(rbase + r) * 128 + col] =
                    gam * (v[nt][r] - mu) * rsqrtf(var + 1e-5f) + bet;
            }
        }
    } else if (FDOT) {
        float part[4] = {0.f, 0.f, 0.f, 0.f};
#pragma unroll
        for (int nt = 0; nt < 8; ++nt) {
            const int col = nt * 16 + ll;
            const float w3 = ldx(W3, col, isf32);
#pragma unroll
            for (int r = 0; r < 4; ++r) part[r] += v[nt][r] * w3;
        }
#pragma unroll
        for (int r = 0; r < 4; ++r) {
#pragma unroll
            for (int o = 1; o < 16; o <<= 1) part[r] += __shfl_xor(part[r], o);
        }
        if (ll == 0) {
            const float bb3 = ldx(b3, 0, isf32);
#pragma unroll
            for (int r = 0; r < 4; ++r) {
                const int row = rbase + r;
                if (isf32) ((float*)out)[row] = part[r] + bb3;
                else ((unsigned short*)out)[row] = f2bf(part[r] + bb3);
            }
        }
    }
}

// ---------------------------------------------------------------------------
// Pure-flash MFMA attention (R11/R13-proven, byte-exact).
// ---------------------------------------------------------------------------
template <int SELF, int NK>
__global__ __launch_bounds__(512, 2) void attn_kernel(
    const unsigned short* __restrict__ Qb,
    const unsigned short* __restrict__ Kb,
    const unsigned short* __restrict__ Vb,
    unsigned short* __restrict__ O,
    const void* __restrict__ center, const float* __restrict__ rs,
    const int* __restrict__ flagp, int bDiv) {
    constexpr int NKR = (NK + 31) & ~31;
    constexpr int VSTR = NKR + 8;
    __shared__ __align__(16) unsigned short sKb[NK * 36];
    __shared__ __align__(16) unsigned short sVT[32 * VSTR];
    __shared__ __align__(16) unsigned short sP[8 * 32 * 36];
    __shared__ float sF[256];
    __shared__ float sC[SELF ? 768 : 1];
    __shared__ float sR[SELF ? 256 : 1];

    const int isf32 = *flagp;
    const int s = blockIdx.x, h = blockIdx.y, tid = threadIdx.x;
    const int l = tid & 63, w = tid >> 6;
    const int hc = h * 32;
    const int lg = l >> 4, ll = l & 15;

    for (int idx = tid; idx < NK * 4; idx += 512) {
        const int j = idx >> 2, g = idx & 3;
        const uint4 t = *(const uint4*)(Kb + ((size_t)(s * NK + j)) * 128 + hc + g * 8);
        uint2* d = (uint2*)(sKb + j * 36 + g * 8);
        d[0] = make_uint2(t.x, t.y);
        d[1] = make_uint2(t.z, t.w);
    }
    for (int idx = tid; idx < NK * 4; idx += 512) {
        const int j = idx >> 2, g = idx & 3;
        const uint4 t = *(const uint4*)(Vb + ((size_t)(s * NK + j)) * 128 + hc + g * 8);
        const unsigned short* e = (const unsigned short*)&t;
#pragma unroll
        for (int u = 0; u < 8; ++u) sVT[(g * 8 + u) * VSTR + j] = e[u];
    }
    if constexpr (NKR != NK) {
        for (int idx = tid; idx < 32 * (NKR - NK); idx += 512) {
            const int i = idx / (NKR - NK), j = NK + idx % (NKR - NK);
            sVT[i * VSTR + j] = 0;
        }
    }
    if (SELF) {
        const int bb = s / bDiv;
        for (int idx = tid; idx < 768; idx += 512)
            sC[idx] = ldx(center, (size_t)bb * 768 + idx, isf32);
        if (tid < 256) sR[tid] = 1.0f / rs[bb * 256 + tid];
    }

    bf16x8 qfrag[2];
#pragma unroll
    for (int sub = 0; sub < 2; ++sub)
        qfrag[sub] = ld_frag16g(Qb + ((size_t)(s * 256 + w * 32 + sub * 16 + ll)) * 128 + hc + lg * 8);

    __syncthreads();

    const float scale = 0.17677669529663687f;
    float cqx[2], cqy[2], cqz[2];
    if (SELF) {
#pragma unroll
        for (int sub = 0; sub < 2; ++sub) {
            const int qg = w * 32 + sub * 16 + ll;
            cqx[sub] = sC[qg * 3]; cqy[sub] = sC[qg * 3 + 1]; cqz[sub] = sC[qg * 3 + 2];
        }
    }
    float m_[2] = {-3.0e38f, -3.0e38f}, l_[2] = {0.f, 0.f};
    const f32x4 zf = {0.f, 0.f, 0.f, 0.f};
    f32x4 oacc[2][2] = {{zf, zf}, {zf, zf}};
    unsigned short* sPw = sP + w * 32 * 36;

    for (int kb = 0; kb < NK; kb += 32) {
        const int full = (NK - kb) >= 32;
        const unsigned short* kbase = sKb + (kb + ll) * 36 + lg * 8;
        const bf16x8 kf0 = ld_frag8(kbase);
        bf16x8 kf1;
        if (full) kf1 = ld_frag8(kbase + 16 * 36);

#pragma unroll
        for (int sub = 0; sub < 2; ++sub) {
            f32x4 s0 = __builtin_amdgcn_mfma_f32_16x16x32_bf16(kf0, qfrag[sub], zf, 0, 0, 0);
            f32x4 s1 = zf;
            if (full) s1 = __builtin_amdgcn_mfma_f32_16x16x32_bf16(kf1, qfrag[sub], zf, 0, 0, 0);

            float sc[8];
#pragma unroll
            for (int r = 0; r < 4; ++r) {
                const int k0 = kb + lg * 4 + r;
                float v0 = s0[r] * scale;
                float v1 = full ? s1[r] * scale : -3.0e38f;
                if (SELF && h < 2) {
                    {
                        const float dx = cqx[sub] - sC[k0 * 3], dy = cqy[sub] - sC[k0 * 3 + 1],
                                    dz = cqz[sub] - sC[k0 * 3 + 2];
                        const float dist = sqrtf(dx * dx + dy * dy + dz * dz);
                        if (h == 0) v0 += __fdividef(1.f, dist + 0.01f) * sR[k0];
                        else v0 -= dist;
                    }
                    if (full) {
                        const int k1 = k0 + 16;
                        const float dx = cqx[sub] - sC[k1 * 3], dy = cqy[sub] - sC[k1 * 3 + 1],
                                    dz = cqz[sub] - sC[k1 * 3 + 2];
                        const float dist = sqrtf(dx * dx + dy * dy + dz * dz);
                        if (h == 0) v1 += __fdividef(1.f, dist + 0.01f) * sR[k1];
                        else v1 -= dist;
                    }
                }
                sc[r] = v0; sc[4 + r] = v1;
            }
            float tmax = fmaxf(fmaxf(fmaxf(sc[0], sc[1]), fmaxf(sc[2], sc[3])),
                               fmaxf(fmaxf(sc[4], sc[5]), fmaxf(sc[6], sc[7])));
            tmax = fmaxf(tmax, __shfl_xor(tmax, 16));
            tmax = fmaxf(tmax, __shfl_xor(tmax, 32));
            const float mnew = fmaxf(m_[sub], tmax);
            const float f = __expf(m_[sub] - mnew);
            m_[sub] = mnew;
            float p[8], lsum = 0.f;
#pragma unroll
            for (int u = 0; u < 8; ++u) { p[u] = __expf(sc[u] - mnew); lsum += p[u]; }
            lsum += __shfl_xor(lsum, 16);
            lsum += __shfl_xor(lsum, 32);
            l_[sub] = l_[sub] * f + lsum;
            if (lg == 0) sF[w * 32 + sub * 16 + ll] = f;
            unsigned* prow = (unsigned*)((char*)sPw + (sub * 16 + ll) * 72 + lg * 8);
            prow[0] = pack2bf(p[0], p[1]);
            prow[1] = pack2bf(p[2], p[3]);
            unsigned* prow1 = (unsigned*)((char*)prow + 32);
            prow1[0] = pack2bf(p[4], p[5]);
            prow1[1] = pack2bf(p[6], p[7]);
        }

        bf16x8 vf[2], pf[2];
#pragma unroll
        for (int dt = 0; dt < 2; ++dt)
            vf[dt] = *(const bf16x8*)(sVT + (dt * 16 + ll) * VSTR + kb + lg * 8);
#pragma unroll
        for (int sub = 0; sub < 2; ++sub) {
            pf[sub] = ld_frag8(sPw + (sub * 16 + ll) * 36 + lg * 8);
            float fr[4];
#pragma unroll
            for (int r = 0; r < 4; ++r) fr[r] = sF[w * 32 + sub * 16 + lg * 4 + r];
#pragma unroll
            for (int dt = 0; dt < 2; ++dt) {
#pragma unroll
                for (int r = 0; r < 4; ++r) oacc[sub][dt][r] *= fr[r];
                oacc[sub][dt] = __builtin_amdgcn_mfma_f32_16x16x32_bf16(
                    pf[sub], vf[dt], oacc[sub][dt], 0, 0, 0);
            }
        }
    }

    if (lg == 0) {
        sF[w * 32 + ll]      = 1.f / l_[0];
        sF[w * 32 + 16 + ll] = 1.f / l_[1];
    }
#pragma unroll
    for (int sub = 0; sub < 2; ++sub) {
#pragma unroll
        for (int r = 0; r < 4; ++r) {
            const float li = sF[w * 32 + sub * 16 + lg * 4 + r];
            const int qrow = w * 32 + sub * 16 + lg * 4 + r;
#pragma unroll
            for (int dt = 0; dt < 2; ++dt) {
                O[((size_t)(s * 256 + qrow)) * 128 + hc + dt * 16 + ll] =
                    f2bf_hw(oacc[sub][dt][r] * li);
            }
        }
    }
}

// ---------------------------------------------------------------------------

extern "C" void kernel_launch(void* const* d_in, const int* in_sizes, int n_in,
                              void* d_out, int out_size, void* d_ws, size_t ws_size,
                              hipStream_t stream) {
    bool ok = (n_in >= 29) && in_sizes[0] == 12288 && in_sizes[1] == 4718592 &&
              in_sizes[2] == 1310720 && in_sizes[7] == 147456 &&
              in_sizes[13] == 98304 && in_sizes[25] == 1024 && in_sizes[27] == 128;
    if (!ok) {
        sentinel_kernel<<<(out_size + 255) / 256, 256, 0, stream>>>(
            (unsigned short*)d_out, out_size, 0x44FA);
        return;
    }
    const size_t SZ = (size_t)32768 * 128;
    const size_t NEED = (16384ull + 2ull * SZ + 2ull * 10240 * 128) * 4ull;  // 44.1 MB (proven)
    if (ws_size < NEED) {
        sentinel_kernel<<<(out_size + 255) / 256, 256, 0, stream>>>(
            (unsigned short*)d_out, out_size, 0x447A);
        return;
    }

    const void* center = d_in[0];
    const void* detr   = d_in[1];
    const void* lang   = d_in[2];
    const void* fc1_W  = d_in[7];
    const void* fc1_b  = d_in[8];
    const void* bn0    = d_in[9];
    const void* prelu0 = d_in[10];
    const void* fc2_W  = d_in[11];
    const void* fc2_b  = d_in[12];
    const void* s_qkv  = d_in[13];
    const void* s_qkvb = d_in[14];
    const void* s_Wo   = d_in[15];
    const void* s_bo   = d_in[16];
    const void* s_ln   = d_in[17];
    const void* c_qkv  = d_in[18];
    const void* c_qkvb = d_in[19];
    const void* c_Wo   = d_in[20];
    const void* c_bo   = d_in[21];
    const void* c_ln   = d_in[22];
    const void* m_W    = d_in[23];
    const void* m_b    = d_in[24];
    const void* m_bn   = d_in[25];
    const void* m_al   = d_in[26];
    const void* m_W3   = d_in[27];
    const void* m_b3   = d_in[28];

    float* wsf  = (float*)d_ws;
    int*   flag = (int*)d_ws;
    float* rs   = wsf + 4096;
    float* X    = wsf + 16384;                      // f32 [32768][128]
    unsigned short* QB = (unsigned short*)(X + SZ); // bf16 [32768][128]
    unsigned short* KB = QB + SZ;
    unsigned short* VB = KB + SZ;
    unsigned short* Wt = VB + SZ;                   // bf16 458752
    float* XS = (float*)((char*)KB + 3670016);      // f32 [4096][128] (KB tail; disjoint
                                                    // from cross-K rows [0,10240))

#define WTO(mat) (147456 + (mat) * 16384)

    detect_kernel<<<1, 256, 0, stream>>>((const unsigned short*)center, flag);
    prep_wt_kernel<<<1792, 256, 0, stream>>>(fc1_W, fc2_W, s_qkv, s_Wo, c_qkv, c_Wo, m_W, Wt, flag);
    rowsum_kernel<<<16, 256, 0, stream>>>(center, rs, flag);

    // fc1 (+BN+PReLU) -> KB bf16 [0,4096); fc2 -> X f32 (= x0)
    gemm_s_kernel<1, 1, 1, 0, 0><<<256, 512, 0, stream>>>(
        detr, Wt, 0, fc1_b, 0, KB, nullptr, nullptr, 1152, bn0, 0, prelu0, 0, 1, flag);
    gemm_s_kernel<1, 2, 0, 1, 0><<<256, 512, 0, stream>>>(
        KB, Wt, WTO(0), fc2_b, 0, X, nullptr, nullptr, 128, nullptr, 0, nullptr, 0, 0, flag);

    // self block 0 (4096 rows): QKV (one pass) -> QB,KB,VB; attn O in-place QB;
    // Wo + res(x0 in X) + LN -> XS f32
    gemm_s_kernel<3, 0, 0, 0, 0><<<256, 512, 0, stream>>>(
        X, Wt, WTO(1), s_qkvb, 0, QB, KB, VB, 128, nullptr, 0, nullptr, 0, 0, flag);
    attn_kernel<1, 256><<<dim3(16, 4), 512, 0, stream>>>(QB, KB, VB, QB, center, rs, flag, 1);
    gemm_b_kernel<0, 1, 0, 0><<<64, 256, 0, stream>>>(
        QB, Wt, WTO(7), s_bo, 0, X, s_ln, 0, nullptr, 0, nullptr, 0, 0,
        nullptr, nullptr, XS, flag);

    // cross block 0: Q (remap-read XS) -> QB; K,V (lang, one pass) -> KB,VB;
    // attn; Wo + res(remap XS) + LN -> X
    gemm_r_kernel<1, 0, 0, 1><<<512, 256, 0, stream>>>(
        XS, Wt, WTO(9), c_qkvb, 0, QB, nullptr, nullptr, nullptr, 0, nullptr, 0, 0, flag);
    gemm_s_kernel<2, 1, 0, 0, 0><<<640, 512, 0, stream>>>(
        lang, Wt, WTO(10), c_qkvb, 128, KB, VB, nullptr, 128, nullptr, 0, nullptr, 0, 0, flag);
    attn_kernel<0, 80><<<dim3(128, 4), 512, 0, stream>>>(QB, KB, VB, QB, nullptr, nullptr, flag, 1);
    gemm_b_kernel<1, 1, 0, 0><<<512, 256, 0, stream>>>(
        QB, Wt, WTO(15), c_bo, 0, XS, c_ln, 0, nullptr, 0, nullptr, 0, 0,
        nullptr, nullptr, X, flag);

    // self block 1: QKV (one pass, gemm_r NOUT=3) -> QB,KB,VB; attn (b = s/8);
    // Wo + res + LN -> X
    gemm_r_kernel<3, 0, 0, 0><<<512, 256, 0, stream>>>(
        X, Wt, WTO(4), s_qkvb, 384, QB, KB, VB, nullptr, 0, nullptr, 0, 0, flag);
    attn_kernel<1, 256><<<dim3(128, 4), 512, 0, stream>>>(QB, KB, VB, QB, center, rs, flag, 8);
    gemm_b_kernel<0, 1, 0, 0><<<512, 256, 0, stream>>>(
        QB, Wt, WTO(8), s_bo, 128, X, s_ln, 256, nullptr, 0, nullptr, 0, 0,
        nullptr, nullptr, X, flag);

    // cross block 1
    gemm_r_kernel<1, 0, 0, 0><<<512, 256, 0, stream>>>(
        X, Wt, WTO(12), c_qkvb, 384, QB, nullptr, nullptr, nullptr, 0, nullptr, 0, 0, flag);
    gemm_s_kernel<2, 1, 0, 0, 0><<<640, 512, 0, stream>>>(
        lang, Wt, WTO(13), c_qkvb, 512, KB, VB, nullptr, 128, nullptr, 0, nullptr, 0, 0, flag);
    attn_kernel<0, 80><<<dim3(128, 4), 512, 0, stream>>>(QB, KB, VB, QB, nullptr, nullptr, flag, 1);
    gemm_b_kernel<0, 1, 0, 0><<<512, 256, 0, stream>>>(
        QB, Wt, WTO(16), c_bo, 128, X, c_ln, 256, nullptr, 0, nullptr, 0, 0,
        nullptr, nullptr, X, flag);

    // match head: GEMM1 (BN+PReLU, gemm_r) -> KB; GEMM2 (BN+PReLU + W3 dot) -> d_out
    gemm_r_kernel<1, 0, 1, 0><<<512, 256, 0, stream>>>(
        X, Wt, WTO(17), m_b, 0, KB, nullptr, nullptr, m_bn, 0, m_al, 0, 0, flag);
    gemm_b_kernel<0, 0, 1, 1><<<512, 256, 0, stream>>>(
        KB, Wt, WTO(18), m_b, 128, nullptr, nullptr, 0, m_bn, 512, m_al, 1, 0,
        m_W3, m_b3, d_out, flag);
#undef WTO
}